// Round 6
// baseline (516.653 us; speedup 1.0000x reference)
//
#include <hip/hip_runtime.h>
#include <stdint.h>
#include <math.h>

#define NEGV -1.0e12f
// Q pre-scale: 1/sqrt(64) * log2(e)  (softmax uses native exp2)
#define QSCALE 0.18033688011112042f

typedef __attribute__((ext_vector_type(8))) short bf16x8;
typedef __attribute__((ext_vector_type(4))) float f32x4;
typedef __attribute__((ext_vector_type(8))) ushort u16x8;

// word-region layout of the packed mask buffer (uint32 indices)
#define AMASK_WORDS 2097152u              // 67.1M bits (attention, keep-bit)
#define M1_BASE     2097152u              // 4.2M bits (m1, masked-bit)
#define M2_BASE     2228224u              // 4.2M bits (m2, masked-bit)
#define TOT_WORDS   2359296u

// guaranteed 1-instruction rotate
#define ROTL1(v, r) ({ uint32_t _d;                                            \
    asm("v_alignbit_b32 %0, %1, %1, %2" : "=v"(_d) : "v"(v), "n"(32 - (r)));   \
    _d; })

#if defined(__has_builtin)
#if __has_builtin(__builtin_amdgcn_exp2f)
#define EXP2(x) __builtin_amdgcn_exp2f(x)
#endif
#endif
#ifndef EXP2
#define EXP2(x) exp2f(x)
#endif

// ---------------- Threefry-2x32/20, host reference (key derivation) ----------------
__host__ static void tf2x32_host(uint32_t k0, uint32_t k1, uint32_t c0, uint32_t c1,
                                 uint32_t* o0, uint32_t* o1) {
    uint32_t ks2 = k0 ^ k1 ^ 0x1BD11BDAu;
    uint32_t x0 = c0 + k0, x1 = c1 + k1;
#define TF_RND(r) x0 += x1; x1 = ((x1 << (r)) | (x1 >> (32 - (r)))); x1 ^= x0;
    TF_RND(13) TF_RND(15) TF_RND(26) TF_RND(6)
    x0 += k1;  x1 += ks2 + 1u;
    TF_RND(17) TF_RND(29) TF_RND(16) TF_RND(24)
    x0 += ks2; x1 += k0 + 2u;
    TF_RND(13) TF_RND(15) TF_RND(26) TF_RND(6)
    x0 += k0;  x1 += k1 + 3u;
    TF_RND(17) TF_RND(29) TF_RND(16) TF_RND(24)
    x0 += k1;  x1 += ks2 + 4u;
    TF_RND(13) TF_RND(15) TF_RND(26) TF_RND(6)
    x0 += ks2; x1 += k0 + 5u;
#undef TF_RND
    *o0 = x0; *o1 = x1;
}

// device: JAX partitionable random bits for counter (0, j): bits = o0 ^ o1
__device__ __forceinline__ uint32_t tf_bits(uint32_t k0, uint32_t k1, uint32_t j) {
    const uint32_t ks2 = k0 ^ k1 ^ 0x1BD11BDAu;
    uint32_t x0 = k0, x1 = j + k1;
#define TFR(r) x0 += x1; x1 = ROTL1(x1, r); x1 ^= x0;
    TFR(13) TFR(15) TFR(26) TFR(6)
    x0 += k1;  x1 += ks2 + 1u;
    TFR(17) TFR(29) TFR(16) TFR(24)
    x0 += ks2; x1 += k0 + 2u;
    TFR(13) TFR(15) TFR(26) TFR(6)
    x0 += k0;  x1 += k1 + 3u;
    TFR(17) TFR(29) TFR(16) TFR(24)
    x0 += k1;  x1 += ks2 + 4u;
    TFR(13) TFR(15) TFR(26) TFR(6)
#undef TFR
    return (x0 + ks2) ^ (x1 + (k0 + 5u));
}

// bernoulli(p) true  <=>  bits < T,  T = ceil(p * 2^23) << 9  (exact vs JAX float path)
__host__ static uint32_t maskT(float p) {
    double t = ceil((double)p * 8388608.0);
    return ((uint32_t)t) << 9;
}

__device__ __forceinline__ ushort f2bf(float x) {
    uint32_t u = __float_as_uint(x);
    u += 0x7fffu + ((u >> 16) & 1u);
    return (ushort)(u >> 16);
}
__device__ __forceinline__ float bf2f(ushort u) {
    return __uint_as_float(((uint32_t)u) << 16);
}

// ---------------- packed-bit mask precompute (pure threefry) ----------------
// thread handles 2 consecutive words (64 draws). Region 0: keep-bit (amask p=0.5);
// regions 1/2: masked-bit (bits < T).
__global__ __launch_bounds__(256) void mask_k(uint32_t* __restrict__ mw,
                                              uint32_t a0, uint32_t a1,
                                              uint32_t b0, uint32_t b1,
                                              uint32_t c0, uint32_t c1,
                                              uint32_t T1, uint32_t T2)
{
    const uint32_t w0 = (blockIdx.x * 256u + threadIdx.x) * 2u;
    if (w0 >= TOT_WORDS) return;
    uint32_t k0, k1, T = 0, jb;
    int keepmode;
    if (w0 < M1_BASE)      { k0 = a0; k1 = a1; jb = w0 * 32u; keepmode = 1; }
    else if (w0 < M2_BASE) { k0 = b0; k1 = b1; jb = (w0 - M1_BASE) * 32u; T = T1; keepmode = 0; }
    else                   { k0 = c0; k1 = c1; jb = (w0 - M2_BASE) * 32u; T = T2; keepmode = 0; }
    uint32_t o0 = 0, o1 = 0;
    if (keepmode) {
#pragma unroll 8
        for (uint32_t i = 0; i < 32; ++i) {
            o0 |= (tf_bits(k0, k1, jb + i) >> 31) << i;
            o1 |= (tf_bits(k0, k1, jb + 32u + i) >> 31) << i;
        }
    } else {
#pragma unroll 8
        for (uint32_t i = 0; i < 32; ++i) {
            o0 |= (uint32_t)(tf_bits(k0, k1, jb + i) < T) << i;
            o1 |= (uint32_t)(tf_bits(k0, k1, jb + 32u + i) < T) << i;
        }
    }
    *(uint2*)(mw + w0) = make_uint2(o0, o1);
}

// ---------------- x transpose+convert: x[b][c][n] fp32 -> xt[b*1024+n][c] bf16 -------
__global__ __launch_bounds__(256) void xpose_k(const float* __restrict__ x,
                                               ushort* __restrict__ xt)
{
    __shared__ float tile[64][65];
    const int tid = threadIdx.x;
    const int b = blockIdx.z, c0 = blockIdx.y * 64, n0 = blockIdx.x * 64;
    const float* src = x + ((size_t)b * 512 + c0) * 1024 + n0;
#pragma unroll
    for (int i = 0; i < 4; ++i) {
        const int r = (tid >> 4) + i * 16;
        const int col = (tid & 15) * 4;
        float4 v = *(const float4*)(src + (size_t)r * 1024 + col);
        tile[r][col + 0] = v.x; tile[r][col + 1] = v.y;
        tile[r][col + 2] = v.z; tile[r][col + 3] = v.w;
    }
    __syncthreads();
#pragma unroll
    for (int i = 0; i < 2; ++i) {
        const int nl = (tid >> 3) + i * 32;
        const int cb = (tid & 7) * 8;
        u16x8 o;
#pragma unroll
        for (int j = 0; j < 8; ++j) o[j] = f2bf(tile[cb + j][nl]);
        *(u16x8*)(xt + ((size_t)b * 1024 + n0 + nl) * 512 + c0 + cb) = o;
    }
}

// ---------------- weight convert fp32 -> bf16 (5 regions packed) ----------------
__global__ __launch_bounds__(256) void wcvt_k(const float* __restrict__ s0,
                                              const float* __restrict__ s1,
                                              const float* __restrict__ s2,
                                              const float* __restrict__ s3,
                                              const float* __restrict__ s4,
                                              ushort* __restrict__ dst)
{
    const size_t i = ((size_t)blockIdx.x * 256 + threadIdx.x) * 8;
    const float* src; size_t off;
    if (i < 262144)       { src = s0; off = 0; }
    else if (i < 1048576) { src = s1; off = 262144; }
    else if (i < 1310720) { src = s2; off = 1048576; }
    else if (i < 1572864) { src = s3; off = 1310720; }
    else                  { src = s4; off = 1572864; }
    const float* p = src + (i - off);
    float4 a = *(const float4*)p;
    float4 b = *(const float4*)(p + 4);
    u16x8 o;
    o[0] = f2bf(a.x); o[1] = f2bf(a.y); o[2] = f2bf(a.z); o[3] = f2bf(a.w);
    o[4] = f2bf(b.x); o[5] = f2bf(b.y); o[6] = f2bf(b.z); o[7] = f2bf(b.w);
    *(u16x8*)(dst + i) = o;
}

// ---------------- bf16 MFMA GEMM: C[m][o] = sum_k A[m][k]*W[o][k] + bias[o] ---------
// A [M][512] bf16, W [O][512] bf16. Block = 4 waves stacked in m; wave tile RWx64.
// EPI 1: qkv scatter  2: gelu + m1-bit -> bf16  3: m2-bit -> fp32  4: bf16 store
template<int RW, int EPI>
__global__ __launch_bounds__(256) void bgemm_k(
    const ushort* __restrict__ A, const ushort* __restrict__ W,
    const float* __restrict__ bias, float* __restrict__ outf,
    ushort* __restrict__ outb,
    ushort* __restrict__ qb, ushort* __restrict__ kb, ushort* __restrict__ vb,
    const uint32_t* __restrict__ mw, uint32_t wbase)
{
    constexpr int NF = RW / 16;
    const int tid = threadIdx.x;
    const int wave = tid >> 6, lane = tid & 63;
    const int lg = lane >> 4, lc = lane & 15;
    const int m0 = blockIdx.x * (4 * RW) + wave * RW;
    const int o0 = blockIdx.y * 64;

    f32x4 acc[NF][4];
#pragma unroll
    for (int i = 0; i < NF; ++i)
#pragma unroll
        for (int j = 0; j < 4; ++j) acc[i][j] = (f32x4){0.f, 0.f, 0.f, 0.f};

    const ushort* Ab = A + (size_t)(m0 + lc) * 512 + lg * 8;
    const ushort* Wb = W + (size_t)(o0 + lc) * 512 + lg * 8;

#pragma unroll 4
    for (int k0 = 0; k0 < 512; k0 += 32) {
        bf16x8 aq[NF], bw[4];
#pragma unroll
        for (int i = 0; i < NF; ++i) aq[i] = *(const bf16x8*)(Ab + (size_t)i * 16 * 512 + k0);
#pragma unroll
        for (int j = 0; j < 4; ++j) bw[j] = *(const bf16x8*)(Wb + (size_t)j * 16 * 512 + k0);
#pragma unroll
        for (int i = 0; i < NF; ++i)
#pragma unroll
            for (int j = 0; j < 4; ++j)
                acc[i][j] = __builtin_amdgcn_mfma_f32_16x16x32_bf16(aq[i], bw[j], acc[i][j], 0, 0, 0);
    }

    float bvv[4];
#pragma unroll
    for (int j = 0; j < 4; ++j) bvv[j] = bias[o0 + j * 16 + lc];

#pragma unroll
    for (int i = 0; i < NF; ++i) {
#pragma unroll
        for (int j = 0; j < 4; ++j) {
#pragma unroll
            for (int r = 0; r < 4; ++r) {
                const int m = m0 + i * 16 + lg * 4 + r;
                const int o = o0 + j * 16 + lc;
                float v = acc[i][j][r] + bvv[j];
                if constexpr (EPI == 4) {
                    outb[(size_t)m * 512 + o] = f2bf(v);
                } else if constexpr (EPI == 2) {
                    v = 0.5f * v * (1.0f + erff(v * 0.70710678118654752f));
                    if ((mw[wbase + (uint32_t)m * 16u + (o >> 5)] >> (o & 31)) & 1u) v += NEGV;
                    outb[(size_t)m * 512 + o] = f2bf(v);
                } else if constexpr (EPI == 3) {
                    if ((mw[wbase + (uint32_t)m * 16u + (o >> 5)] >> (o & 31)) & 1u) v += NEGV;
                    outf[(size_t)m * 512 + o] = v;
                } else {  // EPI == 1: qkv scatter, natural layouts
                    const int s = o >> 9, hh = (o >> 6) & 7, d = o & 63;
                    const int b = m >> 10, n = m & 1023;
                    const int bh = b * 8 + hh;
                    ushort* dst = (s == 0) ? qb : (s == 1) ? kb : vb;
                    const float scl = (s == 0) ? QSCALE : 1.0f;
                    dst[((size_t)bh * 1024 + n) * 64 + d] = f2bf(v * scl);
                }
            }
        }
    }
}

// ---------------- V transpose: v[bh][n][64] -> vt[bh][d][n], LDS tiled ----------------
__global__ __launch_bounds__(256) void vxpose_k(const ushort* __restrict__ v,
                                                ushort* __restrict__ vt)
{
    __shared__ ushort tile[64][72];
    const int tid = threadIdx.x;
    const int bh = blockIdx.y, n0 = blockIdx.x * 64;
    const int row = tid >> 2, cq = (tid & 3) * 16;
    const ushort* src = v + ((size_t)bh * 1024 + n0 + row) * 64 + cq;
    *(u16x8*)&tile[row][cq] = *(const u16x8*)src;
    *(u16x8*)&tile[row][cq + 8] = *(const u16x8*)(src + 8);
    __syncthreads();
    const int d = tid >> 2, nq = (tid & 3) * 16;
    u16x8 o0v, o1v;
#pragma unroll
    for (int i = 0; i < 8; ++i) o0v[i] = tile[nq + i][d];
#pragma unroll
    for (int i = 0; i < 8; ++i) o1v[i] = tile[nq + 8 + i][d];
    ushort* dst = vt + ((size_t)bh * 64 + d) * 1024 + n0 + nq;
    *(u16x8*)dst = o0v;
    *(u16x8*)(dst + 8) = o1v;
}

// ---------------- LayerNorm (LN1): bf16 in, one wave per token, bf16 out ----------------
__global__ __launch_bounds__(256) void ln_k(const ushort* __restrict__ in,
                                            const float* __restrict__ g,
                                            const float* __restrict__ bb,
                                            ushort* __restrict__ outb)
{
    const int wave = threadIdx.x >> 6, lane = threadIdx.x & 63;
    const size_t tok = (size_t)blockIdx.x * 4 + wave;
    const ushort* row = in + tok * 512;
    const int c0 = lane * 8;
    u16x8 vv = *(const u16x8*)(row + c0);
    float x[8];
#pragma unroll
    for (int i = 0; i < 8; i++) x[i] = bf2f(vv[i]);
    float s = 0.f;
#pragma unroll
    for (int i = 0; i < 8; i++) s += x[i];
#pragma unroll
    for (int sh = 32; sh; sh >>= 1) s += __shfl_xor(s, sh, 64);
    const float mu = s * (1.0f / 512.0f);
    float vsum = 0.f;
#pragma unroll
    for (int i = 0; i < 8; i++) { float d = x[i] - mu; vsum += d * d; }
#pragma unroll
    for (int sh = 32; sh; sh >>= 1) vsum += __shfl_xor(vsum, sh, 64);
    const float inv = 1.0f / sqrtf(vsum * (1.0f / 512.0f) + 1e-5f);
    float4 g0 = *(const float4*)(g + c0);
    float4 g1 = *(const float4*)(g + c0 + 4);
    float4 b0 = *(const float4*)(bb + c0);
    float4 b1 = *(const float4*)(bb + c0 + 4);
    float gg[8] = {g0.x, g0.y, g0.z, g0.w, g1.x, g1.y, g1.z, g1.w};
    float bv[8] = {b0.x, b0.y, b0.z, b0.w, b1.x, b1.y, b1.z, b1.w};
    u16x8 o;
#pragma unroll
    for (int i = 0; i < 8; i++) o[i] = f2bf((x[i] - mu) * inv * gg[i] + bv[i]);
    *(u16x8*)(outb + tok * 512 + c0) = o;
}

// ---------------- LN2 + token-partial-sum fused ----------------
__global__ __launch_bounds__(256) void ln2mean_k(const float* __restrict__ in,
                                                 const float* __restrict__ g,
                                                 const float* __restrict__ bb,
                                                 float* __restrict__ pblock)
{
    __shared__ float rows[4][512];
    const int wave = threadIdx.x >> 6, lane = threadIdx.x & 63;
    const int b = blockIdx.x >> 8;
    const size_t tok = (size_t)b * 1024 + (blockIdx.x & 255) * 4 + wave;
    const float* row = in + tok * 512;
    const int c0 = lane * 8;
    float4 v0 = *(const float4*)(row + c0);
    float4 v1 = *(const float4*)(row + c0 + 4);
    float x[8] = {v0.x, v0.y, v0.z, v0.w, v1.x, v1.y, v1.z, v1.w};
    float s = 0.f;
#pragma unroll
    for (int i = 0; i < 8; i++) s += x[i];
#pragma unroll
    for (int sh = 32; sh; sh >>= 1) s += __shfl_xor(s, sh, 64);
    const float mu = s * (1.0f / 512.0f);
    float vsum = 0.f;
#pragma unroll
    for (int i = 0; i < 8; i++) { float d = x[i] - mu; vsum += d * d; }
#pragma unroll
    for (int sh = 32; sh; sh >>= 1) vsum += __shfl_xor(vsum, sh, 64);
    const float inv = 1.0f / sqrtf(vsum * (1.0f / 512.0f) + 1e-5f);
    float4 g0 = *(const float4*)(g + c0);
    float4 g1 = *(const float4*)(g + c0 + 4);
    float4 b0 = *(const float4*)(bb + c0);
    float4 b1 = *(const float4*)(bb + c0 + 4);
    float gg[8] = {g0.x, g0.y, g0.z, g0.w, g1.x, g1.y, g1.z, g1.w};
    float bv[8] = {b0.x, b0.y, b0.z, b0.w, b1.x, b1.y, b1.z, b1.w};
    float o[8];
#pragma unroll
    for (int i = 0; i < 8; i++) o[i] = (x[i] - mu) * inv * gg[i] + bv[i];
    *(float4*)&rows[wave][c0]     = make_float4(o[0], o[1], o[2], o[3]);
    *(float4*)&rows[wave][c0 + 4] = make_float4(o[4], o[5], o[6], o[7]);
    __syncthreads();
    const int c = threadIdx.x;
    float p0 = rows[0][c] + rows[1][c] + rows[2][c] + rows[3][c];
    float p1 = rows[0][c + 256] + rows[1][c + 256] + rows[2][c + 256] + rows[3][c + 256];
    pblock[(size_t)blockIdx.x * 512 + c] = p0;
    pblock[(size_t)blockIdx.x * 512 + c + 256] = p1;
}

// reduce pblock -> tm[b][c] (mean over 1024 tokens)
__global__ __launch_bounds__(256) void mred_k(const float* __restrict__ pblock,
                                              float* __restrict__ tm)
{
    __shared__ float red[8][33];
    const int c0 = blockIdx.x * 32, b = blockIdx.y;
    const int cl = threadIdx.x & 31, jg = threadIdx.x >> 5;
    const float* p = pblock + ((size_t)b * 256 + jg * 32) * 512 + c0 + cl;
    float s = 0.f;
#pragma unroll 8
    for (int j = 0; j < 32; ++j) s += p[(size_t)j * 512];
    red[jg][cl] = s;
    __syncthreads();
    if (jg == 0) {
        float t = 0.f;
#pragma unroll
        for (int g2 = 0; g2 < 8; ++g2) t += red[g2][cl];
        tm[b * 512 + c0 + cl] = t * (1.0f / 1024.0f);
    }
}

// ---------------- MFMA bf16 flash attention, precomputed mask bits ----------------
// grid 1024 1-D, bh = id & 63 (XCD-locality: all q-tiles of one bh on one XCD).
// 4 waves; wave owns 16 q rows; fixed-max softmax in exp2 domain.
__global__ __launch_bounds__(256) void attn_k4(
    const ushort* __restrict__ qb, const ushort* __restrict__ kb,
    const ushort* __restrict__ vtb, const uint32_t* __restrict__ mw,
    ushort* __restrict__ ob)
{
    __shared__ ushort plds[4][16][40];
    const int tid = threadIdx.x;
    const int wave = tid >> 6, lane = tid & 63;
    const int bh = blockIdx.x & 63;
    const int qt = blockIdx.x >> 6;
    const int b = bh >> 3, h = bh & 7;
    const int q0 = qt * 64 + wave * 16;
    const int lg = lane >> 4, lc = lane & 15;

    const ushort* qp = qb + (size_t)bh * 65536;

    bf16x8 aq0 = *(const bf16x8*)(qp + (size_t)(q0 + lc) * 64 + lg * 8);
    bf16x8 aq1 = *(const bf16x8*)(qp + (size_t)(q0 + lc) * 64 + 32 + lg * 8);

    f32x4 zero = {0.f, 0.f, 0.f, 0.f};
    f32x4 oacc[4] = {zero, zero, zero, zero};
    float D[4] = {0.f, 0.f, 0.f, 0.f};

    // mask word stream: word = (bh*1024 + q)*32 + ch; rows for this lane-group are
    // q0+lg*4+r -> base + r*32, ch advances by 1 per chunk.
    const uint32_t* mptr = mw + ((size_t)bh * 1024 + q0 + lg * 4) * 32;

    const ushort* krow = kb + (size_t)bh * 65536 + (size_t)lc * 64 + lg * 8;
    const ushort* vrow = vtb + (size_t)bh * 65536 + (size_t)lc * 1024 + lg * 8;

    for (int ch = 0; ch < 32; ++ch) {
        bf16x8 bk00 = *(const bf16x8*)(krow);
        bf16x8 bk01 = *(const bf16x8*)(krow + 32);
        bf16x8 bk10 = *(const bf16x8*)(krow + 1024);
        bf16x8 bk11 = *(const bf16x8*)(krow + 1056);

        f32x4 s0 = __builtin_amdgcn_mfma_f32_16x16x32_bf16(aq0, bk00, zero, 0, 0, 0);
        s0 = __builtin_amdgcn_mfma_f32_16x16x32_bf16(aq1, bk01, s0, 0, 0, 0);
        f32x4 s1 = __builtin_amdgcn_mfma_f32_16x16x32_bf16(aq0, bk10, zero, 0, 0, 0);
        s1 = __builtin_amdgcn_mfma_f32_16x16x32_bf16(aq1, bk11, s1, 0, 0, 0);

        uint32_t wbits[4];
#pragma unroll
        for (int r = 0; r < 4; ++r) wbits[r] = mptr[r * 32];
        mptr += 1;

#pragma unroll
        for (int r = 0; r < 4; ++r) {
            const uint32_t wv = wbits[r];
            const float pv0 = ((wv >> lc) & 1u) ? EXP2(s0[r]) : 0.f;
            const float pv1 = ((wv >> (lc + 16)) & 1u) ? EXP2(s1[r]) : 0.f;
            D[r] += pv0 + pv1;
            uint32_t pk;
            asm("v_cvt_pk_bf16_f32 %0, %1, %2" : "=v"(pk) : "v"(pv0), "v"(pv1));
            plds[wave][lg * 4 + r][lc] = (ushort)pk;
            plds[wave][lg * 4 + r][lc + 16] = (ushort)(pk >> 16);
        }

        bf16x8 pa = *(const bf16x8*)&plds[wave][lc][lg * 8];

#pragma unroll
        for (int dt = 0; dt < 4; ++dt) {
            bf16x8 bv = *(const bf16x8*)(vrow + (size_t)dt * 16384);
            oacc[dt] = __builtin_amdgcn_mfma_f32_16x16x32_bf16(pa, bv, oacc[dt], 0, 0, 0);
        }
        krow += 2048;
        vrow += 32;
    }

#pragma unroll
    for (int r = 0; r < 4; ++r) {
#pragma unroll
        for (int sh = 1; sh < 16; sh <<= 1) D[r] += __shfl_xor(D[r], sh, 64);
    }

#pragma unroll
    for (int r = 0; r < 4; ++r) {
        const int q = q0 + lg * 4 + r;
        const float inv = 1.0f / D[r];
        ushort* orow = ob + ((size_t)b * 1024 + q) * 512 + h * 64;
#pragma unroll
        for (int dt = 0; dt < 4; ++dt) orow[dt * 16 + lc] = f2bf(oacc[dt][r] * inv);
    }
}

// ---------------- final fc ----------------
__global__ __launch_bounds__(256) void fc_k(const float* __restrict__ tm,
                                            const float* __restrict__ w,
                                            const float* __restrict__ bias,
                                            float* __restrict__ outp)
{
    const int b = blockIdx.y;
    const int o = blockIdx.x * 256 + threadIdx.x;
    const float* tr = tm + b * 512;
    const float* wr = w + (size_t)o * 512;
    float s = 0.f;
    for (int k = 0; k < 512; k += 4) {
        float4 a = *(const float4*)(tr + k);
        float4 ww = *(const float4*)(wr + k);
        s = fmaf(a.x, ww.x, s); s = fmaf(a.y, ww.y, s);
        s = fmaf(a.z, ww.z, s); s = fmaf(a.w, ww.w, s);
    }
    outp[b * 2560 + o] = s + bias[o];
}

// ---------------- launch ----------------
extern "C" void kernel_launch(void* const* d_in, const int* in_sizes, int n_in,
                              void* d_out, int out_size, void* d_ws, size_t ws_size,
                              hipStream_t stream)
{
    const float* x      = (const float*)d_in[0];
    const float* conv_w = (const float*)d_in[1];
    const float* conv_b = (const float*)d_in[2];
    const float* ln_g   = (const float*)d_in[3];
    const float* ln_b   = (const float*)d_in[4];
    const float* qkv_w  = (const float*)d_in[5];
    const float* qkv_b  = (const float*)d_in[6];
    const float* proj_w = (const float*)d_in[7];
    const float* proj_b = (const float*)d_in[8];
    const float* w1     = (const float*)d_in[9];
    const float* b1     = (const float*)d_in[10];
    const float* w2     = (const float*)d_in[11];
    const float* b2     = (const float*)d_in[12];
    const float* fc_w   = (const float*)d_in[13];
    const float* fc_b   = (const float*)d_in[14];
    float* out = (float*)d_out;

    if (ws_size < (size_t)83886080) return;  // need 80 MiB scratch

    uint32_t mk0a, mk0b, mk1a, mk1b, mk2a, mk2b;
    tf2x32_host(0u, 42u, 0u, 0u, &mk0a, &mk0b);
    tf2x32_host(0u, 42u, 0u, 1u, &mk1a, &mk1b);
    tf2x32_host(0u, 42u, 0u, 2u, &mk2a, &mk2b);
    const uint32_t T_m1 = maskT(0.3f);
    const uint32_t T_m2 = maskT(0.1f);

    char* wsb = (char*)d_ws;
    ushort* xt     = (ushort*)wsb;                   // 8 MiB @0     -> obuf
    ushort* wts    = (ushort*)(wsb + 8388608);       // 3.5MiB @8M
    ushort* qbuf   = (ushort*)(wsb + 12582912);      // 8 MiB @12M   -> hbuf
    ushort* kbuf   = (ushort*)(wsb + 20971520);      // 8 MiB @20M   -> pblock+tm
    ushort* vbuf   = (ushort*)(wsb + 29360128);      // 8 MiB @28M
    ushort* vtbuf  = (ushort*)(wsb + 37748736);      // 8 MiB @36M
    ushort* convbf = (ushort*)(wsb + 46137344);      // 8 MiB @44M   (conv bf16 out)
    float*  t2     = (float*)(wsb + 46137344);       // 16 MiB @44M  (w2 out, later)
    ushort* ln1bf  = (ushort*)(wsb + 62914560);      // 8 MiB @60M   -> projbf
    uint32_t* mwds = (uint32_t*)(wsb + 71303168);    // 9.4 MiB @68M (mask bits)
    ushort* obuf   = xt;
    ushort* projbf = ln1bf;
    ushort* hbuf   = qbuf;
    float*  pblock = (float*)(wsb + 20971520);       // 4 MiB
    float*  tm     = (float*)(wsb + 25165824);       // 16 KiB

    ushort* wconv = wts;
    ushort* wqkv  = wts + 262144;
    ushort* wproj = wts + 1048576;
    ushort* ww1   = wts + 1310720;
    ushort* ww2   = wts + 1572864;

    dim3 blk(256);
    // all mask bits (threefry isolated)
    mask_k<<<dim3(4608), blk, 0, stream>>>(mwds, mk0a, mk0b, mk1a, mk1b, mk2a, mk2b,
                                           T_m1, T_m2);
    // x -> xt bf16 [8192][512]
    xpose_k<<<dim3(16, 8, 8), blk, 0, stream>>>(x, xt);
    // weights -> bf16
    wcvt_k<<<dim3(896), blk, 0, stream>>>(conv_w, qkv_w, proj_w, w1, w2, wts);
    // conv -> convbf bf16
    bgemm_k<16, 4><<<dim3(128, 8), blk, 0, stream>>>(xt, wconv, conv_b, nullptr, convbf,
                                                     nullptr, nullptr, nullptr, nullptr, 0u);
    // LN1 (bf16 in) -> ln1bf
    ln_k<<<dim3(2048), blk, 0, stream>>>(convbf, ln_g, ln_b, ln1bf);
    // qkv -> q (exp2-prescaled) / k / v natural bf16
    bgemm_k<32, 1><<<dim3(64, 24), blk, 0, stream>>>(ln1bf, wqkv, qkv_b, nullptr, nullptr,
                                                     qbuf, kbuf, vbuf, nullptr, 0u);
    // v -> vt
    vxpose_k<<<dim3(16, 64), blk, 0, stream>>>(vbuf, vtbuf);
    // attention (mask bits) -> obuf bf16
    attn_k4<<<dim3(1024), blk, 0, stream>>>(qbuf, kbuf, vtbuf, mwds, obuf);
    // proj -> projbf bf16
    bgemm_k<16, 4><<<dim3(128, 8), blk, 0, stream>>>(obuf, wproj, proj_b, nullptr, projbf,
                                                     nullptr, nullptr, nullptr, nullptr, 0u);
    // w1 + gelu + m1-bit -> hbuf bf16
    bgemm_k<16, 2><<<dim3(128, 8), blk, 0, stream>>>(projbf, ww1, b1, nullptr, hbuf,
                                                     nullptr, nullptr, nullptr, mwds, M1_BASE);
    // w2 + m2-bit -> t2 fp32
    bgemm_k<16, 3><<<dim3(128, 8), blk, 0, stream>>>(hbuf, ww2, b2, t2, nullptr,
                                                     nullptr, nullptr, nullptr, mwds, M2_BASE);
    // LN2 + token partial sums
    ln2mean_k<<<dim3(2048), blk, 0, stream>>>(t2, ln_g, ln_b, pblock);
    // reduce partials -> tm
    mred_k<<<dim3(16, 8), blk, 0, stream>>>(pblock, tm);
    // fc -> out
    fc_k<<<dim3(10, 8), blk, 0, stream>>>(tm, fc_w, fc_b, out);
}

// Round 7
// 357.545 us; speedup vs baseline: 1.4450x; 1.4450x over previous
//
#include <hip/hip_runtime.h>
#include <stdint.h>
#include <math.h>

#define NEGV -1.0e12f
// Q pre-scale: 1/sqrt(64) * log2(e)  (softmax uses native exp2)
#define QSCALE 0.18033688011112042f

typedef __attribute__((ext_vector_type(8))) short bf16x8;
typedef __attribute__((ext_vector_type(4))) float f32x4;
typedef __attribute__((ext_vector_type(8))) ushort u16x8;

// 1-instruction rotate (compiler emits v_alignbit for this idiom; keep asm to be sure)
#define ROTL1(v, r) ({ uint32_t _d;                                            \
    asm("v_alignbit_b32 %0, %1, %1, %2" : "=v"(_d) : "v"(v), "n"(32 - (r)));   \
    _d; })

#if defined(__has_builtin)
#if __has_builtin(__builtin_amdgcn_exp2f)
#define EXP2(x) __builtin_amdgcn_exp2f(x)
#endif
#endif
#ifndef EXP2
#define EXP2(x) exp2f(x)
#endif

// ---------------- Threefry-2x32/20, host reference (key derivation) ----------------
__host__ static void tf2x32_host(uint32_t k0, uint32_t k1, uint32_t c0, uint32_t c1,
                                 uint32_t* o0, uint32_t* o1) {
    uint32_t ks2 = k0 ^ k1 ^ 0x1BD11BDAu;
    uint32_t x0 = c0 + k0, x1 = c1 + k1;
#define TF_RND(r) x0 += x1; x1 = ((x1 << (r)) | (x1 >> (32 - (r)))); x1 ^= x0;
    TF_RND(13) TF_RND(15) TF_RND(26) TF_RND(6)
    x0 += k1;  x1 += ks2 + 1u;
    TF_RND(17) TF_RND(29) TF_RND(16) TF_RND(24)
    x0 += ks2; x1 += k0 + 2u;
    TF_RND(13) TF_RND(15) TF_RND(26) TF_RND(6)
    x0 += k0;  x1 += k1 + 3u;
    TF_RND(17) TF_RND(29) TF_RND(16) TF_RND(24)
    x0 += k1;  x1 += ks2 + 4u;
    TF_RND(13) TF_RND(15) TF_RND(26) TF_RND(6)
    x0 += ks2; x1 += k0 + 5u;
#undef TF_RND
    *o0 = x0; *o1 = x1;
}

// device: JAX partitionable random bits for counter (0, j): bits = o0 ^ o1
__device__ __forceinline__ uint32_t tf_bits(uint32_t k0, uint32_t k1, uint32_t j) {
    const uint32_t ks2 = k0 ^ k1 ^ 0x1BD11BDAu;
    uint32_t x0 = k0, x1 = j + k1;
#define TFR(r) x0 += x1; x1 = ROTL1(x1, r); x1 ^= x0;
    TFR(13) TFR(15) TFR(26) TFR(6)
    x0 += k1;  x1 += ks2 + 1u;
    TFR(17) TFR(29) TFR(16) TFR(24)
    x0 += ks2; x1 += k0 + 2u;
    TFR(13) TFR(15) TFR(26) TFR(6)
    x0 += k0;  x1 += k1 + 3u;
    TFR(17) TFR(29) TFR(16) TFR(24)
    x0 += k1;  x1 += ks2 + 4u;
    TFR(13) TFR(15) TFR(26) TFR(6)
#undef TFR
    return (x0 + ks2) ^ (x1 + (k0 + 5u));
}

// bernoulli(p) true  <=>  bits < T,  T = ceil(p * 2^23) << 9  (exact vs JAX float path)
__host__ static uint32_t maskT(float p) {
    double t = ceil((double)p * 8388608.0);
    return ((uint32_t)t) << 9;
}

__device__ __forceinline__ ushort f2bf(float x) {
    uint32_t u = __float_as_uint(x);
    u += 0x7fffu + ((u >> 16) & 1u);
    return (ushort)(u >> 16);
}
__device__ __forceinline__ float bf2f(ushort u) {
    return __uint_as_float(((uint32_t)u) << 16);
}

// ---------------- prep: xpose (blocks 0..1023) + weight convert (1024..1919) --------
// xpose: x[b][c][n] fp32 -> xt[b*1024+n][c] bf16
__global__ __launch_bounds__(256) void prep_k(const float* __restrict__ x,
                                              ushort* __restrict__ xt,
                                              const float* __restrict__ s0,
                                              const float* __restrict__ s1,
                                              const float* __restrict__ s2,
                                              const float* __restrict__ s3,
                                              const float* __restrict__ s4,
                                              ushort* __restrict__ wdst)
{
    __shared__ float tile[64][65];
    const int tid = threadIdx.x;
    if (blockIdx.x < 1024) {
        const int id = blockIdx.x;
        const int n0 = (id & 15) * 64, c0 = ((id >> 4) & 7) * 64, b = id >> 7;
        const float* src = x + ((size_t)b * 512 + c0) * 1024 + n0;
#pragma unroll
        for (int i = 0; i < 4; ++i) {
            const int r = (tid >> 4) + i * 16;
            const int col = (tid & 15) * 4;
            float4 v = *(const float4*)(src + (size_t)r * 1024 + col);
            tile[r][col + 0] = v.x; tile[r][col + 1] = v.y;
            tile[r][col + 2] = v.z; tile[r][col + 3] = v.w;
        }
        __syncthreads();
#pragma unroll
        for (int i = 0; i < 2; ++i) {
            const int nl = (tid >> 3) + i * 32;
            const int cb = (tid & 7) * 8;
            u16x8 o;
#pragma unroll
            for (int j = 0; j < 8; ++j) o[j] = f2bf(tile[cb + j][nl]);
            *(u16x8*)(xt + ((size_t)b * 1024 + n0 + nl) * 512 + c0 + cb) = o;
        }
    } else {
        const size_t i = ((size_t)(blockIdx.x - 1024) * 256 + tid) * 8;
        const float* src; size_t off;
        if (i < 262144)       { src = s0; off = 0; }
        else if (i < 1048576) { src = s1; off = 262144; }
        else if (i < 1310720) { src = s2; off = 1048576; }
        else if (i < 1572864) { src = s3; off = 1310720; }
        else                  { src = s4; off = 1572864; }
        const float* p = src + (i - off);
        float4 a = *(const float4*)p;
        float4 b = *(const float4*)(p + 4);
        u16x8 o;
        o[0] = f2bf(a.x); o[1] = f2bf(a.y); o[2] = f2bf(a.z); o[3] = f2bf(a.w);
        o[4] = f2bf(b.x); o[5] = f2bf(b.y); o[6] = f2bf(b.z); o[7] = f2bf(b.w);
        *(u16x8*)(wdst + i) = o;
    }
}

// ---------------- bf16 MFMA GEMM: C[m][o] = sum_k A[m][k]*W[o][k] + bias[o] ---------
// A [M][512] bf16, W [O][512] bf16. Block = 4 waves stacked in m; wave tile 32x64.
// EPI 1: qkv scatter  2: gelu + m1 threefry -> bf16  3: m2 threefry -> fp32  4: bf16
template<int EPI>
__global__ __launch_bounds__(256) void bgemm_k(
    const ushort* __restrict__ A, const ushort* __restrict__ W,
    const float* __restrict__ bias, float* __restrict__ outf,
    ushort* __restrict__ outb,
    ushort* __restrict__ qb, ushort* __restrict__ kb, ushort* __restrict__ vb,
    uint32_t mkk0, uint32_t mkk1, uint32_t T)
{
    const int tid = threadIdx.x;
    const int wave = tid >> 6, lane = tid & 63;
    const int lg = lane >> 4, lc = lane & 15;
    const int m0 = blockIdx.x * 128 + wave * 32;
    const int o0 = blockIdx.y * 64;

    f32x4 acc[2][4];
#pragma unroll
    for (int i = 0; i < 2; ++i)
#pragma unroll
        for (int j = 0; j < 4; ++j) acc[i][j] = (f32x4){0.f, 0.f, 0.f, 0.f};

    const ushort* Ab = A + (size_t)(m0 + lc) * 512 + lg * 8;
    const ushort* Wb = W + (size_t)(o0 + lc) * 512 + lg * 8;

#pragma unroll 4
    for (int k0 = 0; k0 < 512; k0 += 32) {
        bf16x8 aq[2], bw[4];
        aq[0] = *(const bf16x8*)(Ab + k0);
        aq[1] = *(const bf16x8*)(Ab + 16 * 512 + k0);
#pragma unroll
        for (int j = 0; j < 4; ++j) bw[j] = *(const bf16x8*)(Wb + (size_t)j * 16 * 512 + k0);
#pragma unroll
        for (int i = 0; i < 2; ++i)
#pragma unroll
            for (int j = 0; j < 4; ++j)
                acc[i][j] = __builtin_amdgcn_mfma_f32_16x16x32_bf16(aq[i], bw[j], acc[i][j], 0, 0, 0);
    }

    float bvv[4];
#pragma unroll
    for (int j = 0; j < 4; ++j) bvv[j] = bias[o0 + j * 16 + lc];

#pragma unroll
    for (int i = 0; i < 2; ++i) {
#pragma unroll
        for (int j = 0; j < 4; ++j) {
#pragma unroll
            for (int r = 0; r < 4; ++r) {
                const int m = m0 + i * 16 + lg * 4 + r;
                const int o = o0 + j * 16 + lc;
                float v = acc[i][j][r] + bvv[j];
                if constexpr (EPI == 4) {
                    outb[(size_t)m * 512 + o] = f2bf(v);
                } else if constexpr (EPI == 2) {
                    v = 0.5f * v * (1.0f + erff(v * 0.70710678118654752f));
                    if (tf_bits(mkk0, mkk1, (uint32_t)(m * 512 + o)) < T) v += NEGV;
                    outb[(size_t)m * 512 + o] = f2bf(v);
                } else if constexpr (EPI == 3) {
                    if (tf_bits(mkk0, mkk1, (uint32_t)(m * 512 + o)) < T) v += NEGV;
                    outf[(size_t)m * 512 + o] = v;
                } else {  // EPI == 1: qkv scatter, natural layouts
                    const int s = o >> 9, hh = (o >> 6) & 7, d = o & 63;
                    const int b = m >> 10, n = m & 1023;
                    const int bh = b * 8 + hh;
                    ushort* dst = (s == 0) ? qb : (s == 1) ? kb : vb;
                    const float scl = (s == 0) ? QSCALE : 1.0f;
                    dst[((size_t)bh * 1024 + n) * 64 + d] = f2bf(v * scl);
                }
            }
        }
    }
}

// ---------------- V transpose: v[bh][n][64] -> vt[bh][d][n], LDS tiled ----------------
__global__ __launch_bounds__(256) void vxpose_k(const ushort* __restrict__ v,
                                                ushort* __restrict__ vt)
{
    __shared__ ushort tile[64][72];
    const int tid = threadIdx.x;
    const int bh = blockIdx.y, n0 = blockIdx.x * 64;
    const int row = tid >> 2, cq = (tid & 3) * 16;
    const ushort* src = v + ((size_t)bh * 1024 + n0 + row) * 64 + cq;
    *(u16x8*)&tile[row][cq] = *(const u16x8*)src;
    *(u16x8*)&tile[row][cq + 8] = *(const u16x8*)(src + 8);
    __syncthreads();
    const int d = tid >> 2, nq = (tid & 3) * 16;
    u16x8 o0v, o1v;
#pragma unroll
    for (int i = 0; i < 8; ++i) o0v[i] = tile[nq + i][d];
#pragma unroll
    for (int i = 0; i < 8; ++i) o1v[i] = tile[nq + 8 + i][d];
    ushort* dst = vt + ((size_t)bh * 64 + d) * 1024 + n0 + nq;
    *(u16x8*)dst = o0v;
    *(u16x8*)(dst + 8) = o1v;
}

// ---------------- LayerNorm (LN1): bf16 in, one wave per token, bf16 out ----------------
__global__ __launch_bounds__(256) void ln_k(const ushort* __restrict__ in,
                                            const float* __restrict__ g,
                                            const float* __restrict__ bb,
                                            ushort* __restrict__ outb)
{
    const int wave = threadIdx.x >> 6, lane = threadIdx.x & 63;
    const size_t tok = (size_t)blockIdx.x * 4 + wave;
    const ushort* row = in + tok * 512;
    const int c0 = lane * 8;
    u16x8 vv = *(const u16x8*)(row + c0);
    float x[8];
#pragma unroll
    for (int i = 0; i < 8; i++) x[i] = bf2f(vv[i]);
    float s = 0.f;
#pragma unroll
    for (int i = 0; i < 8; i++) s += x[i];
#pragma unroll
    for (int sh = 32; sh; sh >>= 1) s += __shfl_xor(s, sh, 64);
    const float mu = s * (1.0f / 512.0f);
    float vsum = 0.f;
#pragma unroll
    for (int i = 0; i < 8; i++) { float d = x[i] - mu; vsum += d * d; }
#pragma unroll
    for (int sh = 32; sh; sh >>= 1) vsum += __shfl_xor(vsum, sh, 64);
    const float inv = 1.0f / sqrtf(vsum * (1.0f / 512.0f) + 1e-5f);
    float4 g0 = *(const float4*)(g + c0);
    float4 g1 = *(const float4*)(g + c0 + 4);
    float4 b0 = *(const float4*)(bb + c0);
    float4 b1 = *(const float4*)(bb + c0 + 4);
    float gg[8] = {g0.x, g0.y, g0.z, g0.w, g1.x, g1.y, g1.z, g1.w};
    float bv[8] = {b0.x, b0.y, b0.z, b0.w, b1.x, b1.y, b1.z, b1.w};
    u16x8 o;
#pragma unroll
    for (int i = 0; i < 8; i++) o[i] = f2bf((x[i] - mu) * inv * gg[i] + bv[i]);
    *(u16x8*)(outb + tok * 512 + c0) = o;
}

// ---------------- LN2 + token-partial-sum fused ----------------
__global__ __launch_bounds__(256) void ln2mean_k(const float* __restrict__ in,
                                                 const float* __restrict__ g,
                                                 const float* __restrict__ bb,
                                                 float* __restrict__ pblock)
{
    __shared__ float rows[4][512];
    const int wave = threadIdx.x >> 6, lane = threadIdx.x & 63;
    const int b = blockIdx.x >> 8;
    const size_t tok = (size_t)b * 1024 + (blockIdx.x & 255) * 4 + wave;
    const float* row = in + tok * 512;
    const int c0 = lane * 8;
    float4 v0 = *(const float4*)(row + c0);
    float4 v1 = *(const float4*)(row + c0 + 4);
    float x[8] = {v0.x, v0.y, v0.z, v0.w, v1.x, v1.y, v1.z, v1.w};
    float s = 0.f;
#pragma unroll
    for (int i = 0; i < 8; i++) s += x[i];
#pragma unroll
    for (int sh = 32; sh; sh >>= 1) s += __shfl_xor(s, sh, 64);
    const float mu = s * (1.0f / 512.0f);
    float vsum = 0.f;
#pragma unroll
    for (int i = 0; i < 8; i++) { float d = x[i] - mu; vsum += d * d; }
#pragma unroll
    for (int sh = 32; sh; sh >>= 1) vsum += __shfl_xor(vsum, sh, 64);
    const float inv = 1.0f / sqrtf(vsum * (1.0f / 512.0f) + 1e-5f);
    float4 g0 = *(const float4*)(g + c0);
    float4 g1 = *(const float4*)(g + c0 + 4);
    float4 b0 = *(const float4*)(bb + c0);
    float4 b1 = *(const float4*)(bb + c0 + 4);
    float gg[8] = {g0.x, g0.y, g0.z, g0.w, g1.x, g1.y, g1.z, g1.w};
    float bv[8] = {b0.x, b0.y, b0.z, b0.w, b1.x, b1.y, b1.z, b1.w};
    float o[8];
#pragma unroll
    for (int i = 0; i < 8; i++) o[i] = (x[i] - mu) * inv * gg[i] + bv[i];
    *(float4*)&rows[wave][c0]     = make_float4(o[0], o[1], o[2], o[3]);
    *(float4*)&rows[wave][c0 + 4] = make_float4(o[4], o[5], o[6], o[7]);
    __syncthreads();
    const int c = threadIdx.x;
    float p0 = rows[0][c] + rows[1][c] + rows[2][c] + rows[3][c];
    float p1 = rows[0][c + 256] + rows[1][c + 256] + rows[2][c + 256] + rows[3][c + 256];
    pblock[(size_t)blockIdx.x * 512 + c] = p0;
    pblock[(size_t)blockIdx.x * 512 + c + 256] = p1;
}

// reduce pblock -> tm[b][c] (mean over 1024 tokens)
__global__ __launch_bounds__(256) void mred_k(const float* __restrict__ pblock,
                                              float* __restrict__ tm)
{
    __shared__ float red[8][33];
    const int c0 = blockIdx.x * 32, b = blockIdx.y;
    const int cl = threadIdx.x & 31, jg = threadIdx.x >> 5;
    const float* p = pblock + ((size_t)b * 256 + jg * 32) * 512 + c0 + cl;
    float s = 0.f;
#pragma unroll 8
    for (int j = 0; j < 32; ++j) s += p[(size_t)j * 512];
    red[jg][cl] = s;
    __syncthreads();
    if (jg == 0) {
        float t = 0.f;
#pragma unroll
        for (int g2 = 0; g2 < 8; ++g2) t += red[g2][cl];
        tm[b * 512 + c0 + cl] = t * (1.0f / 1024.0f);
    }
}

// ---------------- MFMA bf16 flash attention, threefry fused, XCD-local grid ---------
// grid 1024 1-D: bh = id & 63 (all q-tiles of one bh land on one XCD), qt = id >> 6.
// 4 waves; wave owns 16 q rows; fixed-max softmax in exp2 domain.
__global__ __launch_bounds__(256) void attn_k(
    const ushort* __restrict__ qb, const ushort* __restrict__ kb,
    const ushort* __restrict__ vtb, ushort* __restrict__ ob,
    uint32_t km0, uint32_t km1)
{
    __shared__ ushort plds[4][16][40];
    const int tid = threadIdx.x;
    const int wave = tid >> 6, lane = tid & 63;
    const int bh = blockIdx.x & 63;
    const int qt = blockIdx.x >> 6;
    const int b = bh >> 3, h = bh & 7;
    const int q0 = qt * 64 + wave * 16;
    const int lg = lane >> 4, lc = lane & 15;

    const ushort* qp = qb + (size_t)bh * 65536;

    bf16x8 aq0 = *(const bf16x8*)(qp + (size_t)(q0 + lc) * 64 + lg * 8);
    bf16x8 aq1 = *(const bf16x8*)(qp + (size_t)(q0 + lc) * 64 + 32 + lg * 8);

    f32x4 zero = {0.f, 0.f, 0.f, 0.f};
    f32x4 oacc[4] = {zero, zero, zero, zero};
    float D[4] = {0.f, 0.f, 0.f, 0.f};

    uint32_t jr[4];
#pragma unroll
    for (int r = 0; r < 4; ++r)
        jr[r] = ((uint32_t)bh * 1024u + (uint32_t)(q0 + lg * 4 + r)) * 1024u + (uint32_t)lc;

    const ushort* krow = kb + (size_t)bh * 65536 + (size_t)lc * 64 + lg * 8;
    const ushort* vrow = vtb + (size_t)bh * 65536 + (size_t)lc * 1024 + lg * 8;

    for (int ch = 0; ch < 32; ++ch) {
        bf16x8 bk00 = *(const bf16x8*)(krow);
        bf16x8 bk01 = *(const bf16x8*)(krow + 32);
        bf16x8 bk10 = *(const bf16x8*)(krow + 1024);
        bf16x8 bk11 = *(const bf16x8*)(krow + 1056);

        f32x4 s0 = __builtin_amdgcn_mfma_f32_16x16x32_bf16(aq0, bk00, zero, 0, 0, 0);
        s0 = __builtin_amdgcn_mfma_f32_16x16x32_bf16(aq1, bk01, s0, 0, 0, 0);
        f32x4 s1 = __builtin_amdgcn_mfma_f32_16x16x32_bf16(aq0, bk10, zero, 0, 0, 0);
        s1 = __builtin_amdgcn_mfma_f32_16x16x32_bf16(aq1, bk11, s1, 0, 0, 0);

#pragma unroll
        for (int r = 0; r < 4; ++r) {
            const uint32_t bits0 = tf_bits(km0, km1, jr[r]);
            const uint32_t bits1 = tf_bits(km0, km1, jr[r] + 16u);
            jr[r] += 32u;
            // keep <=> top bit set (u >= 0.5); masked -> P contribution 0
            const float pv0 = ((int)bits0 < 0) ? EXP2(s0[r]) : 0.f;
            const float pv1 = ((int)bits1 < 0) ? EXP2(s1[r]) : 0.f;
            D[r] += pv0 + pv1;
            uint32_t pk;
            asm("v_cvt_pk_bf16_f32 %0, %1, %2" : "=v"(pk) : "v"(pv0), "v"(pv1));
            plds[wave][lg * 4 + r][lc] = (ushort)pk;
            plds[wave][lg * 4 + r][lc + 16] = (ushort)(pk >> 16);
        }

        bf16x8 pa = *(const bf16x8*)&plds[wave][lc][lg * 8];

#pragma unroll
        for (int dt = 0; dt < 4; ++dt) {
            bf16x8 bv = *(const bf16x8*)(vrow + (size_t)dt * 16384);
            oacc[dt] = __builtin_amdgcn_mfma_f32_16x16x32_bf16(pa, bv, oacc[dt], 0, 0, 0);
        }
        krow += 2048;
        vrow += 32;
    }

#pragma unroll
    for (int r = 0; r < 4; ++r) {
#pragma unroll
        for (int sh = 1; sh < 16; sh <<= 1) D[r] += __shfl_xor(D[r], sh, 64);
    }

#pragma unroll
    for (int r = 0; r < 4; ++r) {
        const int q = q0 + lg * 4 + r;
        const float inv = 1.0f / D[r];
        ushort* orow = ob + ((size_t)b * 1024 + q) * 512 + h * 64;
#pragma unroll
        for (int dt = 0; dt < 4; ++dt) orow[dt * 16 + lc] = f2bf(oacc[dt][r] * inv);
    }
}

// ---------------- final fc ----------------
__global__ __launch_bounds__(256) void fc_k(const float* __restrict__ tm,
                                            const float* __restrict__ w,
                                            const float* __restrict__ bias,
                                            float* __restrict__ outp)
{
    const int b = blockIdx.y;
    const int o = blockIdx.x * 256 + threadIdx.x;
    const float* tr = tm + b * 512;
    const float* wr = w + (size_t)o * 512;
    float s = 0.f;
    for (int k = 0; k < 512; k += 4) {
        float4 a = *(const float4*)(tr + k);
        float4 ww = *(const float4*)(wr + k);
        s = fmaf(a.x, ww.x, s); s = fmaf(a.y, ww.y, s);
        s = fmaf(a.z, ww.z, s); s = fmaf(a.w, ww.w, s);
    }
    outp[b * 2560 + o] = s + bias[o];
}

// ---------------- launch ----------------
extern "C" void kernel_launch(void* const* d_in, const int* in_sizes, int n_in,
                              void* d_out, int out_size, void* d_ws, size_t ws_size,
                              hipStream_t stream)
{
    const float* x      = (const float*)d_in[0];
    const float* conv_w = (const float*)d_in[1];
    const float* conv_b = (const float*)d_in[2];
    const float* ln_g   = (const float*)d_in[3];
    const float* ln_b   = (const float*)d_in[4];
    const float* qkv_w  = (const float*)d_in[5];
    const float* qkv_b  = (const float*)d_in[6];
    const float* proj_w = (const float*)d_in[7];
    const float* proj_b = (const float*)d_in[8];
    const float* w1     = (const float*)d_in[9];
    const float* b1     = (const float*)d_in[10];
    const float* w2     = (const float*)d_in[11];
    const float* b2     = (const float*)d_in[12];
    const float* fc_w   = (const float*)d_in[13];
    const float* fc_b   = (const float*)d_in[14];
    float* out = (float*)d_out;

    if (ws_size < (size_t)71303168) return;  // need 68 MiB scratch

    uint32_t mk0a, mk0b, mk1a, mk1b, mk2a, mk2b;
    tf2x32_host(0u, 42u, 0u, 0u, &mk0a, &mk0b);
    tf2x32_host(0u, 42u, 0u, 1u, &mk1a, &mk1b);
    tf2x32_host(0u, 42u, 0u, 2u, &mk2a, &mk2b);
    const uint32_t T_m1 = maskT(0.3f);
    const uint32_t T_m2 = maskT(0.1f);

    char* wsb = (char*)d_ws;
    ushort* xt     = (ushort*)wsb;                   // 8 MiB @0     -> obuf
    ushort* wts    = (ushort*)(wsb + 8388608);       // 3.5MiB @8M
    ushort* qbuf   = (ushort*)(wsb + 12582912);      // 8 MiB @12M   -> hbuf
    ushort* kbuf   = (ushort*)(wsb + 20971520);      // 8 MiB @20M   -> pblock+tm
    ushort* vbuf   = (ushort*)(wsb + 29360128);      // 8 MiB @28M
    ushort* vtbuf  = (ushort*)(wsb + 37748736);      // 8 MiB @36M
    ushort* convbf = (ushort*)(wsb + 46137344);      // 8 MiB @44M
    float*  t2     = (float*)(wsb + 46137344);       // 16 MiB @44M (after convbf dead)
    ushort* ln1bf  = (ushort*)(wsb + 62914560);      // 8 MiB @60M  -> projbf
    ushort* obuf   = xt;
    ushort* projbf = ln1bf;
    ushort* hbuf   = qbuf;
    float*  pblock = (float*)(wsb + 20971520);       // 4 MiB
    float*  tm     = (float*)(wsb + 25165824);       // 16 KiB

    ushort* wconv = wts;
    ushort* wqkv  = wts + 262144;
    ushort* wproj = wts + 1048576;
    ushort* ww1   = wts + 1310720;
    ushort* ww2   = wts + 1572864;

    dim3 blk(256);
    // x transpose + weight convert, one launch
    prep_k<<<dim3(1920), blk, 0, stream>>>(x, xt, conv_w, qkv_w, proj_w, w1, w2, wts);
    // conv -> convbf bf16
    bgemm_k<4><<<dim3(64, 8), blk, 0, stream>>>(xt, wconv, conv_b, nullptr, convbf,
                                                nullptr, nullptr, nullptr, 0u, 0u, 0u);
    // LN1 (bf16 in) -> ln1bf
    ln_k<<<dim3(2048), blk, 0, stream>>>(convbf, ln_g, ln_b, ln1bf);
    // qkv -> q (exp2-prescaled) / k / v natural bf16
    bgemm_k<1><<<dim3(64, 24), blk, 0, stream>>>(ln1bf, wqkv, qkv_b, nullptr, nullptr,
                                                 qbuf, kbuf, vbuf, 0u, 0u, 0u);
    // v -> vt
    vxpose_k<<<dim3(16, 64), blk, 0, stream>>>(vbuf, vtbuf);
    // attention (threefry fused) -> obuf bf16
    attn_k<<<dim3(1024), blk, 0, stream>>>(qbuf, kbuf, vtbuf, obuf, mk0a, mk0b);
    // proj -> projbf bf16
    bgemm_k<4><<<dim3(64, 8), blk, 0, stream>>>(obuf, wproj, proj_b, nullptr, projbf,
                                                nullptr, nullptr, nullptr, 0u, 0u, 0u);
    // w1 + gelu + m1 -> hbuf bf16
    bgemm_k<2><<<dim3(64, 8), blk, 0, stream>>>(projbf, ww1, b1, nullptr, hbuf,
                                                nullptr, nullptr, nullptr, mk1a, mk1b, T_m1);
    // w2 + m2 -> t2 fp32
    bgemm_k<3><<<dim3(64, 8), blk, 0, stream>>>(hbuf, ww2, b2, t2, nullptr,
                                                nullptr, nullptr, nullptr, mk2a, mk2b, T_m2);
    // LN2 + token partial sums
    ln2mean_k<<<dim3(2048), blk, 0, stream>>>(t2, ln_g, ln_b, pblock);
    // reduce partials -> tm
    mred_k<<<dim3(16, 8), blk, 0, stream>>>(pblock, tm);
    // fc -> out
    fc_k<<<dim3(10, 8), blk, 0, stream>>>(tm, fc_w, fc_b, out);
}

// Round 8
// 354.164 us; speedup vs baseline: 1.4588x; 1.0095x over previous
//
#include <hip/hip_runtime.h>
#include <stdint.h>
#include <math.h>

#define NEGV -1.0e12f
// Q pre-scale: 1/sqrt(64) * log2(e)  (softmax uses native exp2)
#define QSCALE 0.18033688011112042f

typedef __attribute__((ext_vector_type(8))) short bf16x8;
typedef __attribute__((ext_vector_type(4))) float f32x4;
typedef __attribute__((ext_vector_type(8))) ushort u16x8;

// 1-instruction rotate
#define ROTL1(v, r) ({ uint32_t _d;                                            \
    asm("v_alignbit_b32 %0, %1, %1, %2" : "=v"(_d) : "v"(v), "n"(32 - (r)));   \
    _d; })

#if defined(__has_builtin)
#if __has_builtin(__builtin_amdgcn_exp2f)
#define EXP2(x) __builtin_amdgcn_exp2f(x)
#endif
#endif
#ifndef EXP2
#define EXP2(x) exp2f(x)
#endif

// ---------------- Threefry-2x32/20, host reference (key derivation) ----------------
__host__ static void tf2x32_host(uint32_t k0, uint32_t k1, uint32_t c0, uint32_t c1,
                                 uint32_t* o0, uint32_t* o1) {
    uint32_t ks2 = k0 ^ k1 ^ 0x1BD11BDAu;
    uint32_t x0 = c0 + k0, x1 = c1 + k1;
#define TF_RND(r) x0 += x1; x1 = ((x1 << (r)) | (x1 >> (32 - (r)))); x1 ^= x0;
    TF_RND(13) TF_RND(15) TF_RND(26) TF_RND(6)
    x0 += k1;  x1 += ks2 + 1u;
    TF_RND(17) TF_RND(29) TF_RND(16) TF_RND(24)
    x0 += ks2; x1 += k0 + 2u;
    TF_RND(13) TF_RND(15) TF_RND(26) TF_RND(6)
    x0 += k0;  x1 += k1 + 3u;
    TF_RND(17) TF_RND(29) TF_RND(16) TF_RND(24)
    x0 += k1;  x1 += ks2 + 4u;
    TF_RND(13) TF_RND(15) TF_RND(26) TF_RND(6)
    x0 += ks2; x1 += k0 + 5u;
#undef TF_RND
    *o0 = x0; *o1 = x1;
}

// device: JAX partitionable random bits for counter (0, j): bits = o0 ^ o1
__device__ __forceinline__ uint32_t tf_bits(uint32_t k0, uint32_t k1, uint32_t j) {
    const uint32_t ks2 = k0 ^ k1 ^ 0x1BD11BDAu;
    uint32_t x0 = k0, x1 = j + k1;
#define TFR(r) x0 += x1; x1 = ROTL1(x1, r); x1 ^= x0;
    TFR(13) TFR(15) TFR(26) TFR(6)
    x0 += k1;  x1 += ks2 + 1u;
    TFR(17) TFR(29) TFR(16) TFR(24)
    x0 += ks2; x1 += k0 + 2u;
    TFR(13) TFR(15) TFR(26) TFR(6)
    x0 += k0;  x1 += k1 + 3u;
    TFR(17) TFR(29) TFR(16) TFR(24)
    x0 += k1;  x1 += ks2 + 4u;
    TFR(13) TFR(15) TFR(26) TFR(6)
#undef TFR
    return (x0 + ks2) ^ (x1 + (k0 + 5u));
}

// bernoulli(p) true  <=>  bits < T,  T = ceil(p * 2^23) << 9  (exact vs JAX float path)
__host__ static uint32_t maskT(float p) {
    double t = ceil((double)p * 8388608.0);
    return ((uint32_t)t) << 9;
}

__device__ __forceinline__ ushort f2bf(float x) {
    uint32_t u = __float_as_uint(x);
    u += 0x7fffu + ((u >> 16) & 1u);
    return (ushort)(u >> 16);
}
__device__ __forceinline__ float bf2f(ushort u) {
    return __uint_as_float(((uint32_t)u) << 16);
}

// ---------------- prep: xpose (blocks 0..1023) + weight convert (1024..1919) --------
__global__ __launch_bounds__(256) void prep_k(const float* __restrict__ x,
                                              ushort* __restrict__ xt,
                                              const float* __restrict__ s0,
                                              const float* __restrict__ s1,
                                              const float* __restrict__ s2,
                                              const float* __restrict__ s3,
                                              const float* __restrict__ s4,
                                              ushort* __restrict__ wdst)
{
    __shared__ float tile[64][65];
    const int tid = threadIdx.x;
    if (blockIdx.x < 1024) {
        const int id = blockIdx.x;
        const int n0 = (id & 15) * 64, c0 = ((id >> 4) & 7) * 64, b = id >> 7;
        const float* src = x + ((size_t)b * 512 + c0) * 1024 + n0;
#pragma unroll
        for (int i = 0; i < 4; ++i) {
            const int r = (tid >> 4) + i * 16;
            const int col = (tid & 15) * 4;
            float4 v = *(const float4*)(src + (size_t)r * 1024 + col);
            tile[r][col + 0] = v.x; tile[r][col + 1] = v.y;
            tile[r][col + 2] = v.z; tile[r][col + 3] = v.w;
        }
        __syncthreads();
#pragma unroll
        for (int i = 0; i < 2; ++i) {
            const int nl = (tid >> 3) + i * 32;
            const int cb = (tid & 7) * 8;
            u16x8 o;
#pragma unroll
            for (int j = 0; j < 8; ++j) o[j] = f2bf(tile[cb + j][nl]);
            *(u16x8*)(xt + ((size_t)b * 1024 + n0 + nl) * 512 + c0 + cb) = o;
        }
    } else {
        const size_t i = ((size_t)(blockIdx.x - 1024) * 256 + tid) * 8;
        const float* src; size_t off;
        if (i < 262144)       { src = s0; off = 0; }
        else if (i < 1048576) { src = s1; off = 262144; }
        else if (i < 1310720) { src = s2; off = 1048576; }
        else if (i < 1572864) { src = s3; off = 1310720; }
        else                  { src = s4; off = 1572864; }
        const float* p = src + (i - off);
        float4 a = *(const float4*)p;
        float4 b = *(const float4*)(p + 4);
        u16x8 o;
        o[0] = f2bf(a.x); o[1] = f2bf(a.y); o[2] = f2bf(a.z); o[3] = f2bf(a.w);
        o[4] = f2bf(b.x); o[5] = f2bf(b.y); o[6] = f2bf(b.z); o[7] = f2bf(b.w);
        *(u16x8*)(wdst + i) = o;
    }
}

// ---------------- bf16 MFMA GEMM (conv & qkv): wave tile 32x64 ----------------
// EPI 1: qkv scatter   EPI 4: bf16 store
template<int EPI>
__global__ __launch_bounds__(256) void bgemm_k(
    const ushort* __restrict__ A, const ushort* __restrict__ W,
    const float* __restrict__ bias,
    ushort* __restrict__ outb,
    ushort* __restrict__ qb, ushort* __restrict__ kb, ushort* __restrict__ vb)
{
    const int tid = threadIdx.x;
    const int wave = tid >> 6, lane = tid & 63;
    const int lg = lane >> 4, lc = lane & 15;
    const int m0 = blockIdx.x * 128 + wave * 32;
    const int o0 = blockIdx.y * 64;

    f32x4 acc[2][4];
#pragma unroll
    for (int i = 0; i < 2; ++i)
#pragma unroll
        for (int j = 0; j < 4; ++j) acc[i][j] = (f32x4){0.f, 0.f, 0.f, 0.f};

    const ushort* Ab = A + (size_t)(m0 + lc) * 512 + lg * 8;
    const ushort* Wb = W + (size_t)(o0 + lc) * 512 + lg * 8;

#pragma unroll 4
    for (int k0 = 0; k0 < 512; k0 += 32) {
        bf16x8 aq[2], bw[4];
        aq[0] = *(const bf16x8*)(Ab + k0);
        aq[1] = *(const bf16x8*)(Ab + 16 * 512 + k0);
#pragma unroll
        for (int j = 0; j < 4; ++j) bw[j] = *(const bf16x8*)(Wb + (size_t)j * 16 * 512 + k0);
#pragma unroll
        for (int i = 0; i < 2; ++i)
#pragma unroll
            for (int j = 0; j < 4; ++j)
                acc[i][j] = __builtin_amdgcn_mfma_f32_16x16x32_bf16(aq[i], bw[j], acc[i][j], 0, 0, 0);
    }

    float bvv[4];
#pragma unroll
    for (int j = 0; j < 4; ++j) bvv[j] = bias[o0 + j * 16 + lc];

#pragma unroll
    for (int i = 0; i < 2; ++i) {
#pragma unroll
        for (int j = 0; j < 4; ++j) {
#pragma unroll
            for (int r = 0; r < 4; ++r) {
                const int m = m0 + i * 16 + lg * 4 + r;
                const int o = o0 + j * 16 + lc;
                float v = acc[i][j][r] + bvv[j];
                if constexpr (EPI == 4) {
                    outb[(size_t)m * 512 + o] = f2bf(v);
                } else {  // EPI == 1: qkv scatter, natural layouts
                    const int s = o >> 9, hh = (o >> 6) & 7, d = o & 63;
                    const int b = m >> 10, n = m & 1023;
                    const int bh = b * 8 + hh;
                    ushort* dst = (s == 0) ? qb : (s == 1) ? kb : vb;
                    const float scl = (s == 0) ? QSCALE : 1.0f;
                    dst[((size_t)bh * 1024 + n) * 64 + d] = f2bf(v * scl);
                }
            }
        }
    }
}

// ---------------- V transpose: v[bh][n][64] -> vt[bh][d][n], LDS tiled ----------------
__global__ __launch_bounds__(256) void vxpose_k(const ushort* __restrict__ v,
                                                ushort* __restrict__ vt)
{
    __shared__ ushort tile[64][72];
    const int tid = threadIdx.x;
    const int bh = blockIdx.y, n0 = blockIdx.x * 64;
    const int row = tid >> 2, cq = (tid & 3) * 16;
    const ushort* src = v + ((size_t)bh * 1024 + n0 + row) * 64 + cq;
    *(u16x8*)&tile[row][cq] = *(const u16x8*)src;
    *(u16x8*)&tile[row][cq + 8] = *(const u16x8*)(src + 8);
    __syncthreads();
    const int d = tid >> 2, nq = (tid & 3) * 16;
    u16x8 o0v, o1v;
#pragma unroll
    for (int i = 0; i < 8; ++i) o0v[i] = tile[nq + i][d];
#pragma unroll
    for (int i = 0; i < 8; ++i) o1v[i] = tile[nq + 8 + i][d];
    ushort* dst = vt + ((size_t)bh * 64 + d) * 1024 + n0 + nq;
    *(u16x8*)dst = o0v;
    *(u16x8*)(dst + 8) = o1v;
}

// ---------------- LayerNorm (LN1): bf16 in, one wave per token, bf16 out ----------------
__global__ __launch_bounds__(256) void ln_k(const ushort* __restrict__ in,
                                            const float* __restrict__ g,
                                            const float* __restrict__ bb,
                                            ushort* __restrict__ outb)
{
    const int wave = threadIdx.x >> 6, lane = threadIdx.x & 63;
    const size_t tok = (size_t)blockIdx.x * 4 + wave;
    const ushort* row = in + tok * 512;
    const int c0 = lane * 8;
    u16x8 vv = *(const u16x8*)(row + c0);
    float x[8];
#pragma unroll
    for (int i = 0; i < 8; i++) x[i] = bf2f(vv[i]);
    float s = 0.f;
#pragma unroll
    for (int i = 0; i < 8; i++) s += x[i];
#pragma unroll
    for (int sh = 32; sh; sh >>= 1) s += __shfl_xor(s, sh, 64);
    const float mu = s * (1.0f / 512.0f);
    float vsum = 0.f;
#pragma unroll
    for (int i = 0; i < 8; i++) { float d = x[i] - mu; vsum += d * d; }
#pragma unroll
    for (int sh = 32; sh; sh >>= 1) vsum += __shfl_xor(vsum, sh, 64);
    const float inv = 1.0f / sqrtf(vsum * (1.0f / 512.0f) + 1e-5f);
    float4 g0 = *(const float4*)(g + c0);
    float4 g1 = *(const float4*)(g + c0 + 4);
    float4 b0 = *(const float4*)(bb + c0);
    float4 b1 = *(const float4*)(bb + c0 + 4);
    float gg[8] = {g0.x, g0.y, g0.z, g0.w, g1.x, g1.y, g1.z, g1.w};
    float bv[8] = {b0.x, b0.y, b0.z, b0.w, b1.x, b1.y, b1.z, b1.w};
    u16x8 o;
#pragma unroll
    for (int i = 0; i < 8; i++) o[i] = f2bf((x[i] - mu) * inv * gg[i] + bv[i]);
    *(u16x8*)(outb + tok * 512 + c0) = o;
}

// ---------------- MEGA: attn + proj + w1(gelu,m1) + w2(m2) + LN2 + token psum -------
// grid 512: b = id&7 (XCD-aligned), tg = id>>3 (16-token group). 8 waves (512 thr).
// Phase 1: wave = head, 16 q rows (R7 attention body). O -> LDS bufA [16][512].
// Phases 2-4: per-wave 16x64 o-tile GEMMs vs L2-hot weights, ping-pong through bufA.
// Phase 5: LN2 via cross-wave stats, token-partial sums -> pblock[(b*64+tg)][512].
__global__ __launch_bounds__(512) void mega_k(
    const ushort* __restrict__ qb, const ushort* __restrict__ kb,
    const ushort* __restrict__ vtb,
    const ushort* __restrict__ wproj, const float* __restrict__ pjb,
    const ushort* __restrict__ ww1, const float* __restrict__ b1v,
    const ushort* __restrict__ ww2, const float* __restrict__ b2v,
    const float* __restrict__ g, const float* __restrict__ bln,
    float* __restrict__ pblock,
    uint32_t km0, uint32_t km1, uint32_t k10, uint32_t k11,
    uint32_t k20, uint32_t k21, uint32_t T1, uint32_t T2)
{
    __shared__ ushort bufA[16][520];       // O -> t -> h (bf16), row stride 1040B (16B mult)
    __shared__ ushort plds[8][16][40];     // per-wave P tiles
    __shared__ float stats[16][8][2];      // LN2 row partials (row, wave, {sum, sumsq})
    const int tid = threadIdx.x;
    const int wave = tid >> 6, lane = tid & 63;
    const int lg = lane >> 4, lc = lane & 15;
    const int b = blockIdx.x & 7, tg = blockIdx.x >> 3;
    const int bh = b * 8 + wave;
    const int q0 = tg * 16;

    // ---- phase 1: attention (head = wave) ----
    const ushort* qp = qb + (size_t)bh * 65536;
    bf16x8 aq0 = *(const bf16x8*)(qp + (size_t)(q0 + lc) * 64 + lg * 8);
    bf16x8 aq1 = *(const bf16x8*)(qp + (size_t)(q0 + lc) * 64 + 32 + lg * 8);

    f32x4 zero = {0.f, 0.f, 0.f, 0.f};
    f32x4 oacc[4] = {zero, zero, zero, zero};
    float D[4] = {0.f, 0.f, 0.f, 0.f};

    uint32_t jr[4];
#pragma unroll
    for (int r = 0; r < 4; ++r)
        jr[r] = ((uint32_t)bh * 1024u + (uint32_t)(q0 + lg * 4 + r)) * 1024u + (uint32_t)lc;

    const ushort* krow = kb + (size_t)bh * 65536 + (size_t)lc * 64 + lg * 8;
    const ushort* vrow = vtb + (size_t)bh * 65536 + (size_t)lc * 1024 + lg * 8;

    for (int ch = 0; ch < 32; ++ch) {
        bf16x8 bk00 = *(const bf16x8*)(krow);
        bf16x8 bk01 = *(const bf16x8*)(krow + 32);
        bf16x8 bk10 = *(const bf16x8*)(krow + 1024);
        bf16x8 bk11 = *(const bf16x8*)(krow + 1056);

        f32x4 s0 = __builtin_amdgcn_mfma_f32_16x16x32_bf16(aq0, bk00, zero, 0, 0, 0);
        s0 = __builtin_amdgcn_mfma_f32_16x16x32_bf16(aq1, bk01, s0, 0, 0, 0);
        f32x4 s1 = __builtin_amdgcn_mfma_f32_16x16x32_bf16(aq0, bk10, zero, 0, 0, 0);
        s1 = __builtin_amdgcn_mfma_f32_16x16x32_bf16(aq1, bk11, s1, 0, 0, 0);

#pragma unroll
        for (int r = 0; r < 4; ++r) {
            const uint32_t bits0 = tf_bits(km0, km1, jr[r]);
            const uint32_t bits1 = tf_bits(km0, km1, jr[r] + 16u);
            jr[r] += 32u;
            const float pv0 = ((int)bits0 < 0) ? EXP2(s0[r]) : 0.f;
            const float pv1 = ((int)bits1 < 0) ? EXP2(s1[r]) : 0.f;
            D[r] += pv0 + pv1;
            uint32_t pk;
            asm("v_cvt_pk_bf16_f32 %0, %1, %2" : "=v"(pk) : "v"(pv0), "v"(pv1));
            plds[wave][lg * 4 + r][lc] = (ushort)pk;
            plds[wave][lg * 4 + r][lc + 16] = (ushort)(pk >> 16);
        }

        bf16x8 pa = *(const bf16x8*)&plds[wave][lc][lg * 8];

#pragma unroll
        for (int dt = 0; dt < 4; ++dt) {
            bf16x8 bv = *(const bf16x8*)(vrow + (size_t)dt * 16384);
            oacc[dt] = __builtin_amdgcn_mfma_f32_16x16x32_bf16(pa, bv, oacc[dt], 0, 0, 0);
        }
        krow += 2048;
        vrow += 32;
    }

#pragma unroll
    for (int r = 0; r < 4; ++r) {
#pragma unroll
        for (int sh = 1; sh < 16; sh <<= 1) D[r] += __shfl_xor(D[r], sh, 64);
    }

    // O -> bufA (bf16), cols = wave's head range
#pragma unroll
    for (int r = 0; r < 4; ++r) {
        const int row = lg * 4 + r;
        const float inv = 1.0f / D[r];
#pragma unroll
        for (int dt = 0; dt < 4; ++dt)
            bufA[row][wave * 64 + dt * 16 + lc] = f2bf(oacc[dt][r] * inv);
    }
    __syncthreads();

    const int o0 = wave * 64;
    const int mg0 = b * 1024 + tg * 16 + lg * 4;   // global token of row r=0

    // ---- phase 2: proj ----
    f32x4 acc[4] = {zero, zero, zero, zero};
    {
        const ushort* Wb = wproj + (size_t)(o0 + lc) * 512 + lg * 8;
#pragma unroll 4
        for (int k0 = 0; k0 < 512; k0 += 32) {
            bf16x8 a0 = *(const bf16x8*)&bufA[lc][k0 + lg * 8];
#pragma unroll
            for (int j = 0; j < 4; ++j) {
                bf16x8 bw = *(const bf16x8*)(Wb + (size_t)j * 16 * 512 + k0);
                acc[j] = __builtin_amdgcn_mfma_f32_16x16x32_bf16(a0, bw, acc[j], 0, 0, 0);
            }
        }
    }
    float bias4[4];
#pragma unroll
    for (int j = 0; j < 4; ++j) bias4[j] = pjb[o0 + j * 16 + lc];
    __syncthreads();   // everyone done reading O
#pragma unroll
    for (int j = 0; j < 4; ++j)
#pragma unroll
        for (int r = 0; r < 4; ++r)
            bufA[lg * 4 + r][o0 + j * 16 + lc] = f2bf(acc[j][r] + bias4[j]);
    __syncthreads();

    // ---- phase 3: w1 + gelu + m1 ----
#pragma unroll
    for (int j = 0; j < 4; ++j) acc[j] = zero;
    {
        const ushort* Wb = ww1 + (size_t)(o0 + lc) * 512 + lg * 8;
#pragma unroll 4
        for (int k0 = 0; k0 < 512; k0 += 32) {
            bf16x8 a0 = *(const bf16x8*)&bufA[lc][k0 + lg * 8];
#pragma unroll
            for (int j = 0; j < 4; ++j) {
                bf16x8 bw = *(const bf16x8*)(Wb + (size_t)j * 16 * 512 + k0);
                acc[j] = __builtin_amdgcn_mfma_f32_16x16x32_bf16(a0, bw, acc[j], 0, 0, 0);
            }
        }
    }
#pragma unroll
    for (int j = 0; j < 4; ++j) bias4[j] = b1v[o0 + j * 16 + lc];
    __syncthreads();   // everyone done reading t
#pragma unroll
    for (int j = 0; j < 4; ++j) {
#pragma unroll
        for (int r = 0; r < 4; ++r) {
            float v = acc[j][r] + bias4[j];
            v = 0.5f * v * (1.0f + erff(v * 0.70710678118654752f));
            const uint32_t jidx = (uint32_t)((mg0 + r) * 512 + o0 + j * 16 + lc);
            if (tf_bits(k10, k11, jidx) < T1) v += NEGV;
            bufA[lg * 4 + r][o0 + j * 16 + lc] = f2bf(v);
        }
    }
    __syncthreads();

    // ---- phase 4: w2 + m2 -> t2 (fp32 regs) ----
#pragma unroll
    for (int j = 0; j < 4; ++j) acc[j] = zero;
    {
        const ushort* Wb = ww2 + (size_t)(o0 + lc) * 512 + lg * 8;
#pragma unroll 4
        for (int k0 = 0; k0 < 512; k0 += 32) {
            bf16x8 a0 = *(const bf16x8*)&bufA[lc][k0 + lg * 8];
#pragma unroll
            for (int j = 0; j < 4; ++j) {
                bf16x8 bw = *(const bf16x8*)(Wb + (size_t)j * 16 * 512 + k0);
                acc[j] = __builtin_amdgcn_mfma_f32_16x16x32_bf16(a0, bw, acc[j], 0, 0, 0);
            }
        }
    }
#pragma unroll
    for (int j = 0; j < 4; ++j) bias4[j] = b2v[o0 + j * 16 + lc];
    float t2v[4][4];
#pragma unroll
    for (int j = 0; j < 4; ++j) {
#pragma unroll
        for (int r = 0; r < 4; ++r) {
            float v = acc[j][r] + bias4[j];
            const uint32_t jidx = (uint32_t)((mg0 + r) * 512 + o0 + j * 16 + lc);
            if (tf_bits(k20, k21, jidx) < T2) v += NEGV;
            t2v[j][r] = v;
        }
    }

    // ---- phase 5: LN2 + token partial sums ----
    float rs[4], rq[4];
#pragma unroll
    for (int r = 0; r < 4; ++r) {
        float s = 0.f, q = 0.f;
#pragma unroll
        for (int j = 0; j < 4; ++j) { s += t2v[j][r]; q += t2v[j][r] * t2v[j][r]; }
#pragma unroll
        for (int sh = 1; sh < 16; sh <<= 1) {
            s += __shfl_xor(s, sh, 64);
            q += __shfl_xor(q, sh, 64);
        }
        rs[r] = s; rq[r] = q;
    }
    if (lc == 0) {
#pragma unroll
        for (int r = 0; r < 4; ++r) {
            stats[lg * 4 + r][wave][0] = rs[r];
            stats[lg * 4 + r][wave][1] = rq[r];
        }
    }
    __syncthreads();
    float mu[4], inv[4];
#pragma unroll
    for (int r = 0; r < 4; ++r) {
        float S = 0.f, S2 = 0.f;
#pragma unroll
        for (int w = 0; w < 8; ++w) { S += stats[lg * 4 + r][w][0]; S2 += stats[lg * 4 + r][w][1]; }
        const float m = S * (1.0f / 512.0f);
        const float var = S2 * (1.0f / 512.0f) - m * m;
        mu[r] = m;
        inv[r] = 1.0f / sqrtf(var + 1e-5f);
    }
    float gld[4], bld[4];
#pragma unroll
    for (int j = 0; j < 4; ++j) {
        gld[j] = g[o0 + j * 16 + lc];
        bld[j] = bln[o0 + j * 16 + lc];
    }
    float ps[4] = {0.f, 0.f, 0.f, 0.f};
#pragma unroll
    for (int j = 0; j < 4; ++j) {
#pragma unroll
        for (int r = 0; r < 4; ++r)
            ps[j] += (t2v[j][r] - mu[r]) * inv[r] * gld[j] + bld[j];
    }
#pragma unroll
    for (int j = 0; j < 4; ++j) {
        ps[j] += __shfl_xor(ps[j], 16, 64);
        ps[j] += __shfl_xor(ps[j], 32, 64);
    }
    if (lg == 0) {
#pragma unroll
        for (int j = 0; j < 4; ++j)
            pblock[((size_t)(b * 64 + tg)) * 512 + o0 + j * 16 + lc] = ps[j];
    }
}

// ---------------- reduce pblock -> tm[b][c] ----------------
__global__ __launch_bounds__(256) void mred2_k(const float* __restrict__ pblock,
                                               float* __restrict__ tm)
{
    const int b = blockIdx.y;
    const int c = blockIdx.x * 256 + threadIdx.x;   // 0..511
    const float* p = pblock + (size_t)b * 64 * 512 + c;
    float s = 0.f;
#pragma unroll 8
    for (int t = 0; t < 64; ++t) s += p[(size_t)t * 512];
    tm[b * 512 + c] = s * (1.0f / 1024.0f);
}

// ---------------- final fc ----------------
__global__ __launch_bounds__(256) void fc_k(const float* __restrict__ tm,
                                            const float* __restrict__ w,
                                            const float* __restrict__ bias,
                                            float* __restrict__ outp)
{
    const int b = blockIdx.y;
    const int o = blockIdx.x * 256 + threadIdx.x;
    const float* tr = tm + b * 512;
    const float* wr = w + (size_t)o * 512;
    float s = 0.f;
    for (int k = 0; k < 512; k += 4) {
        float4 a = *(const float4*)(tr + k);
        float4 ww = *(const float4*)(wr + k);
        s = fmaf(a.x, ww.x, s); s = fmaf(a.y, ww.y, s);
        s = fmaf(a.z, ww.z, s); s = fmaf(a.w, ww.w, s);
    }
    outp[b * 2560 + o] = s + bias[o];
}

// ---------------- launch ----------------
extern "C" void kernel_launch(void* const* d_in, const int* in_sizes, int n_in,
                              void* d_out, int out_size, void* d_ws, size_t ws_size,
                              hipStream_t stream)
{
    const float* x      = (const float*)d_in[0];
    const float* conv_w = (const float*)d_in[1];
    const float* conv_b = (const float*)d_in[2];
    const float* ln_g   = (const float*)d_in[3];
    const float* ln_b   = (const float*)d_in[4];
    const float* qkv_w  = (const float*)d_in[5];
    const float* qkv_b  = (const float*)d_in[6];
    const float* proj_w = (const float*)d_in[7];
    const float* proj_b = (const float*)d_in[8];
    const float* w1     = (const float*)d_in[9];
    const float* b1     = (const float*)d_in[10];
    const float* w2     = (const float*)d_in[11];
    const float* b2     = (const float*)d_in[12];
    const float* fc_w   = (const float*)d_in[13];
    const float* fc_b   = (const float*)d_in[14];
    float* out = (float*)d_out;

    if (ws_size < (size_t)71303168) return;  // need 68 MiB scratch

    uint32_t mk0a, mk0b, mk1a, mk1b, mk2a, mk2b;
    tf2x32_host(0u, 42u, 0u, 0u, &mk0a, &mk0b);
    tf2x32_host(0u, 42u, 0u, 1u, &mk1a, &mk1b);
    tf2x32_host(0u, 42u, 0u, 2u, &mk2a, &mk2b);
    const uint32_t T_m1 = maskT(0.3f);
    const uint32_t T_m2 = maskT(0.1f);

    char* wsb = (char*)d_ws;
    ushort* xt     = (ushort*)wsb;                   // 8 MiB @0
    ushort* wts    = (ushort*)(wsb + 8388608);       // 3.5MiB @8M
    ushort* qbuf   = (ushort*)(wsb + 12582912);      // 8 MiB @12M
    ushort* kbuf   = (ushort*)(wsb + 20971520);      // 8 MiB @20M
    ushort* vbuf   = (ushort*)(wsb + 29360128);      // 8 MiB @28M
    ushort* vtbuf  = (ushort*)(wsb + 37748736);      // 8 MiB @36M
    ushort* convbf = (ushort*)(wsb + 46137344);      // 8 MiB @44M
    ushort* ln1bf  = (ushort*)(wsb + 54525952);      // 8 MiB @52M
    float*  pblock = (float*)(wsb + 62914560);       // 1 MiB @60M
    float*  tm     = (float*)(wsb + 64487424);       // 16 KiB @61.5M

    ushort* wconv = wts;
    ushort* wqkv  = wts + 262144;
    ushort* wproj = wts + 1048576;
    ushort* ww1   = wts + 1310720;
    ushort* ww2   = wts + 1572864;

    dim3 blk(256);
    // x transpose + weight convert
    prep_k<<<dim3(1920), blk, 0, stream>>>(x, xt, conv_w, qkv_w, proj_w, w1, w2, wts);
    // conv -> convbf bf16
    bgemm_k<4><<<dim3(64, 8), blk, 0, stream>>>(xt, wconv, conv_b, convbf,
                                                nullptr, nullptr, nullptr);
    // LN1 -> ln1bf bf16
    ln_k<<<dim3(2048), blk, 0, stream>>>(convbf, ln_g, ln_b, ln1bf);
    // qkv -> q (exp2-prescaled) / k / v natural bf16
    bgemm_k<1><<<dim3(64, 24), blk, 0, stream>>>(ln1bf, wqkv, qkv_b, nullptr,
                                                 qbuf, kbuf, vbuf);
    // v -> vt
    vxpose_k<<<dim3(16, 64), blk, 0, stream>>>(vbuf, vtbuf);
    // MEGA: attn + proj + FF + LN2 + token psum -> pblock
    mega_k<<<dim3(512), dim3(512), 0, stream>>>(qbuf, kbuf, vtbuf,
                                                wproj, proj_b, ww1, b1, ww2, b2,
                                                ln_g, ln_b, pblock,
                                                mk0a, mk0b, mk1a, mk1b, mk2a, mk2b,
                                                T_m1, T_m2);
    // reduce partials -> tm
    mred2_k<<<dim3(2, 8), blk, 0, stream>>>(pblock, tm);
    // fc -> out
    fc_k<<<dim3(10, 8), blk, 0, stream>>>(tm, fc_w, fc_b, out);
}

// Round 9
// 350.523 us; speedup vs baseline: 1.4739x; 1.0104x over previous
//
#include <hip/hip_runtime.h>
#include <stdint.h>
#include <math.h>

#define NEGV -1.0e12f
// Q pre-scale: 1/sqrt(64) * log2(e)  (softmax uses native exp2)
#define QSCALE 0.18033688011112042f

typedef __attribute__((ext_vector_type(8))) short bf16x8;
typedef __attribute__((ext_vector_type(4))) float f32x4;
typedef __attribute__((ext_vector_type(8))) ushort u16x8;

// 1-instruction rotate
#define ROTL1(v, r) ({ uint32_t _d;                                            \
    asm("v_alignbit_b32 %0, %1, %1, %2" : "=v"(_d) : "v"(v), "n"(32 - (r)));   \
    _d; })

#if defined(__has_builtin)
#if __has_builtin(__builtin_amdgcn_exp2f)
#define EXP2(x) __builtin_amdgcn_exp2f(x)
#endif
#endif
#ifndef EXP2
#define EXP2(x) exp2f(x)
#endif

// ---------------- Threefry-2x32/20, host reference (key derivation) ----------------
__host__ static void tf2x32_host(uint32_t k0, uint32_t k1, uint32_t c0, uint32_t c1,
                                 uint32_t* o0, uint32_t* o1) {
    uint32_t ks2 = k0 ^ k1 ^ 0x1BD11BDAu;
    uint32_t x0 = c0 + k0, x1 = c1 + k1;
#define TF_RND(r) x0 += x1; x1 = ((x1 << (r)) | (x1 >> (32 - (r)))); x1 ^= x0;
    TF_RND(13) TF_RND(15) TF_RND(26) TF_RND(6)
    x0 += k1;  x1 += ks2 + 1u;
    TF_RND(17) TF_RND(29) TF_RND(16) TF_RND(24)
    x0 += ks2; x1 += k0 + 2u;
    TF_RND(13) TF_RND(15) TF_RND(26) TF_RND(6)
    x0 += k0;  x1 += k1 + 3u;
    TF_RND(17) TF_RND(29) TF_RND(16) TF_RND(24)
    x0 += k1;  x1 += ks2 + 4u;
    TF_RND(13) TF_RND(15) TF_RND(26) TF_RND(6)
    x0 += ks2; x1 += k0 + 5u;
#undef TF_RND
    *o0 = x0; *o1 = x1;
}

// device: JAX partitionable random bits for counter (0, j): bits = o0 ^ o1
__device__ __forceinline__ uint32_t tf_bits(uint32_t k0, uint32_t k1, uint32_t j) {
    const uint32_t ks2 = k0 ^ k1 ^ 0x1BD11BDAu;
    uint32_t x0 = k0, x1 = j + k1;
#define TFR(r) x0 += x1; x1 = ROTL1(x1, r); x1 ^= x0;
    TFR(13) TFR(15) TFR(26) TFR(6)
    x0 += k1;  x1 += ks2 + 1u;
    TFR(17) TFR(29) TFR(16) TFR(24)
    x0 += ks2; x1 += k0 + 2u;
    TFR(13) TFR(15) TFR(26) TFR(6)
    x0 += k0;  x1 += k1 + 3u;
    TFR(17) TFR(29) TFR(16) TFR(24)
    x0 += k1;  x1 += ks2 + 4u;
    TFR(13) TFR(15) TFR(26) TFR(6)
#undef TFR
    return (x0 + ks2) ^ (x1 + (k0 + 5u));
}

// bernoulli(p) true  <=>  bits < T,  T = ceil(p * 2^23) << 9  (exact vs JAX float path)
__host__ static uint32_t maskT(float p) {
    double t = ceil((double)p * 8388608.0);
    return ((uint32_t)t) << 9;
}

__device__ __forceinline__ ushort f2bf(float x) {
    uint32_t u = __float_as_uint(x);
    u += 0x7fffu + ((u >> 16) & 1u);
    return (ushort)(u >> 16);
}
__device__ __forceinline__ float bf2f(ushort u) {
    return __uint_as_float(((uint32_t)u) << 16);
}

// ---------------- prep: xpose (blocks 0..1023) + weight convert (1024..1919) --------
__global__ __launch_bounds__(256) void prep_k(const float* __restrict__ x,
                                              ushort* __restrict__ xt,
                                              const float* __restrict__ s0,
                                              const float* __restrict__ s1,
                                              const float* __restrict__ s2,
                                              const float* __restrict__ s3,
                                              const float* __restrict__ s4,
                                              ushort* __restrict__ wdst)
{
    __shared__ float tile[64][65];
    const int tid = threadIdx.x;
    if (blockIdx.x < 1024) {
        const int id = blockIdx.x;
        const int n0 = (id & 15) * 64, c0 = ((id >> 4) & 7) * 64, b = id >> 7;
        const float* src = x + ((size_t)b * 512 + c0) * 1024 + n0;
#pragma unroll
        for (int i = 0; i < 4; ++i) {
            const int r = (tid >> 4) + i * 16;
            const int col = (tid & 15) * 4;
            float4 v = *(const float4*)(src + (size_t)r * 1024 + col);
            tile[r][col + 0] = v.x; tile[r][col + 1] = v.y;
            tile[r][col + 2] = v.z; tile[r][col + 3] = v.w;
        }
        __syncthreads();
#pragma unroll
        for (int i = 0; i < 2; ++i) {
            const int nl = (tid >> 3) + i * 32;
            const int cb = (tid & 7) * 8;
            u16x8 o;
#pragma unroll
            for (int j = 0; j < 8; ++j) o[j] = f2bf(tile[cb + j][nl]);
            *(u16x8*)(xt + ((size_t)b * 1024 + n0 + nl) * 512 + c0 + cb) = o;
        }
    } else {
        const size_t i = ((size_t)(blockIdx.x - 1024) * 256 + tid) * 8;
        const float* src; size_t off;
        if (i < 262144)       { src = s0; off = 0; }
        else if (i < 1048576) { src = s1; off = 262144; }
        else if (i < 1310720) { src = s2; off = 1048576; }
        else if (i < 1572864) { src = s3; off = 1310720; }
        else                  { src = s4; off = 1572864; }
        const float* p = src + (i - off);
        float4 a = *(const float4*)p;
        float4 b = *(const float4*)(p + 4);
        u16x8 o;
        o[0] = f2bf(a.x); o[1] = f2bf(a.y); o[2] = f2bf(a.z); o[3] = f2bf(a.w);
        o[4] = f2bf(b.x); o[5] = f2bf(b.y); o[6] = f2bf(b.z); o[7] = f2bf(b.w);
        *(u16x8*)(wdst + i) = o;
    }
}

// ---------------- conv + LN1 fused: block = 32 tokens x 512 outs ----------------
// grid 256. Wave handles o-tiles {wave*64, 256+wave*64}; all waves share A rows.
// Epilogue -> LDS bf16 [32][520]; LN1 over rows; output ln1bf.
__global__ __launch_bounds__(256) void convln_k(
    const ushort* __restrict__ A, const ushort* __restrict__ W,
    const float* __restrict__ bias,
    const float* __restrict__ g, const float* __restrict__ bln,
    ushort* __restrict__ outb)
{
    __shared__ ushort cbuf[32][520];
    const int tid = threadIdx.x;
    const int wave = tid >> 6, lane = tid & 63;
    const int lg = lane >> 4, lc = lane & 15;
    const int m0 = blockIdx.x * 32;

    f32x4 acc[2][2][4];
#pragma unroll
    for (int t = 0; t < 2; ++t)
#pragma unroll
        for (int i = 0; i < 2; ++i)
#pragma unroll
            for (int j = 0; j < 4; ++j) acc[t][i][j] = (f32x4){0.f, 0.f, 0.f, 0.f};

    const ushort* Ab = A + (size_t)(m0 + lc) * 512 + lg * 8;
    const ushort* Wb0 = W + (size_t)(wave * 64 + lc) * 512 + lg * 8;
    const ushort* Wb1 = W + (size_t)(256 + wave * 64 + lc) * 512 + lg * 8;

#pragma unroll 4
    for (int k0 = 0; k0 < 512; k0 += 32) {
        bf16x8 aq[2], bw0[4], bw1[4];
        aq[0] = *(const bf16x8*)(Ab + k0);
        aq[1] = *(const bf16x8*)(Ab + 16 * 512 + k0);
#pragma unroll
        for (int j = 0; j < 4; ++j) {
            bw0[j] = *(const bf16x8*)(Wb0 + (size_t)j * 16 * 512 + k0);
            bw1[j] = *(const bf16x8*)(Wb1 + (size_t)j * 16 * 512 + k0);
        }
#pragma unroll
        for (int i = 0; i < 2; ++i)
#pragma unroll
            for (int j = 0; j < 4; ++j) {
                acc[0][i][j] = __builtin_amdgcn_mfma_f32_16x16x32_bf16(aq[i], bw0[j], acc[0][i][j], 0, 0, 0);
                acc[1][i][j] = __builtin_amdgcn_mfma_f32_16x16x32_bf16(aq[i], bw1[j], acc[1][i][j], 0, 0, 0);
            }
    }

#pragma unroll
    for (int t = 0; t < 2; ++t) {
        const int o0 = t * 256 + wave * 64;
#pragma unroll
        for (int j = 0; j < 4; ++j) {
            const float bv = bias[o0 + j * 16 + lc];
#pragma unroll
            for (int i = 0; i < 2; ++i)
#pragma unroll
                for (int r = 0; r < 4; ++r)
                    cbuf[i * 16 + lg * 4 + r][o0 + j * 16 + lc] = f2bf(acc[t][i][j][r] + bv);
        }
    }
    __syncthreads();

    // LN over 8 tokens per wave
    const int c0 = lane * 8;
    float4 g0 = *(const float4*)(g + c0);
    float4 g1 = *(const float4*)(g + c0 + 4);
    float4 b0 = *(const float4*)(bln + c0);
    float4 b1 = *(const float4*)(bln + c0 + 4);
    float gg[8] = {g0.x, g0.y, g0.z, g0.w, g1.x, g1.y, g1.z, g1.w};
    float bv8[8] = {b0.x, b0.y, b0.z, b0.w, b1.x, b1.y, b1.z, b1.w};
#pragma unroll
    for (int tt = 0; tt < 8; ++tt) {
        const int row = wave * 8 + tt;
        u16x8 vv = *(const u16x8*)&cbuf[row][c0];
        float xv[8];
#pragma unroll
        for (int i = 0; i < 8; i++) xv[i] = bf2f(vv[i]);
        float s = 0.f;
#pragma unroll
        for (int i = 0; i < 8; i++) s += xv[i];
#pragma unroll
        for (int sh = 32; sh; sh >>= 1) s += __shfl_xor(s, sh, 64);
        const float mu = s * (1.0f / 512.0f);
        float vs = 0.f;
#pragma unroll
        for (int i = 0; i < 8; i++) { float d = xv[i] - mu; vs += d * d; }
#pragma unroll
        for (int sh = 32; sh; sh >>= 1) vs += __shfl_xor(vs, sh, 64);
        const float inv = 1.0f / sqrtf(vs * (1.0f / 512.0f) + 1e-5f);
        u16x8 o;
#pragma unroll
        for (int i = 0; i < 8; i++) o[i] = f2bf((xv[i] - mu) * inv * gg[i] + bv8[i]);
        *(u16x8*)(outb + (size_t)(m0 + row) * 512 + c0) = o;
    }
}

// ---------------- qkv GEMM + in-kernel V transpose ----------------
// grid (64, 24). blockIdx.y<16: q/k scatter. >=16: V block (head = y-16) -> LDS
// transpose -> coalesced Vt[bh][d][n] stores.
__global__ __launch_bounds__(256) void qkvvt_k(
    const ushort* __restrict__ A, const ushort* __restrict__ W,
    const float* __restrict__ bias,
    ushort* __restrict__ qb, ushort* __restrict__ kb, ushort* __restrict__ vtb)
{
    __shared__ ushort vtile[64][136];
    const int tid = threadIdx.x;
    const int wave = tid >> 6, lane = tid & 63;
    const int lg = lane >> 4, lc = lane & 15;
    const int m0 = blockIdx.x * 128 + wave * 32;
    const int o0 = blockIdx.y * 64;

    f32x4 acc[2][4];
#pragma unroll
    for (int i = 0; i < 2; ++i)
#pragma unroll
        for (int j = 0; j < 4; ++j) acc[i][j] = (f32x4){0.f, 0.f, 0.f, 0.f};

    const ushort* Ab = A + (size_t)(m0 + lc) * 512 + lg * 8;
    const ushort* Wb = W + (size_t)(o0 + lc) * 512 + lg * 8;

#pragma unroll 4
    for (int k0 = 0; k0 < 512; k0 += 32) {
        bf16x8 aq[2], bw[4];
        aq[0] = *(const bf16x8*)(Ab + k0);
        aq[1] = *(const bf16x8*)(Ab + 16 * 512 + k0);
#pragma unroll
        for (int j = 0; j < 4; ++j) bw[j] = *(const bf16x8*)(Wb + (size_t)j * 16 * 512 + k0);
#pragma unroll
        for (int i = 0; i < 2; ++i)
#pragma unroll
            for (int j = 0; j < 4; ++j)
                acc[i][j] = __builtin_amdgcn_mfma_f32_16x16x32_bf16(aq[i], bw[j], acc[i][j], 0, 0, 0);
    }

    float bvv[4];
#pragma unroll
    for (int j = 0; j < 4; ++j) bvv[j] = bias[o0 + j * 16 + lc];

    if (blockIdx.y < 16) {
        // q/k: natural [bh][n][64] scatter
#pragma unroll
        for (int i = 0; i < 2; ++i) {
#pragma unroll
            for (int j = 0; j < 4; ++j) {
#pragma unroll
                for (int r = 0; r < 4; ++r) {
                    const int m = m0 + i * 16 + lg * 4 + r;
                    const int o = o0 + j * 16 + lc;
                    float v = acc[i][j][r] + bvv[j];
                    const int s = o >> 9, hh = (o >> 6) & 7, d = o & 63;
                    const int b = m >> 10, n = m & 1023;
                    const int bh = b * 8 + hh;
                    ushort* dst = (s == 0) ? qb : kb;
                    const float scl = (s == 0) ? QSCALE : 1.0f;
                    dst[((size_t)bh * 1024 + n) * 64 + d] = f2bf(v * scl);
                }
            }
        }
    } else {
        // V: block covers full d-range (64) x 128 tokens of one (b, head)
        const int mloc0 = wave * 32;
#pragma unroll
        for (int i = 0; i < 2; ++i)
#pragma unroll
            for (int j = 0; j < 4; ++j)
#pragma unroll
                for (int r = 0; r < 4; ++r)
                    vtile[j * 16 + lc][mloc0 + i * 16 + lg * 4 + r] = f2bf(acc[i][j][r] + bvv[j]);
        __syncthreads();
        const int hh = blockIdx.y - 16;
        const int mb0 = blockIdx.x * 128;
        const int b = mb0 >> 10, n0 = mb0 & 1023;
        const int bh = b * 8 + hh;
        const int d = tid >> 2, ng = (tid & 3) * 32;
        ushort* dst = vtb + ((size_t)bh * 64 + d) * 1024 + n0 + ng;
#pragma unroll
        for (int q8 = 0; q8 < 4; ++q8) {
            u16x8 o;
#pragma unroll
            for (int e = 0; e < 8; ++e) o[e] = vtile[d][ng + q8 * 8 + e];
            *(u16x8*)(dst + q8 * 8) = o;
        }
    }
}

// ---------------- MFMA bf16 flash attention, threefry fused, XCD-local grid ---------
// grid 1024 1-D: bh = id & 63, qt = id >> 6. 4 waves; wave owns 16 q rows.
__global__ __launch_bounds__(256) void attn_k(
    const ushort* __restrict__ qb, const ushort* __restrict__ kb,
    const ushort* __restrict__ vtb, ushort* __restrict__ ob,
    uint32_t km0, uint32_t km1)
{
    __shared__ ushort plds[4][16][40];
    const int tid = threadIdx.x;
    const int wave = tid >> 6, lane = tid & 63;
    const int bh = blockIdx.x & 63;
    const int qt = blockIdx.x >> 6;
    const int b = bh >> 3, h = bh & 7;
    const int q0 = qt * 64 + wave * 16;
    const int lg = lane >> 4, lc = lane & 15;

    const ushort* qp = qb + (size_t)bh * 65536;

    bf16x8 aq0 = *(const bf16x8*)(qp + (size_t)(q0 + lc) * 64 + lg * 8);
    bf16x8 aq1 = *(const bf16x8*)(qp + (size_t)(q0 + lc) * 64 + 32 + lg * 8);

    f32x4 zero = {0.f, 0.f, 0.f, 0.f};
    f32x4 oacc[4] = {zero, zero, zero, zero};
    float D[4] = {0.f, 0.f, 0.f, 0.f};

    uint32_t jr[4];
#pragma unroll
    for (int r = 0; r < 4; ++r)
        jr[r] = ((uint32_t)bh * 1024u + (uint32_t)(q0 + lg * 4 + r)) * 1024u + (uint32_t)lc;

    const ushort* krow = kb + (size_t)bh * 65536 + (size_t)lc * 64 + lg * 8;
    const ushort* vrow = vtb + (size_t)bh * 65536 + (size_t)lc * 1024 + lg * 8;

    for (int ch = 0; ch < 32; ++ch) {
        bf16x8 bk00 = *(const bf16x8*)(krow);
        bf16x8 bk01 = *(const bf16x8*)(krow + 32);
        bf16x8 bk10 = *(const bf16x8*)(krow + 1024);
        bf16x8 bk11 = *(const bf16x8*)(krow + 1056);

        f32x4 s0 = __builtin_amdgcn_mfma_f32_16x16x32_bf16(aq0, bk00, zero, 0, 0, 0);
        s0 = __builtin_amdgcn_mfma_f32_16x16x32_bf16(aq1, bk01, s0, 0, 0, 0);
        f32x4 s1 = __builtin_amdgcn_mfma_f32_16x16x32_bf16(aq0, bk10, zero, 0, 0, 0);
        s1 = __builtin_amdgcn_mfma_f32_16x16x32_bf16(aq1, bk11, s1, 0, 0, 0);

#pragma unroll
        for (int r = 0; r < 4; ++r) {
            const uint32_t bits0 = tf_bits(km0, km1, jr[r]);
            const uint32_t bits1 = tf_bits(km0, km1, jr[r] + 16u);
            jr[r] += 32u;
            const float pv0 = ((int)bits0 < 0) ? EXP2(s0[r]) : 0.f;
            const float pv1 = ((int)bits1 < 0) ? EXP2(s1[r]) : 0.f;
            D[r] += pv0 + pv1;
            uint32_t pk;
            asm("v_cvt_pk_bf16_f32 %0, %1, %2" : "=v"(pk) : "v"(pv0), "v"(pv1));
            plds[wave][lg * 4 + r][lc] = (ushort)pk;
            plds[wave][lg * 4 + r][lc + 16] = (ushort)(pk >> 16);
        }

        bf16x8 pa = *(const bf16x8*)&plds[wave][lc][lg * 8];

#pragma unroll
        for (int dt = 0; dt < 4; ++dt) {
            bf16x8 bv = *(const bf16x8*)(vrow + (size_t)dt * 16384);
            oacc[dt] = __builtin_amdgcn_mfma_f32_16x16x32_bf16(pa, bv, oacc[dt], 0, 0, 0);
        }
        krow += 2048;
        vrow += 32;
    }

#pragma unroll
    for (int r = 0; r < 4; ++r) {
#pragma unroll
        for (int sh = 1; sh < 16; sh <<= 1) D[r] += __shfl_xor(D[r], sh, 64);
    }

#pragma unroll
    for (int r = 0; r < 4; ++r) {
        const int q = q0 + lg * 4 + r;
        const float inv = 1.0f / D[r];
        ushort* orow = ob + ((size_t)b * 1024 + q) * 512 + h * 64;
#pragma unroll
        for (int dt = 0; dt < 4; ++dt) orow[dt * 16 + lc] = f2bf(oacc[dt][r] * inv);
    }
}

// ---------------- FF: proj + w1(gelu,m1) + w2(m2) + LN2 + token psum ----------------
// grid 512: b = id&7, tg = id>>3 (16-token group). 8 waves; wave owns o-slice wave*64.
__global__ __launch_bounds__(512) void ff_k(
    const ushort* __restrict__ ob,
    const ushort* __restrict__ wproj, const float* __restrict__ pjb,
    const ushort* __restrict__ ww1, const float* __restrict__ b1v,
    const ushort* __restrict__ ww2, const float* __restrict__ b2v,
    const float* __restrict__ g, const float* __restrict__ bln,
    float* __restrict__ pblock,
    uint32_t k10, uint32_t k11, uint32_t k20, uint32_t k21,
    uint32_t T1, uint32_t T2)
{
    __shared__ ushort bufA[16][520];
    __shared__ float stats[16][8][2];
    const int tid = threadIdx.x;
    const int wave = tid >> 6, lane = tid & 63;
    const int lg = lane >> 4, lc = lane & 15;
    const int b = blockIdx.x & 7, tg = blockIdx.x >> 3;

    // load O tile [16][512] bf16
    {
        const int row = tid >> 5, c0 = (tid & 31) * 16;
        const ushort* src = ob + ((size_t)(b * 1024 + tg * 16 + row)) * 512 + c0;
        *(u16x8*)&bufA[row][c0] = *(const u16x8*)src;
        *(u16x8*)&bufA[row][c0 + 8] = *(const u16x8*)(src + 8);
    }
    __syncthreads();

    const int o0 = wave * 64;
    const int mg0 = b * 1024 + tg * 16 + lg * 4;
    f32x4 zero = {0.f, 0.f, 0.f, 0.f};

    // ---- proj ----
    f32x4 acc[4] = {zero, zero, zero, zero};
    {
        const ushort* Wb = wproj + (size_t)(o0 + lc) * 512 + lg * 8;
#pragma unroll 4
        for (int k0 = 0; k0 < 512; k0 += 32) {
            bf16x8 a0 = *(const bf16x8*)&bufA[lc][k0 + lg * 8];
#pragma unroll
            for (int j = 0; j < 4; ++j) {
                bf16x8 bw = *(const bf16x8*)(Wb + (size_t)j * 16 * 512 + k0);
                acc[j] = __builtin_amdgcn_mfma_f32_16x16x32_bf16(a0, bw, acc[j], 0, 0, 0);
            }
        }
    }
    float bias4[4];
#pragma unroll
    for (int j = 0; j < 4; ++j) bias4[j] = pjb[o0 + j * 16 + lc];
    __syncthreads();
#pragma unroll
    for (int j = 0; j < 4; ++j)
#pragma unroll
        for (int r = 0; r < 4; ++r)
            bufA[lg * 4 + r][o0 + j * 16 + lc] = f2bf(acc[j][r] + bias4[j]);
    __syncthreads();

    // ---- w1 + gelu + m1 ----
#pragma unroll
    for (int j = 0; j < 4; ++j) acc[j] = zero;
    {
        const ushort* Wb = ww1 + (size_t)(o0 + lc) * 512 + lg * 8;
#pragma unroll 4
        for (int k0 = 0; k0 < 512; k0 += 32) {
            bf16x8 a0 = *(const bf16x8*)&bufA[lc][k0 + lg * 8];
#pragma unroll
            for (int j = 0; j < 4; ++j) {
                bf16x8 bw = *(const bf16x8*)(Wb + (size_t)j * 16 * 512 + k0);
                acc[j] = __builtin_amdgcn_mfma_f32_16x16x32_bf16(a0, bw, acc[j], 0, 0, 0);
            }
        }
    }
#pragma unroll
    for (int j = 0; j < 4; ++j) bias4[j] = b1v[o0 + j * 16 + lc];
    __syncthreads();
#pragma unroll
    for (int j = 0; j < 4; ++j) {
#pragma unroll
        for (int r = 0; r < 4; ++r) {
            float v = acc[j][r] + bias4[j];
            v = 0.5f * v * (1.0f + erff(v * 0.70710678118654752f));
            const uint32_t jidx = (uint32_t)((mg0 + r) * 512 + o0 + j * 16 + lc);
            if (tf_bits(k10, k11, jidx) < T1) v += NEGV;
            bufA[lg * 4 + r][o0 + j * 16 + lc] = f2bf(v);
        }
    }
    __syncthreads();

    // ---- w2 + m2 -> t2 regs ----
#pragma unroll
    for (int j = 0; j < 4; ++j) acc[j] = zero;
    {
        const ushort* Wb = ww2 + (size_t)(o0 + lc) * 512 + lg * 8;
#pragma unroll 4
        for (int k0 = 0; k0 < 512; k0 += 32) {
            bf16x8 a0 = *(const bf16x8*)&bufA[lc][k0 + lg * 8];
#pragma unroll
            for (int j = 0; j < 4; ++j) {
                bf16x8 bw = *(const bf16x8*)(Wb + (size_t)j * 16 * 512 + k0);
                acc[j] = __builtin_amdgcn_mfma_f32_16x16x32_bf16(a0, bw, acc[j], 0, 0, 0);
            }
        }
    }
#pragma unroll
    for (int j = 0; j < 4; ++j) bias4[j] = b2v[o0 + j * 16 + lc];
    float t2v[4][4];
#pragma unroll
    for (int j = 0; j < 4; ++j) {
#pragma unroll
        for (int r = 0; r < 4; ++r) {
            float v = acc[j][r] + bias4[j];
            const uint32_t jidx = (uint32_t)((mg0 + r) * 512 + o0 + j * 16 + lc);
            if (tf_bits(k20, k21, jidx) < T2) v += NEGV;
            t2v[j][r] = v;
        }
    }

    // ---- LN2 + token partial sums ----
    float rs[4], rq[4];
#pragma unroll
    for (int r = 0; r < 4; ++r) {
        float s = 0.f, q = 0.f;
#pragma unroll
        for (int j = 0; j < 4; ++j) { s += t2v[j][r]; q += t2v[j][r] * t2v[j][r]; }
#pragma unroll
        for (int sh = 1; sh < 16; sh <<= 1) {
            s += __shfl_xor(s, sh, 64);
            q += __shfl_xor(q, sh, 64);
        }
        rs[r] = s; rq[r] = q;
    }
    if (lc == 0) {
#pragma unroll
        for (int r = 0; r < 4; ++r) {
            stats[lg * 4 + r][wave][0] = rs[r];
            stats[lg * 4 + r][wave][1] = rq[r];
        }
    }
    __syncthreads();
    float mu[4], inv[4];
#pragma unroll
    for (int r = 0; r < 4; ++r) {
        float S = 0.f, S2 = 0.f;
#pragma unroll
        for (int w = 0; w < 8; ++w) { S += stats[lg * 4 + r][w][0]; S2 += stats[lg * 4 + r][w][1]; }
        const float m = S * (1.0f / 512.0f);
        const float var = S2 * (1.0f / 512.0f) - m * m;
        mu[r] = m;
        inv[r] = 1.0f / sqrtf(var + 1e-5f);
    }
    float gld[4], bld[4];
#pragma unroll
    for (int j = 0; j < 4; ++j) {
        gld[j] = g[o0 + j * 16 + lc];
        bld[j] = bln[o0 + j * 16 + lc];
    }
    float ps[4] = {0.f, 0.f, 0.f, 0.f};
#pragma unroll
    for (int j = 0; j < 4; ++j) {
#pragma unroll
        for (int r = 0; r < 4; ++r)
            ps[j] += (t2v[j][r] - mu[r]) * inv[r] * gld[j] + bld[j];
    }
#pragma unroll
    for (int j = 0; j < 4; ++j) {
        ps[j] += __shfl_xor(ps[j], 16, 64);
        ps[j] += __shfl_xor(ps[j], 32, 64);
    }
    if (lg == 0) {
#pragma unroll
        for (int j = 0; j < 4; ++j)
            pblock[((size_t)(b * 64 + tg)) * 512 + o0 + j * 16 + lc] = ps[j];
    }
}

// ---------------- reduce pblock -> tm[b][c] ----------------
__global__ __launch_bounds__(256) void mred2_k(const float* __restrict__ pblock,
                                               float* __restrict__ tm)
{
    const int b = blockIdx.y;
    const int c = blockIdx.x * 256 + threadIdx.x;
    const float* p = pblock + (size_t)b * 64 * 512 + c;
    float s = 0.f;
#pragma unroll 8
    for (int t = 0; t < 64; ++t) s += p[(size_t)t * 512];
    tm[b * 512 + c] = s * (1.0f / 1024.0f);
}

// ---------------- final fc ----------------
__global__ __launch_bounds__(256) void fc_k(const float* __restrict__ tm,
                                            const float* __restrict__ w,
                                            const float* __restrict__ bias,
                                            float* __restrict__ outp)
{
    const int b = blockIdx.y;
    const int o = blockIdx.x * 256 + threadIdx.x;
    const float* tr = tm + b * 512;
    const float* wr = w + (size_t)o * 512;
    float s = 0.f;
    for (int k = 0; k < 512; k += 4) {
        float4 a = *(const float4*)(tr + k);
        float4 ww = *(const float4*)(wr + k);
        s = fmaf(a.x, ww.x, s); s = fmaf(a.y, ww.y, s);
        s = fmaf(a.z, ww.z, s); s = fmaf(a.w, ww.w, s);
    }
    outp[b * 2560 + o] = s + bias[o];
}

// ---------------- launch ----------------
extern "C" void kernel_launch(void* const* d_in, const int* in_sizes, int n_in,
                              void* d_out, int out_size, void* d_ws, size_t ws_size,
                              hipStream_t stream)
{
    const float* x      = (const float*)d_in[0];
    const float* conv_w = (const float*)d_in[1];
    const float* conv_b = (const float*)d_in[2];
    const float* ln_g   = (const float*)d_in[3];
    const float* ln_b   = (const float*)d_in[4];
    const float* qkv_w  = (const float*)d_in[5];
    const float* qkv_b  = (const float*)d_in[6];
    const float* proj_w = (const float*)d_in[7];
    const float* proj_b = (const float*)d_in[8];
    const float* w1     = (const float*)d_in[9];
    const float* b1     = (const float*)d_in[10];
    const float* w2     = (const float*)d_in[11];
    const float* b2     = (const float*)d_in[12];
    const float* fc_w   = (const float*)d_in[13];
    const float* fc_b   = (const float*)d_in[14];
    float* out = (float*)d_out;

    if (ws_size < (size_t)67108864) return;  // need 64 MiB scratch

    uint32_t mk0a, mk0b, mk1a, mk1b, mk2a, mk2b;
    tf2x32_host(0u, 42u, 0u, 0u, &mk0a, &mk0b);
    tf2x32_host(0u, 42u, 0u, 1u, &mk1a, &mk1b);
    tf2x32_host(0u, 42u, 0u, 2u, &mk2a, &mk2b);
    const uint32_t T_m1 = maskT(0.3f);
    const uint32_t T_m2 = maskT(0.1f);

    char* wsb = (char*)d_ws;
    ushort* xt     = (ushort*)wsb;                   // 8 MiB @0   -> obuf (after convln)
    ushort* wts    = (ushort*)(wsb + 8388608);       // 3.5MiB @8M
    ushort* qbuf   = (ushort*)(wsb + 12582912);      // 8 MiB @12M
    ushort* kbuf   = (ushort*)(wsb + 20971520);      // 8 MiB @20M
    ushort* vtbuf  = (ushort*)(wsb + 29360128);      // 8 MiB @28M
    ushort* ln1bf  = (ushort*)(wsb + 37748736);      // 8 MiB @36M
    float*  pblock = (float*)(wsb + 46137344);       // 1 MiB @44M
    float*  tm     = (float*)(wsb + 47710208);       // 16 KiB @45.5M
    ushort* obuf   = xt;

    ushort* wconv = wts;
    ushort* wqkv  = wts + 262144;
    ushort* wproj = wts + 1048576;
    ushort* ww1   = wts + 1310720;
    ushort* ww2   = wts + 1572864;

    dim3 blk(256);
    // x transpose + weight convert
    prep_k<<<dim3(1920), blk, 0, stream>>>(x, xt, conv_w, qkv_w, proj_w, w1, w2, wts);
    // conv + LN1 -> ln1bf bf16
    convln_k<<<dim3(256), blk, 0, stream>>>(xt, wconv, conv_b, ln_g, ln_b, ln1bf);
    // qkv (+V transpose) -> q/k natural, vt transposed
    qkvvt_k<<<dim3(64, 24), blk, 0, stream>>>(ln1bf, wqkv, qkv_b, qbuf, kbuf, vtbuf);
    // attention (threefry fused) -> obuf bf16
    attn_k<<<dim3(1024), blk, 0, stream>>>(qbuf, kbuf, vtbuf, obuf, mk0a, mk0b);
    // FF fused: proj + w1 + w2 + LN2 + token psum -> pblock
    ff_k<<<dim3(512), dim3(512), 0, stream>>>(obuf, wproj, proj_b, ww1, b1, ww2, b2,
                                              ln_g, ln_b, pblock,
                                              mk1a, mk1b, mk2a, mk2b, T_m1, T_m2);
    // reduce partials -> tm
    mred2_k<<<dim3(2, 8), blk, 0, stream>>>(pblock, tm);
    // fc -> out
    fc_k<<<dim3(10, 8), blk, 0, stream>>>(tm, fc_w, fc_b, out);
}

// Round 10
// 322.956 us; speedup vs baseline: 1.5998x; 1.0854x over previous
//
#include <hip/hip_runtime.h>
#include <stdint.h>
#include <math.h>

#define NEGV -1.0e12f
// Q pre-scale: 1/sqrt(64) * log2(e)  (softmax uses native exp2)
#define QSCALE 0.18033688011112042f

typedef __attribute__((ext_vector_type(8))) short bf16x8;
typedef __attribute__((ext_vector_type(4))) float f32x4;
typedef __attribute__((ext_vector_type(8))) ushort u16x8;

// 1-instruction rotate
#define ROTL1(v, r) ({ uint32_t _d;                                            \
    asm("v_alignbit_b32 %0, %1, %1, %2" : "=v"(_d) : "v"(v), "n"(32 - (r)));   \
    _d; })

#if defined(__has_builtin)
#if __has_builtin(__builtin_amdgcn_exp2f)
#define EXP2(x) __builtin_amdgcn_exp2f(x)
#endif
#endif
#ifndef EXP2
#define EXP2(x) exp2f(x)
#endif

// ---------------- Threefry-2x32/20, host reference (key derivation) ----------------
__host__ static void tf2x32_host(uint32_t k0, uint32_t k1, uint32_t c0, uint32_t c1,
                                 uint32_t* o0, uint32_t* o1) {
    uint32_t ks2 = k0 ^ k1 ^ 0x1BD11BDAu;
    uint32_t x0 = c0 + k0, x1 = c1 + k1;
#define TF_RND(r) x0 += x1; x1 = ((x1 << (r)) | (x1 >> (32 - (r)))); x1 ^= x0;
    TF_RND(13) TF_RND(15) TF_RND(26) TF_RND(6)
    x0 += k1;  x1 += ks2 + 1u;
    TF_RND(17) TF_RND(29) TF_RND(16) TF_RND(24)
    x0 += ks2; x1 += k0 + 2u;
    TF_RND(13) TF_RND(15) TF_RND(26) TF_RND(6)
    x0 += k0;  x1 += k1 + 3u;
    TF_RND(17) TF_RND(29) TF_RND(16) TF_RND(24)
    x0 += k1;  x1 += ks2 + 4u;
    TF_RND(13) TF_RND(15) TF_RND(26) TF_RND(6)
    x0 += ks2; x1 += k0 + 5u;
#undef TF_RND
    *o0 = x0; *o1 = x1;
}

// device: JAX partitionable random bits for counter (0, j): bits = o0 ^ o1
__device__ __forceinline__ uint32_t tf_bits(uint32_t k0, uint32_t k1, uint32_t j) {
    const uint32_t ks2 = k0 ^ k1 ^ 0x1BD11BDAu;
    uint32_t x0 = k0, x1 = j + k1;
#define TFR(r) x0 += x1; x1 = ROTL1(x1, r); x1 ^= x0;
    TFR(13) TFR(15) TFR(26) TFR(6)
    x0 += k1;  x1 += ks2 + 1u;
    TFR(17) TFR(29) TFR(16) TFR(24)
    x0 += ks2; x1 += k0 + 2u;
    TFR(13) TFR(15) TFR(26) TFR(6)
    x0 += k0;  x1 += k1 + 3u;
    TFR(17) TFR(29) TFR(16) TFR(24)
    x0 += k1;  x1 += ks2 + 4u;
    TFR(13) TFR(15) TFR(26) TFR(6)
#undef TFR
    return (x0 + ks2) ^ (x1 + (k0 + 5u));
}

// bernoulli(p) true  <=>  bits < T,  T = ceil(p * 2^23) << 9  (exact vs JAX float path)
__host__ static uint32_t maskT(float p) {
    double t = ceil((double)p * 8388608.0);
    return ((uint32_t)t) << 9;
}

__device__ __forceinline__ ushort f2bf(float x) {
    uint32_t u = __float_as_uint(x);
    u += 0x7fffu + ((u >> 16) & 1u);
    return (ushort)(u >> 16);
}
__device__ __forceinline__ float bf2f(ushort u) {
    return __uint_as_float(((uint32_t)u) << 16);
}

// ---------------- prep: xpose (blocks 0..1023) + weight convert (1024..1919) --------
__global__ __launch_bounds__(256) void prep_k(const float* __restrict__ x,
                                              ushort* __restrict__ xt,
                                              const float* __restrict__ s0,
                                              const float* __restrict__ s1,
                                              const float* __restrict__ s2,
                                              const float* __restrict__ s3,
                                              const float* __restrict__ s4,
                                              ushort* __restrict__ wdst)
{
    __shared__ float tile[64][65];
    const int tid = threadIdx.x;
    if (blockIdx.x < 1024) {
        const int id = blockIdx.x;
        const int n0 = (id & 15) * 64, c0 = ((id >> 4) & 7) * 64, b = id >> 7;
        const float* src = x + ((size_t)b * 512 + c0) * 1024 + n0;
#pragma unroll
        for (int i = 0; i < 4; ++i) {
            const int r = (tid >> 4) + i * 16;
            const int col = (tid & 15) * 4;
            float4 v = *(const float4*)(src + (size_t)r * 1024 + col);
            tile[r][col + 0] = v.x; tile[r][col + 1] = v.y;
            tile[r][col + 2] = v.z; tile[r][col + 3] = v.w;
        }
        __syncthreads();
#pragma unroll
        for (int i = 0; i < 2; ++i) {
            const int nl = (tid >> 3) + i * 32;
            const int cb = (tid & 7) * 8;
            u16x8 o;
#pragma unroll
            for (int j = 0; j < 8; ++j) o[j] = f2bf(tile[cb + j][nl]);
            *(u16x8*)(xt + ((size_t)b * 1024 + n0 + nl) * 512 + c0 + cb) = o;
        }
    } else {
        const size_t i = ((size_t)(blockIdx.x - 1024) * 256 + tid) * 8;
        const float* src; size_t off;
        if (i < 262144)       { src = s0; off = 0; }
        else if (i < 1048576) { src = s1; off = 262144; }
        else if (i < 1310720) { src = s2; off = 1048576; }
        else if (i < 1572864) { src = s3; off = 1310720; }
        else                  { src = s4; off = 1572864; }
        const float* p = src + (i - off);
        float4 a = *(const float4*)p;
        float4 b = *(const float4*)(p + 4);
        u16x8 o;
        o[0] = f2bf(a.x); o[1] = f2bf(a.y); o[2] = f2bf(a.z); o[3] = f2bf(a.w);
        o[4] = f2bf(b.x); o[5] = f2bf(b.y); o[6] = f2bf(b.z); o[7] = f2bf(b.w);
        *(u16x8*)(wdst + i) = o;
    }
}

// ---------------- conv + LN1 fused: 512 thr, 32 tokens x 512 outs, 8 waves ----------
__global__ __launch_bounds__(512) void convln_k(
    const ushort* __restrict__ A, const ushort* __restrict__ W,
    const float* __restrict__ bias,
    const float* __restrict__ g, const float* __restrict__ bln,
    ushort* __restrict__ outb)
{
    __shared__ ushort cbuf[32][520];
    const int tid = threadIdx.x;
    const int wave = tid >> 6, lane = tid & 63;
    const int lg = lane >> 4, lc = lane & 15;
    const int m0 = blockIdx.x * 32;
    const int o0 = wave * 64;

    f32x4 acc[2][4];
#pragma unroll
    for (int i = 0; i < 2; ++i)
#pragma unroll
        for (int j = 0; j < 4; ++j) acc[i][j] = (f32x4){0.f, 0.f, 0.f, 0.f};

    const ushort* Ab = A + (size_t)(m0 + lc) * 512 + lg * 8;
    const ushort* Wb = W + (size_t)(o0 + lc) * 512 + lg * 8;

#pragma unroll 4
    for (int k0 = 0; k0 < 512; k0 += 32) {
        bf16x8 aq[2], bw[4];
        aq[0] = *(const bf16x8*)(Ab + k0);
        aq[1] = *(const bf16x8*)(Ab + 16 * 512 + k0);
#pragma unroll
        for (int j = 0; j < 4; ++j) bw[j] = *(const bf16x8*)(Wb + (size_t)j * 16 * 512 + k0);
#pragma unroll
        for (int i = 0; i < 2; ++i)
#pragma unroll
            for (int j = 0; j < 4; ++j)
                acc[i][j] = __builtin_amdgcn_mfma_f32_16x16x32_bf16(aq[i], bw[j], acc[i][j], 0, 0, 0);
    }

#pragma unroll
    for (int j = 0; j < 4; ++j) {
        const float bv = bias[o0 + j * 16 + lc];
#pragma unroll
        for (int i = 0; i < 2; ++i)
#pragma unroll
            for (int r = 0; r < 4; ++r)
                cbuf[i * 16 + lg * 4 + r][o0 + j * 16 + lc] = f2bf(acc[i][j][r] + bv);
    }
    __syncthreads();

    // LN over 4 tokens per wave
    const int c0 = lane * 8;
    float4 g0 = *(const float4*)(g + c0);
    float4 g1 = *(const float4*)(g + c0 + 4);
    float4 b0 = *(const float4*)(bln + c0);
    float4 b1 = *(const float4*)(bln + c0 + 4);
    float gg[8] = {g0.x, g0.y, g0.z, g0.w, g1.x, g1.y, g1.z, g1.w};
    float bv8[8] = {b0.x, b0.y, b0.z, b0.w, b1.x, b1.y, b1.z, b1.w};
#pragma unroll
    for (int tt = 0; tt < 4; ++tt) {
        const int row = wave * 4 + tt;
        u16x8 vv = *(const u16x8*)&cbuf[row][c0];
        float xv[8];
#pragma unroll
        for (int i = 0; i < 8; i++) xv[i] = bf2f(vv[i]);
        float s = 0.f;
#pragma unroll
        for (int i = 0; i < 8; i++) s += xv[i];
#pragma unroll
        for (int sh = 32; sh; sh >>= 1) s += __shfl_xor(s, sh, 64);
        const float mu = s * (1.0f / 512.0f);
        float vs = 0.f;
#pragma unroll
        for (int i = 0; i < 8; i++) { float d = xv[i] - mu; vs += d * d; }
#pragma unroll
        for (int sh = 32; sh; sh >>= 1) vs += __shfl_xor(vs, sh, 64);
        const float inv = 1.0f / sqrtf(vs * (1.0f / 512.0f) + 1e-5f);
        u16x8 o;
#pragma unroll
        for (int i = 0; i < 8; i++) o[i] = f2bf((xv[i] - mu) * inv * gg[i] + bv8[i]);
        *(u16x8*)(outb + (size_t)(m0 + row) * 512 + c0) = o;
    }
}

// ---------------- qkv GEMM + in-kernel V transpose ----------------
__global__ __launch_bounds__(256) void qkvvt_k(
    const ushort* __restrict__ A, const ushort* __restrict__ W,
    const float* __restrict__ bias,
    ushort* __restrict__ qb, ushort* __restrict__ kb, ushort* __restrict__ vtb)
{
    __shared__ ushort vtile[64][136];
    const int tid = threadIdx.x;
    const int wave = tid >> 6, lane = tid & 63;
    const int lg = lane >> 4, lc = lane & 15;
    const int m0 = blockIdx.x * 128 + wave * 32;
    const int o0 = blockIdx.y * 64;

    f32x4 acc[2][4];
#pragma unroll
    for (int i = 0; i < 2; ++i)
#pragma unroll
        for (int j = 0; j < 4; ++j) acc[i][j] = (f32x4){0.f, 0.f, 0.f, 0.f};

    const ushort* Ab = A + (size_t)(m0 + lc) * 512 + lg * 8;
    const ushort* Wb = W + (size_t)(o0 + lc) * 512 + lg * 8;

#pragma unroll 4
    for (int k0 = 0; k0 < 512; k0 += 32) {
        bf16x8 aq[2], bw[4];
        aq[0] = *(const bf16x8*)(Ab + k0);
        aq[1] = *(const bf16x8*)(Ab + 16 * 512 + k0);
#pragma unroll
        for (int j = 0; j < 4; ++j) bw[j] = *(const bf16x8*)(Wb + (size_t)j * 16 * 512 + k0);
#pragma unroll
        for (int i = 0; i < 2; ++i)
#pragma unroll
            for (int j = 0; j < 4; ++j)
                acc[i][j] = __builtin_amdgcn_mfma_f32_16x16x32_bf16(aq[i], bw[j], acc[i][j], 0, 0, 0);
    }

    float bvv[4];
#pragma unroll
    for (int j = 0; j < 4; ++j) bvv[j] = bias[o0 + j * 16 + lc];

    if (blockIdx.y < 16) {
#pragma unroll
        for (int i = 0; i < 2; ++i) {
#pragma unroll
            for (int j = 0; j < 4; ++j) {
#pragma unroll
                for (int r = 0; r < 4; ++r) {
                    const int m = m0 + i * 16 + lg * 4 + r;
                    const int o = o0 + j * 16 + lc;
                    float v = acc[i][j][r] + bvv[j];
                    const int s = o >> 9, hh = (o >> 6) & 7, d = o & 63;
                    const int b = m >> 10, n = m & 1023;
                    const int bh = b * 8 + hh;
                    ushort* dst = (s == 0) ? qb : kb;
                    const float scl = (s == 0) ? QSCALE : 1.0f;
                    dst[((size_t)bh * 1024 + n) * 64 + d] = f2bf(v * scl);
                }
            }
        }
    } else {
        const int mloc0 = wave * 32;
#pragma unroll
        for (int i = 0; i < 2; ++i)
#pragma unroll
            for (int j = 0; j < 4; ++j)
#pragma unroll
                for (int r = 0; r < 4; ++r)
                    vtile[j * 16 + lc][mloc0 + i * 16 + lg * 4 + r] = f2bf(acc[i][j][r] + bvv[j]);
        __syncthreads();
        const int hh = blockIdx.y - 16;
        const int mb0 = blockIdx.x * 128;
        const int b = mb0 >> 10, n0 = mb0 & 1023;
        const int bh = b * 8 + hh;
        const int d = tid >> 2, ng = (tid & 3) * 32;
        ushort* dst = vtb + ((size_t)bh * 64 + d) * 1024 + n0 + ng;
#pragma unroll
        for (int q8 = 0; q8 < 4; ++q8) {
            u16x8 o;
#pragma unroll
            for (int e = 0; e < 8; ++e) o[e] = vtile[d][ng + q8 * 8 + e];
            *(u16x8*)(dst + q8 * 8) = o;
        }
    }
}

// ---------------- MFMA bf16 flash attention, threefry fused, XCD-local grid ---------
__global__ __launch_bounds__(256) void attn_k(
    const ushort* __restrict__ qb, const ushort* __restrict__ kb,
    const ushort* __restrict__ vtb, ushort* __restrict__ ob,
    uint32_t km0, uint32_t km1)
{
    __shared__ ushort plds[4][16][40];
    const int tid = threadIdx.x;
    const int wave = tid >> 6, lane = tid & 63;
    const int bh = blockIdx.x & 63;
    const int qt = blockIdx.x >> 6;
    const int b = bh >> 3, h = bh & 7;
    const int q0 = qt * 64 + wave * 16;
    const int lg = lane >> 4, lc = lane & 15;

    const ushort* qp = qb + (size_t)bh * 65536;

    bf16x8 aq0 = *(const bf16x8*)(qp + (size_t)(q0 + lc) * 64 + lg * 8);
    bf16x8 aq1 = *(const bf16x8*)(qp + (size_t)(q0 + lc) * 64 + 32 + lg * 8);

    f32x4 zero = {0.f, 0.f, 0.f, 0.f};
    f32x4 oacc[4] = {zero, zero, zero, zero};
    float D[4] = {0.f, 0.f, 0.f, 0.f};

    uint32_t jr[4];
#pragma unroll
    for (int r = 0; r < 4; ++r)
        jr[r] = ((uint32_t)bh * 1024u + (uint32_t)(q0 + lg * 4 + r)) * 1024u + (uint32_t)lc;

    const ushort* krow = kb + (size_t)bh * 65536 + (size_t)lc * 64 + lg * 8;
    const ushort* vrow = vtb + (size_t)bh * 65536 + (size_t)lc * 1024 + lg * 8;

    for (int ch = 0; ch < 32; ++ch) {
        bf16x8 bk00 = *(const bf16x8*)(krow);
        bf16x8 bk01 = *(const bf16x8*)(krow + 32);
        bf16x8 bk10 = *(const bf16x8*)(krow + 1024);
        bf16x8 bk11 = *(const bf16x8*)(krow + 1056);

        f32x4 s0 = __builtin_amdgcn_mfma_f32_16x16x32_bf16(aq0, bk00, zero, 0, 0, 0);
        s0 = __builtin_amdgcn_mfma_f32_16x16x32_bf16(aq1, bk01, s0, 0, 0, 0);
        f32x4 s1 = __builtin_amdgcn_mfma_f32_16x16x32_bf16(aq0, bk10, zero, 0, 0, 0);
        s1 = __builtin_amdgcn_mfma_f32_16x16x32_bf16(aq1, bk11, s1, 0, 0, 0);

#pragma unroll
        for (int r = 0; r < 4; ++r) {
            const uint32_t bits0 = tf_bits(km0, km1, jr[r]);
            const uint32_t bits1 = tf_bits(km0, km1, jr[r] + 16u);
            jr[r] += 32u;
            const float pv0 = ((int)bits0 < 0) ? EXP2(s0[r]) : 0.f;
            const float pv1 = ((int)bits1 < 0) ? EXP2(s1[r]) : 0.f;
            D[r] += pv0 + pv1;
            uint32_t pk;
            asm("v_cvt_pk_bf16_f32 %0, %1, %2" : "=v"(pk) : "v"(pv0), "v"(pv1));
            plds[wave][lg * 4 + r][lc] = (ushort)pk;
            plds[wave][lg * 4 + r][lc + 16] = (ushort)(pk >> 16);
        }

        bf16x8 pa = *(const bf16x8*)&plds[wave][lc][lg * 8];

#pragma unroll
        for (int dt = 0; dt < 4; ++dt) {
            bf16x8 bv = *(const bf16x8*)(vrow + (size_t)dt * 16384);
            oacc[dt] = __builtin_amdgcn_mfma_f32_16x16x32_bf16(pa, bv, oacc[dt], 0, 0, 0);
        }
        krow += 2048;
        vrow += 32;
    }

#pragma unroll
    for (int r = 0; r < 4; ++r) {
#pragma unroll
        for (int sh = 1; sh < 16; sh <<= 1) D[r] += __shfl_xor(D[r], sh, 64);
    }

#pragma unroll
    for (int r = 0; r < 4; ++r) {
        const int q = q0 + lg * 4 + r;
        const float inv = 1.0f / D[r];
        ushort* orow = ob + ((size_t)b * 1024 + q) * 512 + h * 64;
#pragma unroll
        for (int dt = 0; dt < 4; ++dt) orow[dt * 16 + lc] = f2bf(oacc[dt][r] * inv);
    }
}

// ---------------- FF: 32-token blocks — proj + w1(gelu,m1) + w2(m2) + LN2 + psum ----
// grid 256: b = id&7, tg = id>>3 (32-token group). 8 waves; wave owns o-slice wave*64.
__global__ __launch_bounds__(512) void ff_k(
    const ushort* __restrict__ ob,
    const ushort* __restrict__ wproj, const float* __restrict__ pjb,
    const ushort* __restrict__ ww1, const float* __restrict__ b1v,
    const ushort* __restrict__ ww2, const float* __restrict__ b2v,
    const float* __restrict__ g, const float* __restrict__ bln,
    float* __restrict__ pblock,
    uint32_t k10, uint32_t k11, uint32_t k20, uint32_t k21,
    uint32_t T1, uint32_t T2)
{
    __shared__ ushort bufA[32][520];
    __shared__ float stats[32][8][2];
    const int tid = threadIdx.x;
    const int wave = tid >> 6, lane = tid & 63;
    const int lg = lane >> 4, lc = lane & 15;
    const int b = blockIdx.x & 7, tg = blockIdx.x >> 3;

    // load O tile [32][512] bf16
    {
        const int row = tid >> 4, c0 = (tid & 15) * 32;
        const ushort* src = ob + ((size_t)(b * 1024 + tg * 32 + row)) * 512 + c0;
#pragma unroll
        for (int q8 = 0; q8 < 4; ++q8)
            *(u16x8*)&bufA[row][c0 + q8 * 8] = *(const u16x8*)(src + q8 * 8);
    }
    __syncthreads();

    const int o0 = wave * 64;
    const int mg0 = b * 1024 + tg * 32;   // + i*16 + lg*4 + r per element
    f32x4 zero = {0.f, 0.f, 0.f, 0.f};

    // ---- proj ----
    f32x4 acc[2][4];
#pragma unroll
    for (int i = 0; i < 2; ++i)
#pragma unroll
        for (int j = 0; j < 4; ++j) acc[i][j] = zero;
    {
        const ushort* Wb = wproj + (size_t)(o0 + lc) * 512 + lg * 8;
#pragma unroll 4
        for (int k0 = 0; k0 < 512; k0 += 32) {
            bf16x8 a0 = *(const bf16x8*)&bufA[lc][k0 + lg * 8];
            bf16x8 a1 = *(const bf16x8*)&bufA[16 + lc][k0 + lg * 8];
#pragma unroll
            for (int j = 0; j < 4; ++j) {
                bf16x8 bw = *(const bf16x8*)(Wb + (size_t)j * 16 * 512 + k0);
                acc[0][j] = __builtin_amdgcn_mfma_f32_16x16x32_bf16(a0, bw, acc[0][j], 0, 0, 0);
                acc[1][j] = __builtin_amdgcn_mfma_f32_16x16x32_bf16(a1, bw, acc[1][j], 0, 0, 0);
            }
        }
    }
    float bias4[4];
#pragma unroll
    for (int j = 0; j < 4; ++j) bias4[j] = pjb[o0 + j * 16 + lc];
    __syncthreads();
#pragma unroll
    for (int i = 0; i < 2; ++i)
#pragma unroll
        for (int j = 0; j < 4; ++j)
#pragma unroll
            for (int r = 0; r < 4; ++r)
                bufA[i * 16 + lg * 4 + r][o0 + j * 16 + lc] = f2bf(acc[i][j][r] + bias4[j]);
    __syncthreads();

    // ---- w1 + gelu + m1 ----
#pragma unroll
    for (int i = 0; i < 2; ++i)
#pragma unroll
        for (int j = 0; j < 4; ++j) acc[i][j] = zero;
    {
        const ushort* Wb = ww1 + (size_t)(o0 + lc) * 512 + lg * 8;
#pragma unroll 4
        for (int k0 = 0; k0 < 512; k0 += 32) {
            bf16x8 a0 = *(const bf16x8*)&bufA[lc][k0 + lg * 8];
            bf16x8 a1 = *(const bf16x8*)&bufA[16 + lc][k0 + lg * 8];
#pragma unroll
            for (int j = 0; j < 4; ++j) {
                bf16x8 bw = *(const bf16x8*)(Wb + (size_t)j * 16 * 512 + k0);
                acc[0][j] = __builtin_amdgcn_mfma_f32_16x16x32_bf16(a0, bw, acc[0][j], 0, 0, 0);
                acc[1][j] = __builtin_amdgcn_mfma_f32_16x16x32_bf16(a1, bw, acc[1][j], 0, 0, 0);
            }
        }
    }
#pragma unroll
    for (int j = 0; j < 4; ++j) bias4[j] = b1v[o0 + j * 16 + lc];
    __syncthreads();
#pragma unroll
    for (int i = 0; i < 2; ++i) {
#pragma unroll
        for (int j = 0; j < 4; ++j) {
#pragma unroll
            for (int r = 0; r < 4; ++r) {
                float v = acc[i][j][r] + bias4[j];
                v = 0.5f * v * (1.0f + erff(v * 0.70710678118654752f));
                const uint32_t jidx =
                    (uint32_t)((mg0 + i * 16 + lg * 4 + r) * 512 + o0 + j * 16 + lc);
                if (tf_bits(k10, k11, jidx) < T1) v += NEGV;
                bufA[i * 16 + lg * 4 + r][o0 + j * 16 + lc] = f2bf(v);
            }
        }
    }
    __syncthreads();

    // ---- w2 + m2 -> t2 regs ----
#pragma unroll
    for (int i = 0; i < 2; ++i)
#pragma unroll
        for (int j = 0; j < 4; ++j) acc[i][j] = zero;
    {
        const ushort* Wb = ww2 + (size_t)(o0 + lc) * 512 + lg * 8;
#pragma unroll 4
        for (int k0 = 0; k0 < 512; k0 += 32) {
            bf16x8 a0 = *(const bf16x8*)&bufA[lc][k0 + lg * 8];
            bf16x8 a1 = *(const bf16x8*)&bufA[16 + lc][k0 + lg * 8];
#pragma unroll
            for (int j = 0; j < 4; ++j) {
                bf16x8 bw = *(const bf16x8*)(Wb + (size_t)j * 16 * 512 + k0);
                acc[0][j] = __builtin_amdgcn_mfma_f32_16x16x32_bf16(a0, bw, acc[0][j], 0, 0, 0);
                acc[1][j] = __builtin_amdgcn_mfma_f32_16x16x32_bf16(a1, bw, acc[1][j], 0, 0, 0);
            }
        }
    }
#pragma unroll
    for (int j = 0; j < 4; ++j) bias4[j] = b2v[o0 + j * 16 + lc];
    float t2v[2][4][4];
#pragma unroll
    for (int i = 0; i < 2; ++i) {
#pragma unroll
        for (int j = 0; j < 4; ++j) {
#pragma unroll
            for (int r = 0; r < 4; ++r) {
                float v = acc[i][j][r] + bias4[j];
                const uint32_t jidx =
                    (uint32_t)((mg0 + i * 16 + lg * 4 + r) * 512 + o0 + j * 16 + lc);
                if (tf_bits(k20, k21, jidx) < T2) v += NEGV;
                t2v[i][j][r] = v;
            }
        }
    }

    // ---- LN2 + token partial sums ----
#pragma unroll
    for (int i = 0; i < 2; ++i) {
#pragma unroll
        for (int r = 0; r < 4; ++r) {
            float s = 0.f, q = 0.f;
#pragma unroll
            for (int j = 0; j < 4; ++j) { s += t2v[i][j][r]; q += t2v[i][j][r] * t2v[i][j][r]; }
#pragma unroll
            for (int sh = 1; sh < 16; sh <<= 1) {
                s += __shfl_xor(s, sh, 64);
                q += __shfl_xor(q, sh, 64);
            }
            if (lc == 0) {
                stats[i * 16 + lg * 4 + r][wave][0] = s;
                stats[i * 16 + lg * 4 + r][wave][1] = q;
            }
        }
    }
    __syncthreads();
    float mu[2][4], inv[2][4];
#pragma unroll
    for (int i = 0; i < 2; ++i) {
#pragma unroll
        for (int r = 0; r < 4; ++r) {
            float S = 0.f, S2 = 0.f;
#pragma unroll
            for (int w = 0; w < 8; ++w) {
                S += stats[i * 16 + lg * 4 + r][w][0];
                S2 += stats[i * 16 + lg * 4 + r][w][1];
            }
            const float m = S * (1.0f / 512.0f);
            const float var = S2 * (1.0f / 512.0f) - m * m;
            mu[i][r] = m;
            inv[i][r] = 1.0f / sqrtf(var + 1e-5f);
        }
    }
    float gld[4], bld[4];
#pragma unroll
    for (int j = 0; j < 4; ++j) {
        gld[j] = g[o0 + j * 16 + lc];
        bld[j] = bln[o0 + j * 16 + lc];
    }
    float ps[4] = {0.f, 0.f, 0.f, 0.f};
#pragma unroll
    for (int i = 0; i < 2; ++i)
#pragma unroll
        for (int j = 0; j < 4; ++j)
#pragma unroll
            for (int r = 0; r < 4; ++r)
                ps[j] += (t2v[i][j][r] - mu[i][r]) * inv[i][r] * gld[j] + bld[j];
#pragma unroll
    for (int j = 0; j < 4; ++j) {
        ps[j] += __shfl_xor(ps[j], 16, 64);
        ps[j] += __shfl_xor(ps[j], 32, 64);
    }
    if (lg == 0) {
#pragma unroll
        for (int j = 0; j < 4; ++j)
            pblock[((size_t)(b * 32 + tg)) * 512 + o0 + j * 16 + lc] = ps[j];
    }
}

// ---------------- fc2: reduce pblock in-LDS + final fc ----------------
__global__ __launch_bounds__(256) void fc2_k(const float* __restrict__ pblock,
                                             const float* __restrict__ w,
                                             const float* __restrict__ bias,
                                             float* __restrict__ outp)
{
    __shared__ float tmld[512];
    const int b = blockIdx.y;
    const int tid = threadIdx.x;
    // reduce 32 partial rows -> tm[b][:]; 256 threads x 2 cols
#pragma unroll
    for (int cc = 0; cc < 2; ++cc) {
        const int c = tid + cc * 256;
        const float* p = pblock + (size_t)(b * 32) * 512 + c;
        float s = 0.f;
#pragma unroll 8
        for (int t = 0; t < 32; ++t) s += p[(size_t)t * 512];
        tmld[c] = s * (1.0f / 1024.0f);
    }
    __syncthreads();
    const int o = blockIdx.x * 256 + tid;
    const float* wr = w + (size_t)o * 512;
    float s = 0.f;
    for (int k = 0; k < 512; k += 4) {
        float4 a = *(const float4*)(tmld + k);
        float4 ww = *(const float4*)(wr + k);
        s = fmaf(a.x, ww.x, s); s = fmaf(a.y, ww.y, s);
        s = fmaf(a.z, ww.z, s); s = fmaf(a.w, ww.w, s);
    }
    outp[b * 2560 + o] = s + bias[o];
}

// ---------------- launch ----------------
extern "C" void kernel_launch(void* const* d_in, const int* in_sizes, int n_in,
                              void* d_out, int out_size, void* d_ws, size_t ws_size,
                              hipStream_t stream)
{
    const float* x      = (const float*)d_in[0];
    const float* conv_w = (const float*)d_in[1];
    const float* conv_b = (const float*)d_in[2];
    const float* ln_g   = (const float*)d_in[3];
    const float* ln_b   = (const float*)d_in[4];
    const float* qkv_w  = (const float*)d_in[5];
    const float* qkv_b  = (const float*)d_in[6];
    const float* proj_w = (const float*)d_in[7];
    const float* proj_b = (const float*)d_in[8];
    const float* w1     = (const float*)d_in[9];
    const float* b1     = (const float*)d_in[10];
    const float* w2     = (const float*)d_in[11];
    const float* b2     = (const float*)d_in[12];
    const float* fc_w   = (const float*)d_in[13];
    const float* fc_b   = (const float*)d_in[14];
    float* out = (float*)d_out;

    if (ws_size < (size_t)67108864) return;  // need 64 MiB scratch

    uint32_t mk0a, mk0b, mk1a, mk1b, mk2a, mk2b;
    tf2x32_host(0u, 42u, 0u, 0u, &mk0a, &mk0b);
    tf2x32_host(0u, 42u, 0u, 1u, &mk1a, &mk1b);
    tf2x32_host(0u, 42u, 0u, 2u, &mk2a, &mk2b);
    const uint32_t T_m1 = maskT(0.3f);
    const uint32_t T_m2 = maskT(0.1f);

    char* wsb = (char*)d_ws;
    ushort* xt     = (ushort*)wsb;                   // 8 MiB @0   -> obuf
    ushort* wts    = (ushort*)(wsb + 8388608);       // 3.5MiB @8M
    ushort* qbuf   = (ushort*)(wsb + 12582912);      // 8 MiB @12M
    ushort* kbuf   = (ushort*)(wsb + 20971520);      // 8 MiB @20M
    ushort* vtbuf  = (ushort*)(wsb + 29360128);      // 8 MiB @28M
    ushort* ln1bf  = (ushort*)(wsb + 37748736);      // 8 MiB @36M
    float*  pblock = (float*)(wsb + 46137344);       // 512 KiB @44M
    ushort* obuf   = xt;

    ushort* wconv = wts;
    ushort* wqkv  = wts + 262144;
    ushort* wproj = wts + 1048576;
    ushort* ww1   = wts + 1310720;
    ushort* ww2   = wts + 1572864;

    dim3 blk(256);
    // x transpose + weight convert
    prep_k<<<dim3(1920), blk, 0, stream>>>(x, xt, conv_w, qkv_w, proj_w, w1, w2, wts);
    // conv + LN1 -> ln1bf bf16
    convln_k<<<dim3(256), dim3(512), 0, stream>>>(xt, wconv, conv_b, ln_g, ln_b, ln1bf);
    // qkv (+V transpose) -> q/k natural, vt transposed
    qkvvt_k<<<dim3(64, 24), blk, 0, stream>>>(ln1bf, wqkv, qkv_b, qbuf, kbuf, vtbuf);
    // attention (threefry fused) -> obuf bf16
    attn_k<<<dim3(1024), blk, 0, stream>>>(qbuf, kbuf, vtbuf, obuf, mk0a, mk0b);
    // FF fused (32-token blocks) -> pblock
    ff_k<<<dim3(256), dim3(512), 0, stream>>>(obuf, wproj, proj_b, ww1, b1, ww2, b2,
                                              ln_g, ln_b, pblock,
                                              mk1a, mk1b, mk2a, mk2b, T_m1, T_m2);
    // reduce + fc -> out
    fc2_k<<<dim3(10, 8), blk, 0, stream>>>(pblock, fc_w, fc_b, out);
}

// Round 11
// 315.779 us; speedup vs baseline: 1.6361x; 1.0227x over previous
//
#include <hip/hip_runtime.h>
#include <stdint.h>
#include <math.h>

#define NEGV -1.0e12f
// Q pre-scale: 1/sqrt(64) * log2(e)  (softmax uses native exp2)
#define QSCALE 0.18033688011112042f

typedef __attribute__((ext_vector_type(8))) short bf16x8;
typedef __attribute__((ext_vector_type(4))) float f32x4;
typedef __attribute__((ext_vector_type(8))) ushort u16x8;

// 1-instruction rotate
#define ROTL1(v, r) ({ uint32_t _d;                                            \
    asm("v_alignbit_b32 %0, %1, %1, %2" : "=v"(_d) : "v"(v), "n"(32 - (r)));   \
    _d; })

#if defined(__has_builtin)
#if __has_builtin(__builtin_amdgcn_exp2f)
#define EXP2(x) __builtin_amdgcn_exp2f(x)
#endif
#endif
#ifndef EXP2
#define EXP2(x) exp2f(x)
#endif

// ---------------- Threefry-2x32/20, host reference (key derivation) ----------------
__host__ static void tf2x32_host(uint32_t k0, uint32_t k1, uint32_t c0, uint32_t c1,
                                 uint32_t* o0, uint32_t* o1) {
    uint32_t ks2 = k0 ^ k1 ^ 0x1BD11BDAu;
    uint32_t x0 = c0 + k0, x1 = c1 + k1;
#define TF_RND(r) x0 += x1; x1 = ((x1 << (r)) | (x1 >> (32 - (r)))); x1 ^= x0;
    TF_RND(13) TF_RND(15) TF_RND(26) TF_RND(6)
    x0 += k1;  x1 += ks2 + 1u;
    TF_RND(17) TF_RND(29) TF_RND(16) TF_RND(24)
    x0 += ks2; x1 += k0 + 2u;
    TF_RND(13) TF_RND(15) TF_RND(26) TF_RND(6)
    x0 += k0;  x1 += k1 + 3u;
    TF_RND(17) TF_RND(29) TF_RND(16) TF_RND(24)
    x0 += k1;  x1 += ks2 + 4u;
    TF_RND(13) TF_RND(15) TF_RND(26) TF_RND(6)
    x0 += ks2; x1 += k0 + 5u;
#undef TF_RND
    *o0 = x0; *o1 = x1;
}

// device: JAX partitionable random bits for counter (0, j): bits = o0 ^ o1
__device__ __forceinline__ uint32_t tf_bits(uint32_t k0, uint32_t k1, uint32_t j) {
    const uint32_t ks2 = k0 ^ k1 ^ 0x1BD11BDAu;
    uint32_t x0 = k0, x1 = j + k1;
#define TFR(r) x0 += x1; x1 = ROTL1(x1, r); x1 ^= x0;
    TFR(13) TFR(15) TFR(26) TFR(6)
    x0 += k1;  x1 += ks2 + 1u;
    TFR(17) TFR(29) TFR(16) TFR(24)
    x0 += ks2; x1 += k0 + 2u;
    TFR(13) TFR(15) TFR(26) TFR(6)
    x0 += k0;  x1 += k1 + 3u;
    TFR(17) TFR(29) TFR(16) TFR(24)
    x0 += k1;  x1 += ks2 + 4u;
    TFR(13) TFR(15) TFR(26) TFR(6)
#undef TFR
    return (x0 + ks2) ^ (x1 + (k0 + 5u));
}

// bernoulli(p) true  <=>  bits < T,  T = ceil(p * 2^23) << 9  (exact vs JAX float path)
__host__ static uint32_t maskT(float p) {
    double t = ceil((double)p * 8388608.0);
    return ((uint32_t)t) << 9;
}

__device__ __forceinline__ ushort f2bf(float x) {
    uint32_t u = __float_as_uint(x);
    u += 0x7fffu + ((u >> 16) & 1u);
    return (ushort)(u >> 16);
}
__device__ __forceinline__ float bf2f(ushort u) {
    return __uint_as_float(((uint32_t)u) << 16);
}

// ---------------- prep: xpose (blocks 0..1023) + weight convert (1024..1919) --------
__global__ __launch_bounds__(256) void prep_k(const float* __restrict__ x,
                                              ushort* __restrict__ xt,
                                              const float* __restrict__ s0,
                                              const float* __restrict__ s1,
                                              const float* __restrict__ s2,
                                              const float* __restrict__ s3,
                                              const float* __restrict__ s4,
                                              ushort* __restrict__ wdst)
{
    __shared__ float tile[64][65];
    const int tid = threadIdx.x;
    if (blockIdx.x < 1024) {
        const int id = blockIdx.x;
        const int n0 = (id & 15) * 64, c0 = ((id >> 4) & 7) * 64, b = id >> 7;
        const float* src = x + ((size_t)b * 512 + c0) * 1024 + n0;
#pragma unroll
        for (int i = 0; i < 4; ++i) {
            const int r = (tid >> 4) + i * 16;
            const int col = (tid & 15) * 4;
            float4 v = *(const float4*)(src + (size_t)r * 1024 + col);
            tile[r][col + 0] = v.x; tile[r][col + 1] = v.y;
            tile[r][col + 2] = v.z; tile[r][col + 3] = v.w;
        }
        __syncthreads();
#pragma unroll
        for (int i = 0; i < 2; ++i) {
            const int nl = (tid >> 3) + i * 32;
            const int cb = (tid & 7) * 8;
            u16x8 o;
#pragma unroll
            for (int j = 0; j < 8; ++j) o[j] = f2bf(tile[cb + j][nl]);
            *(u16x8*)(xt + ((size_t)b * 1024 + n0 + nl) * 512 + c0 + cb) = o;
        }
    } else {
        const size_t i = ((size_t)(blockIdx.x - 1024) * 256 + tid) * 8;
        const float* src; size_t off;
        if (i < 262144)       { src = s0; off = 0; }
        else if (i < 1048576) { src = s1; off = 262144; }
        else if (i < 1310720) { src = s2; off = 1048576; }
        else if (i < 1572864) { src = s3; off = 1310720; }
        else                  { src = s4; off = 1572864; }
        const float* p = src + (i - off);
        float4 a = *(const float4*)p;
        float4 b = *(const float4*)(p + 4);
        u16x8 o;
        o[0] = f2bf(a.x); o[1] = f2bf(a.y); o[2] = f2bf(a.z); o[3] = f2bf(a.w);
        o[4] = f2bf(b.x); o[5] = f2bf(b.y); o[6] = f2bf(b.z); o[7] = f2bf(b.w);
        *(u16x8*)(wdst + i) = o;
    }
}

// ---------------- conv + LN1 fused: 512 thr, 32 tokens x 512 outs, 8 waves ----------
__global__ __launch_bounds__(512) void convln_k(
    const ushort* __restrict__ A, const ushort* __restrict__ W,
    const float* __restrict__ bias,
    const float* __restrict__ g, const float* __restrict__ bln,
    ushort* __restrict__ outb)
{
    __shared__ ushort cbuf[32][520];
    const int tid = threadIdx.x;
    const int wave = tid >> 6, lane = tid & 63;
    const int lg = lane >> 4, lc = lane & 15;
    const int m0 = blockIdx.x * 32;
    const int o0 = wave * 64;

    f32x4 acc[2][4];
#pragma unroll
    for (int i = 0; i < 2; ++i)
#pragma unroll
        for (int j = 0; j < 4; ++j) acc[i][j] = (f32x4){0.f, 0.f, 0.f, 0.f};

    const ushort* Ab = A + (size_t)(m0 + lc) * 512 + lg * 8;
    const ushort* Wb = W + (size_t)(o0 + lc) * 512 + lg * 8;

#pragma unroll 4
    for (int k0 = 0; k0 < 512; k0 += 32) {
        bf16x8 aq[2], bw[4];
        aq[0] = *(const bf16x8*)(Ab + k0);
        aq[1] = *(const bf16x8*)(Ab + 16 * 512 + k0);
#pragma unroll
        for (int j = 0; j < 4; ++j) bw[j] = *(const bf16x8*)(Wb + (size_t)j * 16 * 512 + k0);
#pragma unroll
        for (int i = 0; i < 2; ++i)
#pragma unroll
            for (int j = 0; j < 4; ++j)
                acc[i][j] = __builtin_amdgcn_mfma_f32_16x16x32_bf16(aq[i], bw[j], acc[i][j], 0, 0, 0);
    }

#pragma unroll
    for (int j = 0; j < 4; ++j) {
        const float bv = bias[o0 + j * 16 + lc];
#pragma unroll
        for (int i = 0; i < 2; ++i)
#pragma unroll
            for (int r = 0; r < 4; ++r)
                cbuf[i * 16 + lg * 4 + r][o0 + j * 16 + lc] = f2bf(acc[i][j][r] + bv);
    }
    __syncthreads();

    // LN over 4 tokens per wave
    const int c0 = lane * 8;
    float4 g0 = *(const float4*)(g + c0);
    float4 g1 = *(const float4*)(g + c0 + 4);
    float4 b0 = *(const float4*)(bln + c0);
    float4 b1 = *(const float4*)(bln + c0 + 4);
    float gg[8] = {g0.x, g0.y, g0.z, g0.w, g1.x, g1.y, g1.z, g1.w};
    float bv8[8] = {b0.x, b0.y, b0.z, b0.w, b1.x, b1.y, b1.z, b1.w};
#pragma unroll
    for (int tt = 0; tt < 4; ++tt) {
        const int row = wave * 4 + tt;
        u16x8 vv = *(const u16x8*)&cbuf[row][c0];
        float xv[8];
#pragma unroll
        for (int i = 0; i < 8; i++) xv[i] = bf2f(vv[i]);
        float s = 0.f;
#pragma unroll
        for (int i = 0; i < 8; i++) s += xv[i];
#pragma unroll
        for (int sh = 32; sh; sh >>= 1) s += __shfl_xor(s, sh, 64);
        const float mu = s * (1.0f / 512.0f);
        float vs = 0.f;
#pragma unroll
        for (int i = 0; i < 8; i++) { float d = xv[i] - mu; vs += d * d; }
#pragma unroll
        for (int sh = 32; sh; sh >>= 1) vs += __shfl_xor(vs, sh, 64);
        const float inv = 1.0f / sqrtf(vs * (1.0f / 512.0f) + 1e-5f);
        u16x8 o;
#pragma unroll
        for (int i = 0; i < 8; i++) o[i] = f2bf((xv[i] - mu) * inv * gg[i] + bv8[i]);
        *(u16x8*)(outb + (size_t)(m0 + row) * 512 + c0) = o;
    }
}

// ---------------- qkv GEMM, wave tile 32x128 (A-frag reuse) + in-kernel V transpose -
// grid (64, 12): y<8 -> q/k outputs [y*128, y*128+128); y>=8 -> V (2 heads per block).
__global__ __launch_bounds__(256) void qkvvt_k(
    const ushort* __restrict__ A, const ushort* __restrict__ W,
    const float* __restrict__ bias,
    ushort* __restrict__ qb, ushort* __restrict__ kb, ushort* __restrict__ vtb)
{
    __shared__ ushort vtile[128][136];
    const int tid = threadIdx.x;
    const int wave = tid >> 6, lane = tid & 63;
    const int lg = lane >> 4, lc = lane & 15;
    const int m0 = blockIdx.x * 128 + wave * 32;
    const int o0 = blockIdx.y * 128;

    f32x4 acc[2][8];
#pragma unroll
    for (int i = 0; i < 2; ++i)
#pragma unroll
        for (int j = 0; j < 8; ++j) acc[i][j] = (f32x4){0.f, 0.f, 0.f, 0.f};

    const ushort* Ab = A + (size_t)(m0 + lc) * 512 + lg * 8;
    const ushort* Wb = W + (size_t)(o0 + lc) * 512 + lg * 8;

#pragma unroll 2
    for (int k0 = 0; k0 < 512; k0 += 32) {
        bf16x8 aq[2], bw[8];
        aq[0] = *(const bf16x8*)(Ab + k0);
        aq[1] = *(const bf16x8*)(Ab + 16 * 512 + k0);
#pragma unroll
        for (int j = 0; j < 8; ++j) bw[j] = *(const bf16x8*)(Wb + (size_t)j * 16 * 512 + k0);
#pragma unroll
        for (int i = 0; i < 2; ++i)
#pragma unroll
            for (int j = 0; j < 8; ++j)
                acc[i][j] = __builtin_amdgcn_mfma_f32_16x16x32_bf16(aq[i], bw[j], acc[i][j], 0, 0, 0);
    }

    float bvv[8];
#pragma unroll
    for (int j = 0; j < 8; ++j) bvv[j] = bias[o0 + j * 16 + lc];

    if (blockIdx.y < 8) {
        // q/k: natural [bh][n][64] scatter; o < 512 -> q (pre-scaled), else k
#pragma unroll
        for (int i = 0; i < 2; ++i) {
#pragma unroll
            for (int j = 0; j < 8; ++j) {
#pragma unroll
                for (int r = 0; r < 4; ++r) {
                    const int m = m0 + i * 16 + lg * 4 + r;
                    const int o = o0 + j * 16 + lc;
                    float v = acc[i][j][r] + bvv[j];
                    const int s = o >> 9, hh = (o >> 6) & 7, d = o & 63;
                    const int b = m >> 10, n = m & 1023;
                    const int bh = b * 8 + hh;
                    ushort* dst = (s == 0) ? qb : kb;
                    const float scl = (s == 0) ? QSCALE : 1.0f;
                    dst[((size_t)bh * 1024 + n) * 64 + d] = f2bf(v * scl);
                }
            }
        }
    } else {
        // V: o-range covers 2 heads x 64 dims; 128 tokens of one batch
        const int mloc0 = wave * 32;
#pragma unroll
        for (int i = 0; i < 2; ++i)
#pragma unroll
            for (int j = 0; j < 8; ++j)
#pragma unroll
                for (int r = 0; r < 4; ++r)
                    vtile[j * 16 + lc][mloc0 + i * 16 + lg * 4 + r] = f2bf(acc[i][j][r] + bvv[j]);
        __syncthreads();
        const int mb0 = blockIdx.x * 128;
        const int b = mb0 >> 10, n0 = mb0 & 1023;
        const int hhbase = (o0 - 1024) >> 6;   // 2 heads: hhbase, hhbase+1
        const int od = tid >> 1, ng = (tid & 1) * 64;
        const int hh = hhbase + (od >> 6), d = od & 63;
        ushort* dst = vtb + ((size_t)(b * 8 + hh) * 64 + d) * 1024 + n0 + ng;
#pragma unroll
        for (int q8 = 0; q8 < 8; ++q8) {
            u16x8 o;
#pragma unroll
            for (int e = 0; e < 8; ++e) o[e] = vtile[od][ng + q8 * 8 + e];
            *(u16x8*)(dst + q8 * 8) = o;
        }
    }
}

// ---------------- MFMA bf16 flash attention, threefry fused, XCD-local grid ---------
__global__ __launch_bounds__(256) void attn_k(
    const ushort* __restrict__ qb, const ushort* __restrict__ kb,
    const ushort* __restrict__ vtb, ushort* __restrict__ ob,
    uint32_t km0, uint32_t km1)
{
    __shared__ ushort plds[4][16][40];
    const int tid = threadIdx.x;
    const int wave = tid >> 6, lane = tid & 63;
    const int bh = blockIdx.x & 63;
    const int qt = blockIdx.x >> 6;
    const int b = bh >> 3, h = bh & 7;
    const int q0 = qt * 64 + wave * 16;
    const int lg = lane >> 4, lc = lane & 15;

    const ushort* qp = qb + (size_t)bh * 65536;

    bf16x8 aq0 = *(const bf16x8*)(qp + (size_t)(q0 + lc) * 64 + lg * 8);
    bf16x8 aq1 = *(const bf16x8*)(qp + (size_t)(q0 + lc) * 64 + 32 + lg * 8);

    f32x4 zero = {0.f, 0.f, 0.f, 0.f};
    f32x4 oacc[4] = {zero, zero, zero, zero};
    float D[4] = {0.f, 0.f, 0.f, 0.f};

    uint32_t jr[4];
#pragma unroll
    for (int r = 0; r < 4; ++r)
        jr[r] = ((uint32_t)bh * 1024u + (uint32_t)(q0 + lg * 4 + r)) * 1024u + (uint32_t)lc;

    const ushort* krow = kb + (size_t)bh * 65536 + (size_t)lc * 64 + lg * 8;
    const ushort* vrow = vtb + (size_t)bh * 65536 + (size_t)lc * 1024 + lg * 8;

    for (int ch = 0; ch < 32; ++ch) {
        bf16x8 bk00 = *(const bf16x8*)(krow);
        bf16x8 bk01 = *(const bf16x8*)(krow + 32);
        bf16x8 bk10 = *(const bf16x8*)(krow + 1024);
        bf16x8 bk11 = *(const bf16x8*)(krow + 1056);

        f32x4 s0 = __builtin_amdgcn_mfma_f32_16x16x32_bf16(aq0, bk00, zero, 0, 0, 0);
        s0 = __builtin_amdgcn_mfma_f32_16x16x32_bf16(aq1, bk01, s0, 0, 0, 0);
        f32x4 s1 = __builtin_amdgcn_mfma_f32_16x16x32_bf16(aq0, bk10, zero, 0, 0, 0);
        s1 = __builtin_amdgcn_mfma_f32_16x16x32_bf16(aq1, bk11, s1, 0, 0, 0);

#pragma unroll
        for (int r = 0; r < 4; ++r) {
            const uint32_t bits0 = tf_bits(km0, km1, jr[r]);
            const uint32_t bits1 = tf_bits(km0, km1, jr[r] + 16u);
            jr[r] += 32u;
            const float pv0 = ((int)bits0 < 0) ? EXP2(s0[r]) : 0.f;
            const float pv1 = ((int)bits1 < 0) ? EXP2(s1[r]) : 0.f;
            D[r] += pv0 + pv1;
            uint32_t pk;
            asm("v_cvt_pk_bf16_f32 %0, %1, %2" : "=v"(pk) : "v"(pv0), "v"(pv1));
            plds[wave][lg * 4 + r][lc] = (ushort)pk;
            plds[wave][lg * 4 + r][lc + 16] = (ushort)(pk >> 16);
        }

        bf16x8 pa = *(const bf16x8*)&plds[wave][lc][lg * 8];

#pragma unroll
        for (int dt = 0; dt < 4; ++dt) {
            bf16x8 bv = *(const bf16x8*)(vrow + (size_t)dt * 16384);
            oacc[dt] = __builtin_amdgcn_mfma_f32_16x16x32_bf16(pa, bv, oacc[dt], 0, 0, 0);
        }
        krow += 2048;
        vrow += 32;
    }

#pragma unroll
    for (int r = 0; r < 4; ++r) {
#pragma unroll
        for (int sh = 1; sh < 16; sh <<= 1) D[r] += __shfl_xor(D[r], sh, 64);
    }

#pragma unroll
    for (int r = 0; r < 4; ++r) {
        const int q = q0 + lg * 4 + r;
        const float inv = 1.0f / D[r];
        ushort* orow = ob + ((size_t)b * 1024 + q) * 512 + h * 64;
#pragma unroll
        for (int dt = 0; dt < 4; ++dt) orow[dt * 16 + lc] = f2bf(oacc[dt][r] * inv);
    }
}

// ---------------- FF: 32-token blocks — proj + w1(gelu,m1) + w2(m2) + LN2 + psum ----
__global__ __launch_bounds__(512) void ff_k(
    const ushort* __restrict__ ob,
    const ushort* __restrict__ wproj, const float* __restrict__ pjb,
    const ushort* __restrict__ ww1, const float* __restrict__ b1v,
    const ushort* __restrict__ ww2, const float* __restrict__ b2v,
    const float* __restrict__ g, const float* __restrict__ bln,
    float* __restrict__ pblock,
    uint32_t k10, uint32_t k11, uint32_t k20, uint32_t k21,
    uint32_t T1, uint32_t T2)
{
    __shared__ ushort bufA[32][520];
    __shared__ float stats[32][8][2];
    const int tid = threadIdx.x;
    const int wave = tid >> 6, lane = tid & 63;
    const int lg = lane >> 4, lc = lane & 15;
    const int b = blockIdx.x & 7, tg = blockIdx.x >> 3;

    // load O tile [32][512] bf16
    {
        const int row = tid >> 4, c0 = (tid & 15) * 32;
        const ushort* src = ob + ((size_t)(b * 1024 + tg * 32 + row)) * 512 + c0;
#pragma unroll
        for (int q8 = 0; q8 < 4; ++q8)
            *(u16x8*)&bufA[row][c0 + q8 * 8] = *(const u16x8*)(src + q8 * 8);
    }
    __syncthreads();

    const int o0 = wave * 64;
    const int mg0 = b * 1024 + tg * 32;
    f32x4 zero = {0.f, 0.f, 0.f, 0.f};

    // ---- proj ----
    f32x4 acc[2][4];
#pragma unroll
    for (int i = 0; i < 2; ++i)
#pragma unroll
        for (int j = 0; j < 4; ++j) acc[i][j] = zero;
    {
        const ushort* Wb = wproj + (size_t)(o0 + lc) * 512 + lg * 8;
#pragma unroll 4
        for (int k0 = 0; k0 < 512; k0 += 32) {
            bf16x8 a0 = *(const bf16x8*)&bufA[lc][k0 + lg * 8];
            bf16x8 a1 = *(const bf16x8*)&bufA[16 + lc][k0 + lg * 8];
#pragma unroll
            for (int j = 0; j < 4; ++j) {
                bf16x8 bw = *(const bf16x8*)(Wb + (size_t)j * 16 * 512 + k0);
                acc[0][j] = __builtin_amdgcn_mfma_f32_16x16x32_bf16(a0, bw, acc[0][j], 0, 0, 0);
                acc[1][j] = __builtin_amdgcn_mfma_f32_16x16x32_bf16(a1, bw, acc[1][j], 0, 0, 0);
            }
        }
    }
    float bias4[4];
#pragma unroll
    for (int j = 0; j < 4; ++j) bias4[j] = pjb[o0 + j * 16 + lc];
    __syncthreads();
#pragma unroll
    for (int i = 0; i < 2; ++i)
#pragma unroll
        for (int j = 0; j < 4; ++j)
#pragma unroll
            for (int r = 0; r < 4; ++r)
                bufA[i * 16 + lg * 4 + r][o0 + j * 16 + lc] = f2bf(acc[i][j][r] + bias4[j]);
    __syncthreads();

    // ---- w1 + gelu + m1 ----
#pragma unroll
    for (int i = 0; i < 2; ++i)
#pragma unroll
        for (int j = 0; j < 4; ++j) acc[i][j] = zero;
    {
        const ushort* Wb = ww1 + (size_t)(o0 + lc) * 512 + lg * 8;
#pragma unroll 4
        for (int k0 = 0; k0 < 512; k0 += 32) {
            bf16x8 a0 = *(const bf16x8*)&bufA[lc][k0 + lg * 8];
            bf16x8 a1 = *(const bf16x8*)&bufA[16 + lc][k0 + lg * 8];
#pragma unroll
            for (int j = 0; j < 4; ++j) {
                bf16x8 bw = *(const bf16x8*)(Wb + (size_t)j * 16 * 512 + k0);
                acc[0][j] = __builtin_amdgcn_mfma_f32_16x16x32_bf16(a0, bw, acc[0][j], 0, 0, 0);
                acc[1][j] = __builtin_amdgcn_mfma_f32_16x16x32_bf16(a1, bw, acc[1][j], 0, 0, 0);
            }
        }
    }
#pragma unroll
    for (int j = 0; j < 4; ++j) bias4[j] = b1v[o0 + j * 16 + lc];
    __syncthreads();
#pragma unroll
    for (int i = 0; i < 2; ++i) {
#pragma unroll
        for (int j = 0; j < 4; ++j) {
#pragma unroll
            for (int r = 0; r < 4; ++r) {
                float v = acc[i][j][r] + bias4[j];
                v = 0.5f * v * (1.0f + erff(v * 0.70710678118654752f));
                const uint32_t jidx =
                    (uint32_t)((mg0 + i * 16 + lg * 4 + r) * 512 + o0 + j * 16 + lc);
                if (tf_bits(k10, k11, jidx) < T1) v += NEGV;
                bufA[i * 16 + lg * 4 + r][o0 + j * 16 + lc] = f2bf(v);
            }
        }
    }
    __syncthreads();

    // ---- w2 + m2 -> t2 regs ----
#pragma unroll
    for (int i = 0; i < 2; ++i)
#pragma unroll
        for (int j = 0; j < 4; ++j) acc[i][j] = zero;
    {
        const ushort* Wb = ww2 + (size_t)(o0 + lc) * 512 + lg * 8;
#pragma unroll 4
        for (int k0 = 0; k0 < 512; k0 += 32) {
            bf16x8 a0 = *(const bf16x8*)&bufA[lc][k0 + lg * 8];
            bf16x8 a1 = *(const bf16x8*)&bufA[16 + lc][k0 + lg * 8];
#pragma unroll
            for (int j = 0; j < 4; ++j) {
                bf16x8 bw = *(const bf16x8*)(Wb + (size_t)j * 16 * 512 + k0);
                acc[0][j] = __builtin_amdgcn_mfma_f32_16x16x32_bf16(a0, bw, acc[0][j], 0, 0, 0);
                acc[1][j] = __builtin_amdgcn_mfma_f32_16x16x32_bf16(a1, bw, acc[1][j], 0, 0, 0);
            }
        }
    }
#pragma unroll
    for (int j = 0; j < 4; ++j) bias4[j] = b2v[o0 + j * 16 + lc];
    float t2v[2][4][4];
#pragma unroll
    for (int i = 0; i < 2; ++i) {
#pragma unroll
        for (int j = 0; j < 4; ++j) {
#pragma unroll
            for (int r = 0; r < 4; ++r) {
                float v = acc[i][j][r] + bias4[j];
                const uint32_t jidx =
                    (uint32_t)((mg0 + i * 16 + lg * 4 + r) * 512 + o0 + j * 16 + lc);
                if (tf_bits(k20, k21, jidx) < T2) v += NEGV;
                t2v[i][j][r] = v;
            }
        }
    }

    // ---- LN2 + token partial sums ----
#pragma unroll
    for (int i = 0; i < 2; ++i) {
#pragma unroll
        for (int r = 0; r < 4; ++r) {
            float s = 0.f, q = 0.f;
#pragma unroll
            for (int j = 0; j < 4; ++j) { s += t2v[i][j][r]; q += t2v[i][j][r] * t2v[i][j][r]; }
#pragma unroll
            for (int sh = 1; sh < 16; sh <<= 1) {
                s += __shfl_xor(s, sh, 64);
                q += __shfl_xor(q, sh, 64);
            }
            if (lc == 0) {
                stats[i * 16 + lg * 4 + r][wave][0] = s;
                stats[i * 16 + lg * 4 + r][wave][1] = q;
            }
        }
    }
    __syncthreads();
    float mu[2][4], inv[2][4];
#pragma unroll
    for (int i = 0; i < 2; ++i) {
#pragma unroll
        for (int r = 0; r < 4; ++r) {
            float S = 0.f, S2 = 0.f;
#pragma unroll
            for (int w = 0; w < 8; ++w) {
                S += stats[i * 16 + lg * 4 + r][w][0];
                S2 += stats[i * 16 + lg * 4 + r][w][1];
            }
            const float m = S * (1.0f / 512.0f);
            const float var = S2 * (1.0f / 512.0f) - m * m;
            mu[i][r] = m;
            inv[i][r] = 1.0f / sqrtf(var + 1e-5f);
        }
    }
    float gld[4], bld[4];
#pragma unroll
    for (int j = 0; j < 4; ++j) {
        gld[j] = g[o0 + j * 16 + lc];
        bld[j] = bln[o0 + j * 16 + lc];
    }
    float ps[4] = {0.f, 0.f, 0.f, 0.f};
#pragma unroll
    for (int i = 0; i < 2; ++i)
#pragma unroll
        for (int j = 0; j < 4; ++j)
#pragma unroll
            for (int r = 0; r < 4; ++r)
                ps[j] += (t2v[i][j][r] - mu[i][r]) * inv[i][r] * gld[j] + bld[j];
#pragma unroll
    for (int j = 0; j < 4; ++j) {
        ps[j] += __shfl_xor(ps[j], 16, 64);
        ps[j] += __shfl_xor(ps[j], 32, 64);
    }
    if (lg == 0) {
#pragma unroll
        for (int j = 0; j < 4; ++j)
            pblock[((size_t)(b * 32 + tg)) * 512 + o0 + j * 16 + lc] = ps[j];
    }
}

// ---------------- fc2: reduce pblock in-LDS + final fc ----------------
__global__ __launch_bounds__(256) void fc2_k(const float* __restrict__ pblock,
                                             const float* __restrict__ w,
                                             const float* __restrict__ bias,
                                             float* __restrict__ outp)
{
    __shared__ float tmld[512];
    const int b = blockIdx.y;
    const int tid = threadIdx.x;
#pragma unroll
    for (int cc = 0; cc < 2; ++cc) {
        const int c = tid + cc * 256;
        const float* p = pblock + (size_t)(b * 32) * 512 + c;
        float s = 0.f;
#pragma unroll 8
        for (int t = 0; t < 32; ++t) s += p[(size_t)t * 512];
        tmld[c] = s * (1.0f / 1024.0f);
    }
    __syncthreads();
    const int o = blockIdx.x * 256 + tid;
    const float* wr = w + (size_t)o * 512;
    float s = 0.f;
    for (int k = 0; k < 512; k += 4) {
        float4 a = *(const float4*)(tmld + k);
        float4 ww = *(const float4*)(wr + k);
        s = fmaf(a.x, ww.x, s); s = fmaf(a.y, ww.y, s);
        s = fmaf(a.z, ww.z, s); s = fmaf(a.w, ww.w, s);
    }
    outp[b * 2560 + o] = s + bias[o];
}

// ---------------- launch ----------------
extern "C" void kernel_launch(void* const* d_in, const int* in_sizes, int n_in,
                              void* d_out, int out_size, void* d_ws, size_t ws_size,
                              hipStream_t stream)
{
    const float* x      = (const float*)d_in[0];
    const float* conv_w = (const float*)d_in[1];
    const float* conv_b = (const float*)d_in[2];
    const float* ln_g   = (const float*)d_in[3];
    const float* ln_b   = (const float*)d_in[4];
    const float* qkv_w  = (const float*)d_in[5];
    const float* qkv_b  = (const float*)d_in[6];
    const float* proj_w = (const float*)d_in[7];
    const float* proj_b = (const float*)d_in[8];
    const float* w1     = (const float*)d_in[9];
    const float* b1     = (const float*)d_in[10];
    const float* w2     = (const float*)d_in[11];
    const float* b2     = (const float*)d_in[12];
    const float* fc_w   = (const float*)d_in[13];
    const float* fc_b   = (const float*)d_in[14];
    float* out = (float*)d_out;

    if (ws_size < (size_t)67108864) return;  // need 64 MiB scratch

    uint32_t mk0a, mk0b, mk1a, mk1b, mk2a, mk2b;
    tf2x32_host(0u, 42u, 0u, 0u, &mk0a, &mk0b);
    tf2x32_host(0u, 42u, 0u, 1u, &mk1a, &mk1b);
    tf2x32_host(0u, 42u, 0u, 2u, &mk2a, &mk2b);
    const uint32_t T_m1 = maskT(0.3f);
    const uint32_t T_m2 = maskT(0.1f);

    char* wsb = (char*)d_ws;
    ushort* xt     = (ushort*)wsb;                   // 8 MiB @0   -> obuf
    ushort* wts    = (ushort*)(wsb + 8388608);       // 3.5MiB @8M
    ushort* qbuf   = (ushort*)(wsb + 12582912);      // 8 MiB @12M
    ushort* kbuf   = (ushort*)(wsb + 20971520);      // 8 MiB @20M
    ushort* vtbuf  = (ushort*)(wsb + 29360128);      // 8 MiB @28M
    ushort* ln1bf  = (ushort*)(wsb + 37748736);      // 8 MiB @36M
    float*  pblock = (float*)(wsb + 46137344);       // 512 KiB @44M
    ushort* obuf   = xt;

    ushort* wconv = wts;
    ushort* wqkv  = wts + 262144;
    ushort* wproj = wts + 1048576;
    ushort* ww1   = wts + 1310720;
    ushort* ww2   = wts + 1572864;

    dim3 blk(256);
    // x transpose + weight convert
    prep_k<<<dim3(1920), blk, 0, stream>>>(x, xt, conv_w, qkv_w, proj_w, w1, w2, wts);
    // conv + LN1 -> ln1bf bf16
    convln_k<<<dim3(256), dim3(512), 0, stream>>>(xt, wconv, conv_b, ln_g, ln_b, ln1bf);
    // qkv (wave tile 32x128, +V transpose) -> q/k natural, vt transposed
    qkvvt_k<<<dim3(64, 12), blk, 0, stream>>>(ln1bf, wqkv, qkv_b, qbuf, kbuf, vtbuf);
    // attention (threefry fused) -> obuf bf16
    attn_k<<<dim3(1024), blk, 0, stream>>>(qbuf, kbuf, vtbuf, obuf, mk0a, mk0b);
    // FF fused (32-token blocks) -> pblock
    ff_k<<<dim3(256), dim3(512), 0, stream>>>(obuf, wproj, proj_b, ww1, b1, ww2, b2,
                                              ln_g, ln_b, pblock,
                                              mk1a, mk1b, mk2a, mk2b, T_m1, T_m2);
    // reduce + fc -> out
    fc2_k<<<dim3(10, 8), blk, 0, stream>>>(pblock, fc_w, fc_b, out);
}

// Round 12
// 315.228 us; speedup vs baseline: 1.6390x; 1.0018x over previous
//
#include <hip/hip_runtime.h>
#include <stdint.h>
#include <math.h>

#define NEGV -1.0e12f
// Q pre-scale: 1/sqrt(64) * log2(e)  (softmax uses native exp2)
#define QSCALE 0.18033688011112042f

typedef __attribute__((ext_vector_type(8))) short bf16x8;
typedef __attribute__((ext_vector_type(4))) float f32x4;
typedef __attribute__((ext_vector_type(8))) ushort u16x8;

// 1-instruction rotate
#define ROTL1(v, r) ({ uint32_t _d;                                            \
    asm("v_alignbit_b32 %0, %1, %1, %2" : "=v"(_d) : "v"(v), "n"(32 - (r)));   \
    _d; })

#if defined(__has_builtin)
#if __has_builtin(__builtin_amdgcn_exp2f)
#define EXP2(x) __builtin_amdgcn_exp2f(x)
#endif
#endif
#ifndef EXP2
#define EXP2(x) exp2f(x)
#endif

// ---------------- Threefry-2x32/20, host reference (key derivation) ----------------
__host__ static void tf2x32_host(uint32_t k0, uint32_t k1, uint32_t c0, uint32_t c1,
                                 uint32_t* o0, uint32_t* o1) {
    uint32_t ks2 = k0 ^ k1 ^ 0x1BD11BDAu;
    uint32_t x0 = c0 + k0, x1 = c1 + k1;
#define TF_RND(r) x0 += x1; x1 = ((x1 << (r)) | (x1 >> (32 - (r)))); x1 ^= x0;
    TF_RND(13) TF_RND(15) TF_RND(26) TF_RND(6)
    x0 += k1;  x1 += ks2 + 1u;
    TF_RND(17) TF_RND(29) TF_RND(16) TF_RND(24)
    x0 += ks2; x1 += k0 + 2u;
    TF_RND(13) TF_RND(15) TF_RND(26) TF_RND(6)
    x0 += k0;  x1 += k1 + 3u;
    TF_RND(17) TF_RND(29) TF_RND(16) TF_RND(24)
    x0 += k1;  x1 += ks2 + 4u;
    TF_RND(13) TF_RND(15) TF_RND(26) TF_RND(6)
    x0 += ks2; x1 += k0 + 5u;
#undef TF_RND
    *o0 = x0; *o1 = x1;
}

// device: JAX partitionable random bits for counter (0, j): bits = o0 ^ o1
__device__ __forceinline__ uint32_t tf_bits(uint32_t k0, uint32_t k1, uint32_t j) {
    const uint32_t ks2 = k0 ^ k1 ^ 0x1BD11BDAu;
    uint32_t x0 = k0, x1 = j + k1;
#define TFR(r) x0 += x1; x1 = ROTL1(x1, r); x1 ^= x0;
    TFR(13) TFR(15) TFR(26) TFR(6)
    x0 += k1;  x1 += ks2 + 1u;
    TFR(17) TFR(29) TFR(16) TFR(24)
    x0 += ks2; x1 += k0 + 2u;
    TFR(13) TFR(15) TFR(26) TFR(6)
    x0 += k0;  x1 += k1 + 3u;
    TFR(17) TFR(29) TFR(16) TFR(24)
    x0 += k1;  x1 += ks2 + 4u;
    TFR(13) TFR(15) TFR(26) TFR(6)
#undef TFR
    return (x0 + ks2) ^ (x1 + (k0 + 5u));
}

// bernoulli(p) true  <=>  bits < T,  T = ceil(p * 2^23) << 9  (exact vs JAX float path)
__host__ static uint32_t maskT(float p) {
    double t = ceil((double)p * 8388608.0);
    return ((uint32_t)t) << 9;
}

__device__ __forceinline__ ushort f2bf(float x) {
    uint32_t u = __float_as_uint(x);
    u += 0x7fffu + ((u >> 16) & 1u);
    return (ushort)(u >> 16);
}
__device__ __forceinline__ float bf2f(ushort u) {
    return __uint_as_float(((uint32_t)u) << 16);
}

// ---------------- prep: xpose (blocks 0..1023) + weight convert (1024..1919) --------
__global__ __launch_bounds__(256) void prep_k(const float* __restrict__ x,
                                              ushort* __restrict__ xt,
                                              const float* __restrict__ s0,
                                              const float* __restrict__ s1,
                                              const float* __restrict__ s2,
                                              const float* __restrict__ s3,
                                              const float* __restrict__ s4,
                                              ushort* __restrict__ wdst)
{
    __shared__ float tile[64][65];
    const int tid = threadIdx.x;
    if (blockIdx.x < 1024) {
        const int id = blockIdx.x;
        const int n0 = (id & 15) * 64, c0 = ((id >> 4) & 7) * 64, b = id >> 7;
        const float* src = x + ((size_t)b * 512 + c0) * 1024 + n0;
#pragma unroll
        for (int i = 0; i < 4; ++i) {
            const int r = (tid >> 4) + i * 16;
            const int col = (tid & 15) * 4;
            float4 v = *(const float4*)(src + (size_t)r * 1024 + col);
            tile[r][col + 0] = v.x; tile[r][col + 1] = v.y;
            tile[r][col + 2] = v.z; tile[r][col + 3] = v.w;
        }
        __syncthreads();
#pragma unroll
        for (int i = 0; i < 2; ++i) {
            const int nl = (tid >> 3) + i * 32;
            const int cb = (tid & 7) * 8;
            u16x8 o;
#pragma unroll
            for (int j = 0; j < 8; ++j) o[j] = f2bf(tile[cb + j][nl]);
            *(u16x8*)(xt + ((size_t)b * 1024 + n0 + nl) * 512 + c0 + cb) = o;
        }
    } else {
        const size_t i = ((size_t)(blockIdx.x - 1024) * 256 + tid) * 8;
        const float* src; size_t off;
        if (i < 262144)       { src = s0; off = 0; }
        else if (i < 1048576) { src = s1; off = 262144; }
        else if (i < 1310720) { src = s2; off = 1048576; }
        else if (i < 1572864) { src = s3; off = 1310720; }
        else                  { src = s4; off = 1572864; }
        const float* p = src + (i - off);
        float4 a = *(const float4*)p;
        float4 b = *(const float4*)(p + 4);
        u16x8 o;
        o[0] = f2bf(a.x); o[1] = f2bf(a.y); o[2] = f2bf(a.z); o[3] = f2bf(a.w);
        o[4] = f2bf(b.x); o[5] = f2bf(b.y); o[6] = f2bf(b.z); o[7] = f2bf(b.w);
        *(u16x8*)(wdst + i) = o;
    }
}

// ---------------- conv + LN1 fused: 512 thr, 32 tokens x 512 outs, 8 waves ----------
__global__ __launch_bounds__(512) void convln_k(
    const ushort* __restrict__ A, const ushort* __restrict__ W,
    const float* __restrict__ bias,
    const float* __restrict__ g, const float* __restrict__ bln,
    ushort* __restrict__ outb)
{
    __shared__ ushort cbuf[32][520];
    const int tid = threadIdx.x;
    const int wave = tid >> 6, lane = tid & 63;
    const int lg = lane >> 4, lc = lane & 15;
    const int m0 = blockIdx.x * 32;
    const int o0 = wave * 64;

    f32x4 acc[2][4];
#pragma unroll
    for (int i = 0; i < 2; ++i)
#pragma unroll
        for (int j = 0; j < 4; ++j) acc[i][j] = (f32x4){0.f, 0.f, 0.f, 0.f};

    const ushort* Ab = A + (size_t)(m0 + lc) * 512 + lg * 8;
    const ushort* Wb = W + (size_t)(o0 + lc) * 512 + lg * 8;

#pragma unroll 4
    for (int k0 = 0; k0 < 512; k0 += 32) {
        bf16x8 aq[2], bw[4];
        aq[0] = *(const bf16x8*)(Ab + k0);
        aq[1] = *(const bf16x8*)(Ab + 16 * 512 + k0);
#pragma unroll
        for (int j = 0; j < 4; ++j) bw[j] = *(const bf16x8*)(Wb + (size_t)j * 16 * 512 + k0);
#pragma unroll
        for (int i = 0; i < 2; ++i)
#pragma unroll
            for (int j = 0; j < 4; ++j)
                acc[i][j] = __builtin_amdgcn_mfma_f32_16x16x32_bf16(aq[i], bw[j], acc[i][j], 0, 0, 0);
    }

#pragma unroll
    for (int j = 0; j < 4; ++j) {
        const float bv = bias[o0 + j * 16 + lc];
#pragma unroll
        for (int i = 0; i < 2; ++i)
#pragma unroll
            for (int r = 0; r < 4; ++r)
                cbuf[i * 16 + lg * 4 + r][o0 + j * 16 + lc] = f2bf(acc[i][j][r] + bv);
    }
    __syncthreads();

    // LN over 4 tokens per wave
    const int c0 = lane * 8;
    float4 g0 = *(const float4*)(g + c0);
    float4 g1 = *(const float4*)(g + c0 + 4);
    float4 b0 = *(const float4*)(bln + c0);
    float4 b1 = *(const float4*)(bln + c0 + 4);
    float gg[8] = {g0.x, g0.y, g0.z, g0.w, g1.x, g1.y, g1.z, g1.w};
    float bv8[8] = {b0.x, b0.y, b0.z, b0.w, b1.x, b1.y, b1.z, b1.w};
#pragma unroll
    for (int tt = 0; tt < 4; ++tt) {
        const int row = wave * 4 + tt;
        u16x8 vv = *(const u16x8*)&cbuf[row][c0];
        float xv[8];
#pragma unroll
        for (int i = 0; i < 8; i++) xv[i] = bf2f(vv[i]);
        float s = 0.f;
#pragma unroll
        for (int i = 0; i < 8; i++) s += xv[i];
#pragma unroll
        for (int sh = 32; sh; sh >>= 1) s += __shfl_xor(s, sh, 64);
        const float mu = s * (1.0f / 512.0f);
        float vs = 0.f;
#pragma unroll
        for (int i = 0; i < 8; i++) { float d = xv[i] - mu; vs += d * d; }
#pragma unroll
        for (int sh = 32; sh; sh >>= 1) vs += __shfl_xor(vs, sh, 64);
        const float inv = 1.0f / sqrtf(vs * (1.0f / 512.0f) + 1e-5f);
        u16x8 o;
#pragma unroll
        for (int i = 0; i < 8; i++) o[i] = f2bf((xv[i] - mu) * inv * gg[i] + bv8[i]);
        *(u16x8*)(outb + (size_t)(m0 + row) * 512 + c0) = o;
    }
}

// ---------------- qkv GEMM, wave tile 32x128 (A-frag reuse) + in-kernel V transpose -
// grid (64, 12): y<8 -> q/k outputs [y*128, y*128+128); y>=8 -> V (2 heads per block).
__global__ __launch_bounds__(256) void qkvvt_k(
    const ushort* __restrict__ A, const ushort* __restrict__ W,
    const float* __restrict__ bias,
    ushort* __restrict__ qb, ushort* __restrict__ kb, ushort* __restrict__ vtb)
{
    __shared__ ushort vtile[128][136];
    const int tid = threadIdx.x;
    const int wave = tid >> 6, lane = tid & 63;
    const int lg = lane >> 4, lc = lane & 15;
    const int m0 = blockIdx.x * 128 + wave * 32;
    const int o0 = blockIdx.y * 128;

    f32x4 acc[2][8];
#pragma unroll
    for (int i = 0; i < 2; ++i)
#pragma unroll
        for (int j = 0; j < 8; ++j) acc[i][j] = (f32x4){0.f, 0.f, 0.f, 0.f};

    const ushort* Ab = A + (size_t)(m0 + lc) * 512 + lg * 8;
    const ushort* Wb = W + (size_t)(o0 + lc) * 512 + lg * 8;

#pragma unroll 2
    for (int k0 = 0; k0 < 512; k0 += 32) {
        bf16x8 aq[2], bw[8];
        aq[0] = *(const bf16x8*)(Ab + k0);
        aq[1] = *(const bf16x8*)(Ab + 16 * 512 + k0);
#pragma unroll
        for (int j = 0; j < 8; ++j) bw[j] = *(const bf16x8*)(Wb + (size_t)j * 16 * 512 + k0);
#pragma unroll
        for (int i = 0; i < 2; ++i)
#pragma unroll
            for (int j = 0; j < 8; ++j)
                acc[i][j] = __builtin_amdgcn_mfma_f32_16x16x32_bf16(aq[i], bw[j], acc[i][j], 0, 0, 0);
    }

    float bvv[8];
#pragma unroll
    for (int j = 0; j < 8; ++j) bvv[j] = bias[o0 + j * 16 + lc];

    if (blockIdx.y < 8) {
        // q/k: natural [bh][n][64] scatter; o < 512 -> q (pre-scaled), else k
#pragma unroll
        for (int i = 0; i < 2; ++i) {
#pragma unroll
            for (int j = 0; j < 8; ++j) {
#pragma unroll
                for (int r = 0; r < 4; ++r) {
                    const int m = m0 + i * 16 + lg * 4 + r;
                    const int o = o0 + j * 16 + lc;
                    float v = acc[i][j][r] + bvv[j];
                    const int s = o >> 9, hh = (o >> 6) & 7, d = o & 63;
                    const int b = m >> 10, n = m & 1023;
                    const int bh = b * 8 + hh;
                    ushort* dst = (s == 0) ? qb : kb;
                    const float scl = (s == 0) ? QSCALE : 1.0f;
                    dst[((size_t)bh * 1024 + n) * 64 + d] = f2bf(v * scl);
                }
            }
        }
    } else {
        // V: o-range covers 2 heads x 64 dims; 128 tokens of one batch
        const int mloc0 = wave * 32;
#pragma unroll
        for (int i = 0; i < 2; ++i)
#pragma unroll
            for (int j = 0; j < 8; ++j)
#pragma unroll
                for (int r = 0; r < 4; ++r)
                    vtile[j * 16 + lc][mloc0 + i * 16 + lg * 4 + r] = f2bf(acc[i][j][r] + bvv[j]);
        __syncthreads();
        const int mb0 = blockIdx.x * 128;
        const int b = mb0 >> 10, n0 = mb0 & 1023;
        const int hhbase = (o0 - 1024) >> 6;   // 2 heads: hhbase, hhbase+1
        const int od = tid >> 1, ng = (tid & 1) * 64;
        const int hh = hhbase + (od >> 6), d = od & 63;
        ushort* dst = vtb + ((size_t)(b * 8 + hh) * 64 + d) * 1024 + n0 + ng;
#pragma unroll
        for (int q8 = 0; q8 < 8; ++q8) {
            u16x8 o;
#pragma unroll
            for (int e = 0; e < 8; ++e) o[e] = vtile[od][ng + q8 * 8 + e];
            *(u16x8*)(dst + q8 * 8) = o;
        }
    }
}

// ---------------- MFMA bf16 flash attention, threefry fused, XCD-local grid ---------
// 128 threads = 2 waves per block; grid 2048: bh = id & 63, qt = id >> 6 (32-row tiles).
// Smaller blocks -> more blocks/CU -> better wave packing for the VALU-bound RNG.
__global__ __launch_bounds__(128) void attn_k(
    const ushort* __restrict__ qb, const ushort* __restrict__ kb,
    const ushort* __restrict__ vtb, ushort* __restrict__ ob,
    uint32_t km0, uint32_t km1)
{
    __shared__ ushort plds[2][16][40];
    const int tid = threadIdx.x;
    const int wave = tid >> 6, lane = tid & 63;
    const int bh = blockIdx.x & 63;
    const int qt = blockIdx.x >> 6;
    const int b = bh >> 3, h = bh & 7;
    const int q0 = qt * 32 + wave * 16;
    const int lg = lane >> 4, lc = lane & 15;

    const ushort* qp = qb + (size_t)bh * 65536;

    bf16x8 aq0 = *(const bf16x8*)(qp + (size_t)(q0 + lc) * 64 + lg * 8);
    bf16x8 aq1 = *(const bf16x8*)(qp + (size_t)(q0 + lc) * 64 + 32 + lg * 8);

    f32x4 zero = {0.f, 0.f, 0.f, 0.f};
    f32x4 oacc[4] = {zero, zero, zero, zero};
    float D[4] = {0.f, 0.f, 0.f, 0.f};

    uint32_t jr[4];
#pragma unroll
    for (int r = 0; r < 4; ++r)
        jr[r] = ((uint32_t)bh * 1024u + (uint32_t)(q0 + lg * 4 + r)) * 1024u + (uint32_t)lc;

    const ushort* krow = kb + (size_t)bh * 65536 + (size_t)lc * 64 + lg * 8;
    const ushort* vrow = vtb + (size_t)bh * 65536 + (size_t)lc * 1024 + lg * 8;

    for (int ch = 0; ch < 32; ++ch) {
        bf16x8 bk00 = *(const bf16x8*)(krow);
        bf16x8 bk01 = *(const bf16x8*)(krow + 32);
        bf16x8 bk10 = *(const bf16x8*)(krow + 1024);
        bf16x8 bk11 = *(const bf16x8*)(krow + 1056);

        f32x4 s0 = __builtin_amdgcn_mfma_f32_16x16x32_bf16(aq0, bk00, zero, 0, 0, 0);
        s0 = __builtin_amdgcn_mfma_f32_16x16x32_bf16(aq1, bk01, s0, 0, 0, 0);
        f32x4 s1 = __builtin_amdgcn_mfma_f32_16x16x32_bf16(aq0, bk10, zero, 0, 0, 0);
        s1 = __builtin_amdgcn_mfma_f32_16x16x32_bf16(aq1, bk11, s1, 0, 0, 0);

#pragma unroll
        for (int r = 0; r < 4; ++r) {
            const uint32_t bits0 = tf_bits(km0, km1, jr[r]);
            const uint32_t bits1 = tf_bits(km0, km1, jr[r] + 16u);
            jr[r] += 32u;
            const float pv0 = ((int)bits0 < 0) ? EXP2(s0[r]) : 0.f;
            const float pv1 = ((int)bits1 < 0) ? EXP2(s1[r]) : 0.f;
            D[r] += pv0 + pv1;
            uint32_t pk;
            asm("v_cvt_pk_bf16_f32 %0, %1, %2" : "=v"(pk) : "v"(pv0), "v"(pv1));
            plds[wave][lg * 4 + r][lc] = (ushort)pk;
            plds[wave][lg * 4 + r][lc + 16] = (ushort)(pk >> 16);
        }

        bf16x8 pa = *(const bf16x8*)&plds[wave][lc][lg * 8];

#pragma unroll
        for (int dt = 0; dt < 4; ++dt) {
            bf16x8 bv = *(const bf16x8*)(vrow + (size_t)dt * 16384);
            oacc[dt] = __builtin_amdgcn_mfma_f32_16x16x32_bf16(pa, bv, oacc[dt], 0, 0, 0);
        }
        krow += 2048;
        vrow += 32;
    }

#pragma unroll
    for (int r = 0; r < 4; ++r) {
#pragma unroll
        for (int sh = 1; sh < 16; sh <<= 1) D[r] += __shfl_xor(D[r], sh, 64);
    }

#pragma unroll
    for (int r = 0; r < 4; ++r) {
        const int q = q0 + lg * 4 + r;
        const float inv = 1.0f / D[r];
        ushort* orow = ob + ((size_t)b * 1024 + q) * 512 + h * 64;
#pragma unroll
        for (int dt = 0; dt < 4; ++dt) orow[dt * 16 + lc] = f2bf(oacc[dt][r] * inv);
    }
}

// ---------------- FF: 32-token blocks — proj + w1(gelu,m1) + w2(m2) + LN2 + psum ----
__global__ __launch_bounds__(512) void ff_k(
    const ushort* __restrict__ ob,
    const ushort* __restrict__ wproj, const float* __restrict__ pjb,
    const ushort* __restrict__ ww1, const float* __restrict__ b1v,
    const ushort* __restrict__ ww2, const float* __restrict__ b2v,
    const float* __restrict__ g, const float* __restrict__ bln,
    float* __restrict__ pblock,
    uint32_t k10, uint32_t k11, uint32_t k20, uint32_t k21,
    uint32_t T1, uint32_t T2)
{
    __shared__ ushort bufA[32][520];
    __shared__ float stats[32][8][2];
    const int tid = threadIdx.x;
    const int wave = tid >> 6, lane = tid & 63;
    const int lg = lane >> 4, lc = lane & 15;
    const int b = blockIdx.x & 7, tg = blockIdx.x >> 3;

    // load O tile [32][512] bf16
    {
        const int row = tid >> 4, c0 = (tid & 15) * 32;
        const ushort* src = ob + ((size_t)(b * 1024 + tg * 32 + row)) * 512 + c0;
#pragma unroll
        for (int q8 = 0; q8 < 4; ++q8)
            *(u16x8*)&bufA[row][c0 + q8 * 8] = *(const u16x8*)(src + q8 * 8);
    }
    __syncthreads();

    const int o0 = wave * 64;
    const int mg0 = b * 1024 + tg * 32;
    f32x4 zero = {0.f, 0.f, 0.f, 0.f};

    // ---- proj ----
    f32x4 acc[2][4];
#pragma unroll
    for (int i = 0; i < 2; ++i)
#pragma unroll
        for (int j = 0; j < 4; ++j) acc[i][j] = zero;
    {
        const ushort* Wb = wproj + (size_t)(o0 + lc) * 512 + lg * 8;
#pragma unroll 4
        for (int k0 = 0; k0 < 512; k0 += 32) {
            bf16x8 a0 = *(const bf16x8*)&bufA[lc][k0 + lg * 8];
            bf16x8 a1 = *(const bf16x8*)&bufA[16 + lc][k0 + lg * 8];
#pragma unroll
            for (int j = 0; j < 4; ++j) {
                bf16x8 bw = *(const bf16x8*)(Wb + (size_t)j * 16 * 512 + k0);
                acc[0][j] = __builtin_amdgcn_mfma_f32_16x16x32_bf16(a0, bw, acc[0][j], 0, 0, 0);
                acc[1][j] = __builtin_amdgcn_mfma_f32_16x16x32_bf16(a1, bw, acc[1][j], 0, 0, 0);
            }
        }
    }
    float bias4[4];
#pragma unroll
    for (int j = 0; j < 4; ++j) bias4[j] = pjb[o0 + j * 16 + lc];
    __syncthreads();
#pragma unroll
    for (int i = 0; i < 2; ++i)
#pragma unroll
        for (int j = 0; j < 4; ++j)
#pragma unroll
            for (int r = 0; r < 4; ++r)
                bufA[i * 16 + lg * 4 + r][o0 + j * 16 + lc] = f2bf(acc[i][j][r] + bias4[j]);
    __syncthreads();

    // ---- w1 + gelu + m1 ----
#pragma unroll
    for (int i = 0; i < 2; ++i)
#pragma unroll
        for (int j = 0; j < 4; ++j) acc[i][j] = zero;
    {
        const ushort* Wb = ww1 + (size_t)(o0 + lc) * 512 + lg * 8;
#pragma unroll 4
        for (int k0 = 0; k0 < 512; k0 += 32) {
            bf16x8 a0 = *(const bf16x8*)&bufA[lc][k0 + lg * 8];
            bf16x8 a1 = *(const bf16x8*)&bufA[16 + lc][k0 + lg * 8];
#pragma unroll
            for (int j = 0; j < 4; ++j) {
                bf16x8 bw = *(const bf16x8*)(Wb + (size_t)j * 16 * 512 + k0);
                acc[0][j] = __builtin_amdgcn_mfma_f32_16x16x32_bf16(a0, bw, acc[0][j], 0, 0, 0);
                acc[1][j] = __builtin_amdgcn_mfma_f32_16x16x32_bf16(a1, bw, acc[1][j], 0, 0, 0);
            }
        }
    }
#pragma unroll
    for (int j = 0; j < 4; ++j) bias4[j] = b1v[o0 + j * 16 + lc];
    __syncthreads();
#pragma unroll
    for (int i = 0; i < 2; ++i) {
#pragma unroll
        for (int j = 0; j < 4; ++j) {
#pragma unroll
            for (int r = 0; r < 4; ++r) {
                float v = acc[i][j][r] + bias4[j];
                v = 0.5f * v * (1.0f + erff(v * 0.70710678118654752f));
                const uint32_t jidx =
                    (uint32_t)((mg0 + i * 16 + lg * 4 + r) * 512 + o0 + j * 16 + lc);
                if (tf_bits(k10, k11, jidx) < T1) v += NEGV;
                bufA[i * 16 + lg * 4 + r][o0 + j * 16 + lc] = f2bf(v);
            }
        }
    }
    __syncthreads();

    // ---- w2 + m2 -> t2 regs ----
#pragma unroll
    for (int i = 0; i < 2; ++i)
#pragma unroll
        for (int j = 0; j < 4; ++j) acc[i][j] = zero;
    {
        const ushort* Wb = ww2 + (size_t)(o0 + lc) * 512 + lg * 8;
#pragma unroll 4
        for (int k0 = 0; k0 < 512; k0 += 32) {
            bf16x8 a0 = *(const bf16x8*)&bufA[lc][k0 + lg * 8];
            bf16x8 a1 = *(const bf16x8*)&bufA[16 + lc][k0 + lg * 8];
#pragma unroll
            for (int j = 0; j < 4; ++j) {
                bf16x8 bw = *(const bf16x8*)(Wb + (size_t)j * 16 * 512 + k0);
                acc[0][j] = __builtin_amdgcn_mfma_f32_16x16x32_bf16(a0, bw, acc[0][j], 0, 0, 0);
                acc[1][j] = __builtin_amdgcn_mfma_f32_16x16x32_bf16(a1, bw, acc[1][j], 0, 0, 0);
            }
        }
    }
#pragma unroll
    for (int j = 0; j < 4; ++j) bias4[j] = b2v[o0 + j * 16 + lc];
    float t2v[2][4][4];
#pragma unroll
    for (int i = 0; i < 2; ++i) {
#pragma unroll
        for (int j = 0; j < 4; ++j) {
#pragma unroll
            for (int r = 0; r < 4; ++r) {
                float v = acc[i][j][r] + bias4[j];
                const uint32_t jidx =
                    (uint32_t)((mg0 + i * 16 + lg * 4 + r) * 512 + o0 + j * 16 + lc);
                if (tf_bits(k20, k21, jidx) < T2) v += NEGV;
                t2v[i][j][r] = v;
            }
        }
    }

    // ---- LN2 + token partial sums ----
#pragma unroll
    for (int i = 0; i < 2; ++i) {
#pragma unroll
        for (int r = 0; r < 4; ++r) {
            float s = 0.f, q = 0.f;
#pragma unroll
            for (int j = 0; j < 4; ++j) { s += t2v[i][j][r]; q += t2v[i][j][r] * t2v[i][j][r]; }
#pragma unroll
            for (int sh = 1; sh < 16; sh <<= 1) {
                s += __shfl_xor(s, sh, 64);
                q += __shfl_xor(q, sh, 64);
            }
            if (lc == 0) {
                stats[i * 16 + lg * 4 + r][wave][0] = s;
                stats[i * 16 + lg * 4 + r][wave][1] = q;
            }
        }
    }
    __syncthreads();
    float mu[2][4], inv[2][4];
#pragma unroll
    for (int i = 0; i < 2; ++i) {
#pragma unroll
        for (int r = 0; r < 4; ++r) {
            float S = 0.f, S2 = 0.f;
#pragma unroll
            for (int w = 0; w < 8; ++w) {
                S += stats[i * 16 + lg * 4 + r][w][0];
                S2 += stats[i * 16 + lg * 4 + r][w][1];
            }
            const float m = S * (1.0f / 512.0f);
            const float var = S2 * (1.0f / 512.0f) - m * m;
            mu[i][r] = m;
            inv[i][r] = 1.0f / sqrtf(var + 1e-5f);
        }
    }
    float gld[4], bld[4];
#pragma unroll
    for (int j = 0; j < 4; ++j) {
        gld[j] = g[o0 + j * 16 + lc];
        bld[j] = bln[o0 + j * 16 + lc];
    }
    float ps[4] = {0.f, 0.f, 0.f, 0.f};
#pragma unroll
    for (int i = 0; i < 2; ++i)
#pragma unroll
        for (int j = 0; j < 4; ++j)
#pragma unroll
            for (int r = 0; r < 4; ++r)
                ps[j] += (t2v[i][j][r] - mu[i][r]) * inv[i][r] * gld[j] + bld[j];
#pragma unroll
    for (int j = 0; j < 4; ++j) {
        ps[j] += __shfl_xor(ps[j], 16, 64);
        ps[j] += __shfl_xor(ps[j], 32, 64);
    }
    if (lg == 0) {
#pragma unroll
        for (int j = 0; j < 4; ++j)
            pblock[((size_t)(b * 32 + tg)) * 512 + o0 + j * 16 + lc] = ps[j];
    }
}

// ---------------- fc2: reduce pblock in-LDS + final fc ----------------
__global__ __launch_bounds__(256) void fc2_k(const float* __restrict__ pblock,
                                             const float* __restrict__ w,
                                             const float* __restrict__ bias,
                                             float* __restrict__ outp)
{
    __shared__ float tmld[512];
    const int b = blockIdx.y;
    const int tid = threadIdx.x;
#pragma unroll
    for (int cc = 0; cc < 2; ++cc) {
        const int c = tid + cc * 256;
        const float* p = pblock + (size_t)(b * 32) * 512 + c;
        float s = 0.f;
#pragma unroll 8
        for (int t = 0; t < 32; ++t) s += p[(size_t)t * 512];
        tmld[c] = s * (1.0f / 1024.0f);
    }
    __syncthreads();
    const int o = blockIdx.x * 256 + tid;
    const float* wr = w + (size_t)o * 512;
    float s = 0.f;
    for (int k = 0; k < 512; k += 4) {
        float4 a = *(const float4*)(tmld + k);
        float4 ww = *(const float4*)(wr + k);
        s = fmaf(a.x, ww.x, s); s = fmaf(a.y, ww.y, s);
        s = fmaf(a.z, ww.z, s); s = fmaf(a.w, ww.w, s);
    }
    outp[b * 2560 + o] = s + bias[o];
}

// ---------------- launch ----------------
extern "C" void kernel_launch(void* const* d_in, const int* in_sizes, int n_in,
                              void* d_out, int out_size, void* d_ws, size_t ws_size,
                              hipStream_t stream)
{
    const float* x      = (const float*)d_in[0];
    const float* conv_w = (const float*)d_in[1];
    const float* conv_b = (const float*)d_in[2];
    const float* ln_g   = (const float*)d_in[3];
    const float* ln_b   = (const float*)d_in[4];
    const float* qkv_w  = (const float*)d_in[5];
    const float* qkv_b  = (const float*)d_in[6];
    const float* proj_w = (const float*)d_in[7];
    const float* proj_b = (const float*)d_in[8];
    const float* w1     = (const float*)d_in[9];
    const float* b1     = (const float*)d_in[10];
    const float* w2     = (const float*)d_in[11];
    const float* b2     = (const float*)d_in[12];
    const float* fc_w   = (const float*)d_in[13];
    const float* fc_b   = (const float*)d_in[14];
    float* out = (float*)d_out;

    if (ws_size < (size_t)67108864) return;  // need 64 MiB scratch

    uint32_t mk0a, mk0b, mk1a, mk1b, mk2a, mk2b;
    tf2x32_host(0u, 42u, 0u, 0u, &mk0a, &mk0b);
    tf2x32_host(0u, 42u, 0u, 1u, &mk1a, &mk1b);
    tf2x32_host(0u, 42u, 0u, 2u, &mk2a, &mk2b);
    const uint32_t T_m1 = maskT(0.3f);
    const uint32_t T_m2 = maskT(0.1f);

    char* wsb = (char*)d_ws;
    ushort* xt     = (ushort*)wsb;                   // 8 MiB @0   -> obuf
    ushort* wts    = (ushort*)(wsb + 8388608);       // 3.5MiB @8M
    ushort* qbuf   = (ushort*)(wsb + 12582912);      // 8 MiB @12M
    ushort* kbuf   = (ushort*)(wsb + 20971520);      // 8 MiB @20M
    ushort* vtbuf  = (ushort*)(wsb + 29360128);      // 8 MiB @28M
    ushort* ln1bf  = (ushort*)(wsb + 37748736);      // 8 MiB @36M
    float*  pblock = (float*)(wsb + 46137344);       // 512 KiB @44M
    ushort* obuf   = xt;

    ushort* wconv = wts;
    ushort* wqkv  = wts + 262144;
    ushort* wproj = wts + 1048576;
    ushort* ww1   = wts + 1310720;
    ushort* ww2   = wts + 1572864;

    dim3 blk(256);
    // x transpose + weight convert
    prep_k<<<dim3(1920), blk, 0, stream>>>(x, xt, conv_w, qkv_w, proj_w, w1, w2, wts);
    // conv + LN1 -> ln1bf bf16
    convln_k<<<dim3(256), dim3(512), 0, stream>>>(xt, wconv, conv_b, ln_g, ln_b, ln1bf);
    // qkv (wave tile 32x128, +V transpose) -> q/k natural, vt transposed
    qkvvt_k<<<dim3(64, 12), blk, 0, stream>>>(ln1bf, wqkv, qkv_b, qbuf, kbuf, vtbuf);
    // attention (threefry fused), 2-wave blocks -> obuf bf16
    attn_k<<<dim3(2048), dim3(128), 0, stream>>>(qbuf, kbuf, vtbuf, obuf, mk0a, mk0b);
    // FF fused (32-token blocks) -> pblock
    ff_k<<<dim3(256), dim3(512), 0, stream>>>(obuf, wproj, proj_b, ww1, b1, ww2, b2,
                                              ln_g, ln_b, pblock,
                                              mk1a, mk1b, mk2a, mk2b, T_m1, T_m2);
    // reduce + fc -> out
    fc2_k<<<dim3(10, 8), blk, 0, stream>>>(pblock, fc_w, fc_b, out);
}